// Round 22
// baseline (219.636 us; speedup 1.0000x reference)
//
#include <hip/hip_runtime.h>
#include <math.h>

#define T_TOK 12544   // 64*196
#define DE 768
#define DQ 512
#define DD 256
#define SEQ 196
#define NCH 4096
#define NCL 256
#define SPL_H 16      // high codebook: 16 slices of 256 codes
#define CODES_PER_BLK 256
#define MARGIN 2.0f
#define CAND_CAP 16
#define VQTOK 32      // tokens per vq block (32 -> 2x concurrency vs 64)

typedef __attribute__((ext_vector_type(8))) short s16x8;
typedef __attribute__((ext_vector_type(4))) float f32x4;

__device__ __forceinline__ float wave_reduce_sum(float v) {
    #pragma unroll
    for (int off = 32; off > 0; off >>= 1) v += __shfl_xor(v, off);
    return v;
}

__device__ __forceinline__ unsigned short f2bf(float f) {
    unsigned int u = __float_as_uint(f);
    u = (u + 0x7fffu + ((u >> 16) & 1u)) >> 16;
    return (unsigned short)u;
}
__device__ __forceinline__ float bf2f(unsigned short h) {
    return __uint_as_float(((unsigned int)h) << 16);
}

// async global->LDS 16B: dest = wave-uniform base + lane*16 (pre-swizzled source)
__device__ __forceinline__ void gload_lds16(const unsigned short* g, unsigned short* l) {
    __builtin_amdgcn_global_load_lds(
        (const __attribute__((address_space(1))) void*)g,
        (__attribute__((address_space(3))) void*)l,
        16, 0, 0);
}

// ---------------- device helpers for merged preprocessing ----------------
__device__ __forceinline__ void sumsq_body(const float* __restrict__ cb,
                                           float* __restrict__ cs2,
                                           unsigned short* __restrict__ cbB,
                                           int blk, int NC) {
    int row = blk * 4 + (threadIdx.x >> 6);
    int lane = threadIdx.x & 63;
    if (row >= NC) return;
    const float4* p = (const float4*)(cb + (size_t)row * DQ);
    float4 a = p[lane];
    float4 b = p[lane + 64];
    if (cbB) {
        unsigned short* dst = cbB + (size_t)row * DQ;
        ushort4 ha, hb;
        ha.x = f2bf(a.x); ha.y = f2bf(a.y); ha.z = f2bf(a.z); ha.w = f2bf(a.w);
        hb.x = f2bf(b.x); hb.y = f2bf(b.y); hb.z = f2bf(b.z); hb.w = f2bf(b.w);
        *(ushort4*)(dst + lane * 4) = ha;
        *(ushort4*)(dst + 256 + lane * 4) = hb;
    }
    float s = a.x*a.x + a.y*a.y + a.z*a.z + a.w*a.w
            + b.x*b.x + b.y*b.y + b.z*b.z + b.w*b.w;
    s = wave_reduce_sum(s);
    if (lane == 0) cs2[row] = s;
}

__device__ __forceinline__ void split_body(const float* __restrict__ W, int K, int N,
                                           unsigned short* __restrict__ Thi,
                                           unsigned short* __restrict__ Tlo,
                                           int blk, int nb) {
    int total = K * N;
    for (int idx = blk * 256 + threadIdx.x; idx < total; idx += nb * 256) {
        int n = idx / K, k = idx - n * K;
        float v = W[(size_t)k * N + n];
        unsigned short h = f2bf(v);
        Thi[idx] = h;
        Tlo[idx] = f2bf(v - bf2f(h));
    }
}

// ---------------- merged preprocessing: sumsq(H,L) + splitW(proj,dec) ----------------
__global__ __launch_bounds__(256) void prep_all(const float* __restrict__ cb_h,
                                                float* __restrict__ cs2h,
                                                unsigned short* __restrict__ cbhB,
                                                const float* __restrict__ cb_l,
                                                float* __restrict__ cs2l,
                                                unsigned short* __restrict__ cblB,
                                                const float* __restrict__ Wp,
                                                unsigned short* __restrict__ WThi,
                                                unsigned short* __restrict__ WTlo,
                                                const float* __restrict__ Wd,
                                                unsigned short* __restrict__ WdThi,
                                                unsigned short* __restrict__ WdTlo) {
    int blk = blockIdx.x;
    if (blk < 1024)       sumsq_body(cb_h, cs2h, cbhB, blk, NCH);
    else if (blk < 1088)  sumsq_body(cb_l, cs2l, cblB, blk - 1024, NCL);
    else if (blk < 1600)  split_body(Wp, DE, DQ, WThi, WTlo, blk - 1088, 512);
    else                  split_body(Wd, DQ, DD, WdThi, WdTlo, blk - 1600, 256);
}

// ---------------- fallback code_sumsq (fp32 path only) ----------------
template<int NC>
__global__ __launch_bounds__(256) void code_sumsq(const float* __restrict__ cb,
                                                  float* __restrict__ cs2) {
    sumsq_body(cb, cs2, nullptr, blockIdx.x, NC);
}

// ---------------- proj/dec via 3-term split-bf16 MFMA, double-buffered ----------------
// BM=64, BN=64 (CPW=1): proven no-spill shape (VGPR 44, ~62 us). Do NOT widen.
template<int KDIM, int NSTRIDE, int BN>
__global__ __launch_bounds__(256) void gemm_mfma3(const float* __restrict__ A,
                                                  const unsigned short* __restrict__ BThi,
                                                  const unsigned short* __restrict__ BTlo,
                                                  const float* __restrict__ bias,
                                                  float* __restrict__ out) {
    constexpr int CPW = BN / 64;
    __shared__ __align__(16) unsigned short Ahi[2][64 * 32];
    __shared__ __align__(16) unsigned short Alo[2][64 * 32];
    __shared__ __align__(16) unsigned short Bhi[2][BN * 32];
    __shared__ __align__(16) unsigned short Blo[2][BN * 32];
    const int m0 = blockIdx.x * 64, n0 = blockIdx.y * BN;
    const int tid = threadIdx.x, lane = tid & 63, w = tid >> 6;
    const int stok = tid >> 2, sslot = tid & 3;

    f32x4 acc[4][CPW] = {};
    float4 av0, av1;
    uint4 bh4[CPW], bl4[CPW];

    auto loadStep = [&](int k0) {
        const float* src = A + (size_t)(m0 + stok) * KDIM + k0 + sslot * 8;
        av0 = *(const float4*)src;
        av1 = *(const float4*)(src + 4);
        #pragma unroll
        for (int c = 0; c < CPW; c++) {
            size_t soff = (size_t)(n0 + c * 64 + stok) * KDIM + k0 + sslot * 8;
            bh4[c] = *(const uint4*)(BThi + soff);
            bl4[c] = *(const uint4*)(BTlo + soff);
        }
    };
    auto writeStep = [&](int buf) {
        float xv[8] = {av0.x, av0.y, av0.z, av0.w, av1.x, av1.y, av1.z, av1.w};
        unsigned int hw[4], lw[4];
        #pragma unroll
        for (int j = 0; j < 4; j++) {
            unsigned short h0 = f2bf(xv[2*j]),   h1 = f2bf(xv[2*j+1]);
            unsigned short l0 = f2bf(xv[2*j] - bf2f(h0));
            unsigned short l1 = f2bf(xv[2*j+1] - bf2f(h1));
            hw[j] = (unsigned)h0 | ((unsigned)h1 << 16);
            lw[j] = (unsigned)l0 | ((unsigned)l1 << 16);
        }
        int doffA = stok * 32 + (sslot ^ ((stok >> 1) & 3)) * 8;
        *(uint4*)&Ahi[buf][doffA] = make_uint4(hw[0], hw[1], hw[2], hw[3]);
        *(uint4*)&Alo[buf][doffA] = make_uint4(lw[0], lw[1], lw[2], lw[3]);
        #pragma unroll
        for (int c = 0; c < CPW; c++) {
            int col = c * 64 + stok;
            int doffB = col * 32 + (sslot ^ ((col >> 1) & 3)) * 8;
            *(uint4*)&Bhi[buf][doffB] = bh4[c];
            *(uint4*)&Blo[buf][doffB] = bl4[c];
        }
    };

    loadStep(0); writeStep(0); __syncthreads();
    const int NT = KDIM / 32;
    for (int t = 0; t < NT; t++) {
        const int cur = t & 1;
        if (t + 1 < NT) loadStep((t + 1) * 32);
        const int fr = lane & 15, fs = lane >> 4;
        s16x8 ah[4], al[4];
        #pragma unroll
        for (int tm = 0; tm < 4; tm++) {
            int tok = tm * 16 + fr;
            int off = tok * 32 + (fs ^ ((tok >> 1) & 3)) * 8;
            ah[tm] = *(const s16x8*)&Ahi[cur][off];
            al[tm] = *(const s16x8*)&Alo[cur][off];
        }
        #pragma unroll
        for (int n = 0; n < CPW; n++) {
            int col = w * (16 * CPW) + n * 16 + fr;
            int boff = col * 32 + (fs ^ ((col >> 1) & 3)) * 8;
            s16x8 bh = *(const s16x8*)&Bhi[cur][boff];
            s16x8 bl = *(const s16x8*)&Blo[cur][boff];
            #pragma unroll
            for (int tm = 0; tm < 4; tm++) {
                acc[tm][n] = __builtin_amdgcn_mfma_f32_16x16x32_bf16(ah[tm], bh, acc[tm][n], 0, 0, 0);
                acc[tm][n] = __builtin_amdgcn_mfma_f32_16x16x32_bf16(ah[tm], bl, acc[tm][n], 0, 0, 0);
                acc[tm][n] = __builtin_amdgcn_mfma_f32_16x16x32_bf16(al[tm], bh, acc[tm][n], 0, 0, 0);
            }
        }
        if (t + 1 < NT) writeStep(cur ^ 1);
        __syncthreads();
    }
    const int fr = lane & 15, fg = lane >> 4;
    #pragma unroll
    for (int n = 0; n < CPW; n++) {
        const int col = n0 + w * (16 * CPW) + n * 16 + fr;
        const float bb = bias[col];
        #pragma unroll
        for (int tm = 0; tm < 4; tm++) {
            #pragma unroll
            for (int r = 0; r < 4; r++) {
                int row = m0 + tm * 16 + fg * 4 + r;
                out[(size_t)row * NSTRIDE + col] = acc[tm][n][r] + bb;
            }
        }
    }
}

// ---------------- fp32 proj (fallback only) ----------------
__global__ __launch_bounds__(256) void proj_gemm(const float* __restrict__ X,
                                                 const float* __restrict__ W,
                                                 const float* __restrict__ bias,
                                                 float* __restrict__ out) {
    __shared__ float As[32][66];
    __shared__ float Bs[32][64];
    const int m0 = blockIdx.x * 64, n0 = blockIdx.y * 64;
    const int tid = threadIdx.x;
    const int tx = tid & 15, ty = tid >> 4;
    float acc[4][4] = {};
    for (int k0 = 0; k0 < DE; k0 += 32) {
        {
            int e = tid;
            int r = e >> 3, c4 = e & 7;
            float4 v = *(const float4*)(X + (size_t)(m0 + r) * DE + k0 + c4 * 4);
            As[c4*4+0][r] = v.x; As[c4*4+1][r] = v.y; As[c4*4+2][r] = v.z; As[c4*4+3][r] = v.w;
            e = tid + 256;
            r = e >> 3; c4 = e & 7;
            v = *(const float4*)(X + (size_t)(m0 + r) * DE + k0 + c4 * 4);
            As[c4*4+0][r] = v.x; As[c4*4+1][r] = v.y; As[c4*4+2][r] = v.z; As[c4*4+3][r] = v.w;
        }
        {
            int e = tid;
            int kk = e >> 4, c4 = e & 15;
            *(float4*)&Bs[kk][c4*4] = *(const float4*)(W + (size_t)(k0 + kk) * DQ + n0 + c4 * 4);
            e = tid + 256;
            kk = e >> 4; c4 = e & 15;
            *(float4*)&Bs[kk][c4*4] = *(const float4*)(W + (size_t)(k0 + kk) * DQ + n0 + c4 * 4);
        }
        __syncthreads();
        #pragma unroll
        for (int k = 0; k < 32; k++) {
            float2 a01 = *(const float2*)&As[k][ty * 4];
            float2 a23 = *(const float2*)&As[k][ty * 4 + 2];
            float4 b = *(const float4*)&Bs[k][tx * 4];
            float av[4] = {a01.x, a01.y, a23.x, a23.y};
            float bv[4] = {b.x, b.y, b.z, b.w};
            #pragma unroll
            for (int i = 0; i < 4; i++)
                #pragma unroll
                for (int j = 0; j < 4; j++)
                    acc[i][j] += av[i] * bv[j];
        }
        __syncthreads();
    }
    float4 bv4 = *(const float4*)(bias + n0 + tx * 4);
    float bb[4] = {bv4.x, bv4.y, bv4.z, bv4.w};
    #pragma unroll
    for (int i = 0; i < 4; i++) {
        int row = m0 + ty * 4 + i;
        float4 o;
        o.x = acc[i][0] + bb[0];
        o.y = acc[i][1] + bb[1];
        o.z = acc[i][2] + bb[2];
        o.w = acc[i][3] + bb[3];
        *(float4*)(out + (size_t)row * DQ + n0 + tx * 4) = o;
    }
}

// ---------------- LayerNorm (in place) + routing + fused bf16 emit ----------------
__global__ __launch_bounds__(256) void ln_route(float* __restrict__ xp,
                                                const float* __restrict__ g,
                                                const float* __restrict__ b,
                                                const float* __restrict__ logits,
                                                float* __restrict__ score,
                                                int* __restrict__ mask,
                                                unsigned short* __restrict__ xpB) {
    int row = blockIdx.x * 4 + (threadIdx.x >> 6);
    int lane = threadIdx.x & 63;
    float* p = xp + (size_t)row * DQ;
    float4 v0 = *(float4*)(p + lane * 4);
    float4 v1 = *(float4*)(p + 256 + lane * 4);
    float s  = v0.x + v0.y + v0.z + v0.w + v1.x + v1.y + v1.z + v1.w;
    float ss = v0.x*v0.x + v0.y*v0.y + v0.z*v0.z + v0.w*v0.w
             + v1.x*v1.x + v1.y*v1.y + v1.z*v1.z + v1.w*v1.w;
    s = wave_reduce_sum(s);
    ss = wave_reduce_sum(ss);
    float m = s * (1.f / DQ);
    float var = ss * (1.f / DQ) - m * m;
    float scale = rsqrtf(var + 1e-5f);
    float4 g0 = *(const float4*)(g + lane * 4);
    float4 g1 = *(const float4*)(g + 256 + lane * 4);
    float4 b0 = *(const float4*)(b + lane * 4);
    float4 b1 = *(const float4*)(b + 256 + lane * 4);
    float4 o0, o1;
    o0.x = (v0.x - m) * scale * g0.x + b0.x;
    o0.y = (v0.y - m) * scale * g0.y + b0.y;
    o0.z = (v0.z - m) * scale * g0.z + b0.z;
    o0.w = (v0.w - m) * scale * g0.w + b0.w;
    o1.x = (v1.x - m) * scale * g1.x + b1.x;
    o1.y = (v1.y - m) * scale * g1.y + b1.y;
    o1.z = (v1.z - m) * scale * g1.z + b1.z;
    o1.w = (v1.w - m) * scale * g1.w + b1.w;
    *(float4*)(p + lane * 4) = o0;
    *(float4*)(p + 256 + lane * 4) = o1;
    if (xpB) {
        unsigned short* dst = xpB + (size_t)row * DQ;
        ushort4 h0, h1;
        h0.x = f2bf(o0.x); h0.y = f2bf(o0.y); h0.z = f2bf(o0.z); h0.w = f2bf(o0.w);
        h1.x = f2bf(o1.x); h1.y = f2bf(o1.y); h1.z = f2bf(o1.z); h1.w = f2bf(o1.w);
        *(ushort4*)(dst + lane * 4) = h0;
        *(ushort4*)(dst + 256 + lane * 4) = h1;
    }
    if (lane == 0) {
        float lg = logits[row];
        float sc = 1.f / (1.f + expf(-lg));
        score[row] = sc;
        mask[row] = sc > 0.6f ? 1 : 0;
    }
}

// ---------------- deterministic compaction (1024 threads) ----------------
__global__ __launch_bounds__(1024) void scan_compact(const int* __restrict__ mask,
                                                     int* __restrict__ hlist,
                                                     int* __restrict__ llist,
                                                     int* __restrict__ counts) {
    __shared__ int wsum[16];
    __shared__ int base_h, base_l;
    int tid = threadIdx.x, lane = tid & 63, wid = tid >> 6;
    if (tid == 0) { base_h = 0; base_l = 0; }
    __syncthreads();
    for (int t0 = 0; t0 < T_TOK; t0 += 1024) {
        int t = t0 + tid;
        int valid = t < T_TOK;
        int m = valid ? mask[t] : 0;
        unsigned long long bal = __ballot(m);
        int pre = __popcll(bal & ((1ull << lane) - 1ull));
        if (lane == 0) wsum[wid] = __popcll(bal);
        __syncthreads();
        int woff = 0;
        for (int w = 0; w < wid; w++) woff += wsum[w];
        int btot = 0;
        for (int w = 0; w < 16; w++) btot += wsum[w];
        int vcnt = T_TOK - t0; if (vcnt > 1024) vcnt = 1024;
        int bh = base_h, bl = base_l;
        if (valid) {
            if (m) hlist[bh + woff + pre] = t;
            else   llist[bl + (tid - (woff + pre))] = t;
        }
        __syncthreads();
        if (tid == 0) { base_h = bh + btot; base_l = bl + (vcnt - btot); }
        __syncthreads();
    }
    if (tid == 0) { counts[0] = base_h; counts[1] = base_l; }
}

// ---------------- merged MFMA approx-score VQ: 32-token tiles for 2x concurrency ----------------
// Per-token scores bit-identical to the 64-token version (MFMA is element-exact
// per output row; tile grouping does not change any token's dot products).
__global__ __launch_bounds__(256) void vq_mfma_all(const unsigned short* __restrict__ xpB,
                                                   const unsigned short* __restrict__ cbhB,
                                                   const float* __restrict__ cs2h,
                                                   const int* __restrict__ hlist,
                                                   const unsigned short* __restrict__ cblB,
                                                   const float* __restrict__ cs2l,
                                                   const int* __restrict__ llist,
                                                   const int* __restrict__ counts,
                                                   float* __restrict__ smaxH,
                                                   int* __restrict__ scntH,
                                                   uint2* __restrict__ candH,
                                                   float* __restrict__ smaxL,
                                                   int* __restrict__ scntL,
                                                   uint2* __restrict__ candL) {
    const int by = blockIdx.y;
    const unsigned short* cbB; const float* cs2; const int* list;
    float* smax; int* scnt; uint2* cand;
    int count, slice, SPLIT;
    if (by < SPL_H) {
        cbB = cbhB; cs2 = cs2h; list = hlist; count = counts[0];
        slice = by; SPLIT = SPL_H; smax = smaxH; scnt = scntH; cand = candH;
    } else {
        cbB = cblB; cs2 = cs2l; list = llist; count = counts[1];
        slice = 0; SPLIT = 1; smax = smaxL; scnt = scntL; cand = candL;
    }
    const int base = blockIdx.x * VQTOK;
    if (base >= count) return;
    const int cbase = slice * CODES_PER_BLK;

    __shared__ __align__(16) unsigned short Abuf[VQTOK * 32];     // 2 KB
    __shared__ __align__(16) unsigned short Bbuf[256 * 32];       // 16 KB
    __shared__ float wmaxs[4][VQTOK];
    __shared__ float tokmax[VQTOK];
    __shared__ int ccnt[VQTOK];
    __shared__ uint2 cland[VQTOK][CAND_CAP];
    __shared__ int rows_s[VQTOK];

    const int tid = threadIdx.x;
    const int lane = tid & 63;
    const int w = tid >> 6;
    const int stok = tid >> 2, sslot = tid & 3;

    if (tid < VQTOK) {
        int tl = base + tid;
        rows_s[tid] = list[tl < count ? tl : (count - 1)];
        ccnt[tid] = 0;
    }
    __syncthreads();

    // per-lane pre-swizzled global source pointers (elem units)
    const int swz = sslot ^ ((stok >> 1) & 3);
    const unsigned short* gA  = xpB + (size_t)rows_s[stok & (VQTOK - 1)] * DQ + swz * 8;
    const unsigned short* gB0 = cbB + (size_t)(cbase + 0 * 64 + stok) * DQ + swz * 8;
    const unsigned short* gB1 = cbB + (size_t)(cbase + 1 * 64 + stok) * DQ + swz * 8;
    const unsigned short* gB2 = cbB + (size_t)(cbase + 2 * 64 + stok) * DQ + swz * 8;
    const unsigned short* gB3 = cbB + (size_t)(cbase + 3 * 64 + stok) * DQ + swz * 8;
    // wave-uniform LDS dest bases (elem units); HW adds lane*16B
    unsigned short* dA = Abuf + w * 512;          // only waves 0,1 (stok<32)
    unsigned short* dB = Bbuf + w * 512;

    f32x4 acc[2][4] = {};

    const int NT = DQ / 32;                // 16
    for (int t = 0; t < NT; t++) {
        const int k0 = t * 32;
        if (w < 2) gload_lds16(gA + k0, dA);      // wave-uniform branch
        gload_lds16(gB0 + k0, dB + 0 * 2048);
        gload_lds16(gB1 + k0, dB + 1 * 2048);
        gload_lds16(gB2 + k0, dB + 2 * 2048);
        gload_lds16(gB3 + k0, dB + 3 * 2048);
        __syncthreads();                   // drains loads: tiles ready
        const int fr = lane & 15, fs = lane >> 4;
        s16x8 af[2], bf[4];
        #pragma unroll
        for (int tm = 0; tm < 2; tm++) {
            int tok = tm * 16 + fr;
            af[tm] = *(const s16x8*)&Abuf[tok * 32 + (fs ^ ((tok >> 1) & 3)) * 8];
        }
        #pragma unroll
        for (int tn = 0; tn < 4; tn++) {
            int cl = w * 64 + tn * 16 + fr;
            bf[tn] = *(const s16x8*)&Bbuf[cl * 32 + (fs ^ ((cl >> 1) & 3)) * 8];
        }
        #pragma unroll
        for (int tm = 0; tm < 2; tm++)
            #pragma unroll
            for (int tn = 0; tn < 4; tn++)
                acc[tm][tn] = __builtin_amdgcn_mfma_f32_16x16x32_bf16(af[tm], bf[tn], acc[tm][tn], 0, 0, 0);
        __syncthreads();                   // seals reads before next overwrite
    }

    const int fr = lane & 15, fg = lane >> 4;
    float c2[4];
    #pragma unroll
    for (int tn = 0; tn < 4; tn++) c2[tn] = 0.5f * cs2[cbase + w * 64 + tn * 16 + fr];

    #pragma unroll
    for (int tm = 0; tm < 2; tm++) {
        #pragma unroll
        for (int r = 0; r < 4; r++) {
            float m4 = -3.0e38f;
            #pragma unroll
            for (int tn = 0; tn < 4; tn++) {
                float s = acc[tm][tn][r] - c2[tn];
                m4 = fmaxf(m4, s);
            }
            #pragma unroll
            for (int off = 1; off < 16; off <<= 1)
                m4 = fmaxf(m4, __shfl_xor(m4, off));
            if (fr == 0) wmaxs[w][tm * 16 + fg * 4 + r] = m4;
        }
    }
    __syncthreads();
    if (tid < VQTOK)
        tokmax[tid] = fmaxf(fmaxf(wmaxs[0][tid], wmaxs[1][tid]),
                            fmaxf(wmaxs[2][tid], wmaxs[3][tid]));
    __syncthreads();

    #pragma unroll
    for (int tm = 0; tm < 2; tm++) {
        #pragma unroll
        for (int r = 0; r < 4; r++) {
            int token = tm * 16 + fg * 4 + r;
            float thr = tokmax[token] - MARGIN;
            #pragma unroll
            for (int tn = 0; tn < 4; tn++) {
                float s = acc[tm][tn][r] - c2[tn];
                if (s > thr) {
                    int pos = atomicAdd(&ccnt[token], 1);
                    if (pos < CAND_CAP) {
                        uint2 cd;
                        cd.x = __float_as_uint(s);
                        cd.y = (unsigned)(cbase + w * 64 + tn * 16 + fr);
                        cland[token][pos] = cd;
                    }
                }
            }
        }
    }
    __syncthreads();

    if (tid < VQTOK) {
        int tl = base + tid;
        if (tl < count) {
            smax[(size_t)tl * SPLIT + slice] = tokmax[tid];
            scnt[(size_t)tl * SPLIT + slice] = min(ccnt[tid], CAND_CAP);
        }
    }
    for (int i = tid; i < VQTOK * CAND_CAP; i += 256) {
        int token = i >> 4, j = i & (CAND_CAP - 1);
        int tl = base + token;
        if (tl < count && j < min(ccnt[token], CAND_CAP))
            cand[((size_t)tl * SPLIT + slice) * CAND_CAP + j] = cland[token][j];
    }
}

// ---------------- merged exact fp64 rescore + FUSED gather/loss/y ----------------
__global__ __launch_bounds__(256) void vq_rescore_all(float* __restrict__ xp,
                                                      const float* __restrict__ cb_h,
                                                      const float* __restrict__ smaxH,
                                                      const int* __restrict__ scntH,
                                                      const uint2* __restrict__ candH,
                                                      const int* __restrict__ hlist,
                                                      const float* __restrict__ cb_l,
                                                      const float* __restrict__ smaxL,
                                                      const int* __restrict__ scntL,
                                                      const uint2* __restrict__ candL,
                                                      const int* __restrict__ llist,
                                                      const int* __restrict__ counts,
                                                      int* __restrict__ out_idx,
                                                      const float* __restrict__ noise,
                                                      const float* __restrict__ h_ri,
                                                      const float* __restrict__ score,
                                                      float* __restrict__ lh,
                                                      float* __restrict__ ll) {
    const int HB = T_TOK / 4;
    int bx = blockIdx.x;
    const float* cb; const float* smax; const int* scnt; const uint2* cand; const int* list;
    int count, SPLIT, cidx;
    if (bx < HB) {
        cb = cb_h; smax = smaxH; scnt = scntH; cand = candH; list = hlist;
        count = counts[0]; SPLIT = SPL_H; cidx = 0;
    } else {
        bx -= HB;
        cb = cb_l; smax = smaxL; scnt = scntL; cand = candL; list = llist;
        count = counts[1]; SPLIT = 1; cidx = 1;
    }
    const int wid = threadIdx.x >> 6;
    const int lane = threadIdx.x & 63;
    const int tl = bx * 4 + wid;
    if (tl >= count) return;

    float gm = -3.0e38f;
    if (lane < SPLIT) gm = smax[(size_t)tl * SPLIT + lane];
    #pragma unroll
    for (int off = 1; off < 64; off <<= 1)
        gm = fmaxf(gm, __shfl_xor(gm, off));
    const float thr = gm - MARGIN;

    const int t = list[tl];
    float xv[8];
    #pragma unroll
    for (int kk = 0; kk < 8; kk++) xv[kk] = xp[(size_t)t * DQ + lane * 8 + kk];

    double bs = -1.0e300;
    int bi = 0x7fffffff;
    for (int s = 0; s < SPLIT; s++) {
        int cn = scnt[(size_t)tl * SPLIT + s];
        for (int j = 0; j < cn; j++) {
            uint2 cd = cand[((size_t)tl * SPLIT + s) * CAND_CAP + j];
            float av = __uint_as_float(cd.x);
            if (av >= thr) {
                int code = (int)cd.y;
                const float* crow = cb + (size_t)code * DQ;
                double dot = 0.0, nrm = 0.0;
                #pragma unroll
                for (int kk = 0; kk < 8; kk++) {
                    double cv = (double)crow[lane * 8 + kk];
                    dot += (double)xv[kk] * cv;
                    nrm += cv * cv;
                }
                #pragma unroll
                for (int off = 1; off < 64; off <<= 1) {
                    dot += __shfl_xor(dot, off);
                    nrm += __shfl_xor(nrm, off);
                }
                double sc = dot - 0.5 * nrm;
                if (sc > bs || (sc == bs && code < bi)) { bs = sc; bi = code; }
            }
        }
    }
    const float* qrow = cb + (size_t)bi * DQ;
    float4 q0 = *(const float4*)(qrow + lane * 8);
    float4 q1 = *(const float4*)(qrow + lane * 8 + 4);
    const float* nz = noise + (size_t)t * DQ;
    float4 n0 = *(const float4*)(nz + lane * 8);
    float4 n1 = *(const float4*)(nz + lane * 8 + 4);
    float ds = 0.f, dx;
    dx = xv[0] - q0.x; ds += dx * dx;
    dx = xv[1] - q0.y; ds += dx * dx;
    dx = xv[2] - q0.z; ds += dx * dx;
    dx = xv[3] - q0.w; ds += dx * dx;
    dx = xv[4] - q1.x; ds += dx * dx;
    dx = xv[5] - q1.y; ds += dx * dx;
    dx = xv[6] - q1.z; ds += dx * dx;
    dx = xv[7] - q1.w; ds += dx * dx;
    ds = wave_reduce_sum(ds);
    int bbt = t / SEQ;
    float hh0 = h_ri[bbt * 2], hh1 = h_ri[bbt * 2 + 1];
    float hh = sqrtf((hh0 * hh0 + hh1 * hh1) * 0.5f);
    float cc = sqrtf(1e-3f) / hh;
    float4 y0, y1;
    y0.x = q0.x + cc * n0.x; y0.y = q0.y + cc * n0.y;
    y0.z = q0.z + cc * n0.z; y0.w = q0.w + cc * n0.w;
    y1.x = q1.x + cc * n1.x; y1.y = q1.y + cc * n1.y;
    y1.z = q1.z + cc * n1.z; y1.w = q1.w + cc * n1.w;
    *(float4*)(xp + (size_t)t * DQ + lane * 8) = y0;
    *(float4*)(xp + (size_t)t * DQ + lane * 8 + 4) = y1;
    if (lane == 0) {
        out_idx[t] = bi;
        float loss = 1.25f * ds * (1.f / DQ);
        float sc = score[t];
        if (cidx == 0) { lh[t] = loss * sc;  ll[t] = 0.f; }
        else           { lh[t] = 0.f;        ll[t] = loss * (1.f - sc); }
    }
}

// ---------------- FALLBACK fp32 VQ (unchanged) ----------------
template<int NC, int SPLIT>
__global__ __launch_bounds__(256) void vq_partial(const float* __restrict__ xp,
                                                  const float* __restrict__ cb,
                                                  const float* __restrict__ cs2,
                                                  const int* __restrict__ list,
                                                  const int* __restrict__ counts,
                                                  int cidx,
                                                  float* __restrict__ part_s,
                                                  int* __restrict__ part_i) {
    const int count = counts[cidx];
    const int base = blockIdx.x * 64;
    if (base >= count) return;
    const int CODES = NC / SPLIT;
    const int cbase = blockIdx.y * CODES;
    __shared__ float As[32][68];
    __shared__ float Cs[32][68];
    __shared__ int rows_s[64];
    const int tid = threadIdx.x;
    if (tid < 64) {
        int tl = base + tid;
        rows_s[tid] = list[tl < count ? tl : (count - 1)];
    }
    __syncthreads();
    const int tx = tid & 15, ty = tid >> 4;
    float best_s[4];
    int best_i[4];
    #pragma unroll
    for (int i = 0; i < 4; i++) { best_s[i] = -3.0e38f; best_i[i] = 0; }
    for (int c0 = cbase; c0 < cbase + CODES; c0 += 64) {
        float acc[4][4] = {};
        for (int k0 = 0; k0 < DQ; k0 += 32) {
            {
                int e = tid;
                int r = e >> 3, c4 = e & 7;
                float4 v = *(const float4*)(xp + (size_t)rows_s[r] * DQ + k0 + c4 * 4);
                As[c4*4+0][r] = v.x; As[c4*4+1][r] = v.y; As[c4*4+2][r] = v.z; As[c4*4+3][r] = v.w;
                e = tid + 256; r = e >> 3; c4 = e & 7;
                v = *(const float4*)(xp + (size_t)rows_s[r] * DQ + k0 + c4 * 4);
                As[c4*4+0][r] = v.x; As[c4*4+1][r] = v.y; As[c4*4+2][r] = v.z; As[c4*4+3][r] = v.w;
            }
            {
                int e = tid;
                int r = e >> 3, c4 = e & 7;
                float4 v = *(const float4*)(cb + (size_t)(c0 + r) * DQ + k0 + c4 * 4);
                Cs[c4*4+0][r] = v.x; Cs[c4*4+1][r] = v.y; Cs[c4*4+2][r] = v.z; Cs[c4*4+3][r] = v.w;
                e = tid + 256; r = e >> 3; c4 = e & 7;
                v = *(const float4*)(cb + (size_t)(c0 + r) * DQ + k0 + c4 * 4);
                Cs[c4*4+0][r] = v.x; Cs[c4*4+1][r] = v.y; Cs[c4*4+2][r] = v.z; Cs[c4*4+3][r] = v.w;
            }
            __syncthreads();
            #pragma unroll
            for (int k = 0; k < 32; k++) {
                float4 a = *(const float4*)&As[k][ty * 4];
                float4 b = *(const float4*)&Cs[k][tx * 4];
                float av[4] = {a.x, a.y, a.z, a.w};
                float bv[4] = {b.x, b.y, b.z, b.w};
                #pragma unroll
                for (int i = 0; i < 4; i++)
                    #pragma unroll
                    for (int j = 0; j < 4; j++)
                        acc[i][j] += av[i] * bv[j];
            }
            __syncthreads();
        }
        float4 c2v = *(const float4*)(cs2 + c0 + tx * 4);
        float c2[4] = {c2v.x, c2v.y, c2v.z, c2v.w};
        #pragma unroll
        for (int i = 0; i < 4; i++) {
            float s = acc[i][0] - 0.5f * c2[0];
            int bi = c0 + tx * 4;
            #pragma unroll
            for (int j = 1; j < 4; j++) {
                float sj = acc[i][j] - 0.5f * c2[j];
                if (sj > s) { s = sj; bi = c0 + tx * 4 + j; }
            }
            #pragma unroll
            for (int off = 1; off < 16; off <<= 1) {
                float os = __shfl_xor(s, off);
                int oi = __shfl_xor(bi, off);
                if (os > s || (os == s && oi < bi)) { s = os; bi = oi; }
            }
            if (s > best_s[i] || (s == best_s[i] && bi < best_i[i])) {
                best_s[i] = s; best_i[i] = bi;
            }
        }
    }
    if (tx == 0) {
        #pragma unroll
        for (int i = 0; i < 4; i++) {
            int tl = base + ty * 4 + i;
            if (tl < count) {
                part_s[(size_t)tl * SPLIT + blockIdx.y] = best_s[i];
                part_i[(size_t)tl * SPLIT + blockIdx.y] = best_i[i];
            }
        }
    }
}

template<int SPLIT>
__global__ __launch_bounds__(256) void vq_reduce(const float* __restrict__ part_s,
                                                 const int* __restrict__ part_i,
                                                 const int* __restrict__ list,
                                                 const int* __restrict__ counts,
                                                 int cidx,
                                                 int* __restrict__ out_idx) {
    int tl = blockIdx.x * 256 + threadIdx.x;
    if (tl >= counts[cidx]) return;
    float bs = part_s[(size_t)tl * SPLIT];
    int bi = part_i[(size_t)tl * SPLIT];
    #pragma unroll
    for (int s = 1; s < SPLIT; s++) {
        float v = part_s[(size_t)tl * SPLIT + s];
        int vi = part_i[(size_t)tl * SPLIT + s];
        if (v > bs || (v == bs && vi < bi)) { bs = v; bi = vi; }
    }
    out_idx[list[tl]] = bi;
}

// ---------------- gather q, per-token loss, y (fallback path only) ----------------
__global__ __launch_bounds__(256) void gather_loss_y(float* __restrict__ xp,
                                                     const float* __restrict__ cb_h,
                                                     const float* __restrict__ cb_l,
                                                     const int* __restrict__ idx,
                                                     const float* __restrict__ score,
                                                     const int* __restrict__ mask,
                                                     const float* __restrict__ noise,
                                                     const float* __restrict__ h_ri,
                                                     float* __restrict__ lh,
                                                     float* __restrict__ ll) {
    int t = blockIdx.x * 4 + (threadIdx.x >> 6);
    int lane = threadIdx.x & 63;
    int m = mask[t];
    float sc = score[t];
    const float* q = (m ? cb_h : cb_l) + (size_t)idx[t] * DQ;
    float* x = xp + (size_t)t * DQ;
    const float* nz = noise + (size_t)t * DQ;
    int bb = t / SEQ;
    float h0 = h_ri[bb * 2], h1 = h_ri[bb * 2 + 1];
    float h = sqrtf((h0 * h0 + h1 * h1) * 0.5f);
    float c = sqrtf(1e-3f) / h;
    float4 xv0 = *(float4*)(x + lane * 4);
    float4 xv1 = *(float4*)(x + 256 + lane * 4);
    float4 qv0 = *(const float4*)(q + lane * 4);
    float4 qv1 = *(const float4*)(q + 256 + lane * 4);
    float4 nv0 = *(const float4*)(nz + lane * 4);
    float4 nv1 = *(const float4*)(nz + 256 + lane * 4);
    float dx, ds = 0.f;
    dx = xv0.x - qv0.x; ds += dx * dx;
    dx = xv0.y - qv0.y; ds += dx * dx;
    dx = xv0.z - qv0.z; ds += dx * dx;
    dx = xv0.w - qv0.w; ds += dx * dx;
    dx = xv1.x - qv1.x; ds += dx * dx;
    dx = xv1.y - qv1.y; ds += dx * dx;
    dx = xv1.z - qv1.z; ds += dx * dx;
    dx = xv1.w - qv1.w; ds += dx * dx;
    ds = wave_reduce_sum(ds);
    float4 y0, y1;
    y0.x = qv0.x + c * nv0.x; y0.y = qv0.y + c * nv0.y;
    y0.z = qv0.z + c * nv0.z; y0.w = qv0.w + c * nv0.w;
    y1.x = qv1.x + c * nv1.x; y1.y = qv1.y + c * nv1.y;
    y1.z = qv1.z + c * nv1.z; y1.w = qv1.w + c * nv1.w;
    *(float4*)(x + lane * 4) = y0;
    *(float4*)(x + 256 + lane * 4) = y1;
    if (lane == 0) {
        float loss = 1.25f * ds * (1.f / DQ);
        lh[t] = m ? loss * sc : 0.f;
        ll[t] = m ? 0.f : loss * (1.f - sc);
    }
}

// ---------------- deterministic loss reduction (unchanged) ----------------
__global__ __launch_bounds__(256) void loss_reduce(const float* __restrict__ lh,
                                                   const float* __restrict__ ll,
                                                   const int* __restrict__ counts,
                                                   float* __restrict__ out) {
    __shared__ float sh[256], sl[256];
    int tid = threadIdx.x;
    float ah = 0.f, al = 0.f;
    for (int t = tid; t < T_TOK; t += 256) { ah += lh[t]; al += ll[t]; }
    sh[tid] = ah; sl[tid] = al;
    __syncthreads();
    for (int o = 128; o > 0; o >>= 1) {
        if (tid < o) { sh[tid] += sh[tid + o]; sl[tid] += sl[tid + o]; }
        __syncthreads();
    }
    if (tid == 0) {
        int nh = counts[0];
        int nl = T_TOK - nh;
        nh = nh > 1 ? nh : 1;
        nl = nl > 1 ? nl : 1;
        out[(size_t)T_TOK * DD] = 0.5f * (sh[0] / (float)nh + sl[0] / (float)nl);
    }
}

// ---------------- fp32 dec (fallback only) ----------------
__global__ __launch_bounds__(256) void dec_gemm(const float* __restrict__ Y,
                                                const float* __restrict__ W,
                                                const float* __restrict__ bias,
                                                float* __restrict__ out) {
    __shared__ float As[32][66];
    __shared__ float Bs[32][64];
    const int m0 = blockIdx.x * 64, n0 = blockIdx.y * 64;
    const int tid = threadIdx.x;
    const int tx = tid & 15, ty = tid >> 4;
    float acc[4][4] = {};
    for (int k0 = 0; k0 < DQ; k0 += 32) {
        {
            int e = tid;
            int r = e >> 3, c4 = e & 7;
            float4 v = *(const float4*)(Y + (size_t)(m0 + r) * DQ + k0 + c4 * 4);
            As[c4*4+0][r] = v.x; As[c4*4+1][r] = v.y; As[c4*4+2][r] = v.z; As[c4*4+3][r] = v.w;
            e = tid + 256; r = e >> 3; c4 = e & 7;
            v = *(const float4*)(Y + (size_t)(m0 + r) * DQ + k0 + c4 * 4);
            As[c4*4+0][r] = v.x; As[c4*4+1][r] = v.y; As[c4*4+2][r] = v.z; As[c4*4+3][r] = v.w;
        }
        {
            int e = tid;
            int kk = e >> 4, c4 = e & 15;
            *(float4*)&Bs[kk][c4*4] = *(const float4*)(W + (size_t)(k0 + kk) * DD + n0 + c4 * 4);
            e = tid + 256; kk = e >> 4; c4 = e & 15;
            *(float4*)&Bs[kk][c4*4] = *(const float4*)(W + (size_t)(k0 + kk) * DD + n0 + c4 * 4);
        }
        __syncthreads();
        #pragma unroll
        for (int k = 0; k < 32; k++) {
            float2 a01 = *(const float2*)&As[k][ty * 4];
            float2 a23 = *(const float2*)&As[k][ty * 4 + 2];
            float4 b = *(const float4*)&Bs[k][tx * 4];
            float av[4] = {a01.x, a01.y, a23.x, a23.y};
            float bv[4] = {b.x, b.y, b.z, b.w};
            #pragma unroll
            for (int i = 0; i < 4; i++)
                #pragma unroll
                for (int j = 0; j < 4; j++)
                    acc[i][j] += av[i] * bv[j];
        }
        __syncthreads();
    }
    float4 bv4 = *(const float4*)(bias + n0 + tx * 4);
    float bbv[4] = {bv4.x, bv4.y, bv4.z, bv4.w};
    #pragma unroll
    for (int i = 0; i < 4; i++) {
        int row = m0 + ty * 4 + i;
        float4 o;
        o.x = acc[i][0] + bbv[0];
        o.y = acc[i][1] + bbv[1];
        o.z = acc[i][2] + bbv[2];
        o.w = acc[i][3] + bbv[3];
        *(float4*)(out + (size_t)row * DD + n0 + tx * 4) = o;
    }
}

extern "C" void kernel_launch(void* const* d_in, const int* in_sizes, int n_in,
                              void* d_out, int out_size, void* d_ws, size_t ws_size,
                              hipStream_t stream) {
    const float* x_tokens = (const float*)d_in[0];
    const float* fim      = (const float*)d_in[1];
    const float* W_proj   = (const float*)d_in[2];
    const float* b_proj   = (const float*)d_in[3];
    const float* ln_g     = (const float*)d_in[4];
    const float* ln_b     = (const float*)d_in[5];
    const float* cb_high  = (const float*)d_in[6];
    const float* cb_low   = (const float*)d_in[7];
    const float* W_dec    = (const float*)d_in[8];
    const float* b_dec    = (const float*)d_in[9];
    const float* h_ri     = (const float*)d_in[10];
    const float* noise    = (const float*)d_in[11];
    float* out = (float*)d_out;

    char* ws = (char*)d_ws;
    size_t off = 0;
    float* xp = (float*)(ws + off);     off += (size_t)T_TOK * DQ * 4;
    int*   idxb = (int*)(ws + off);     off += (size_t)T_TOK * 4;
    float* score = (float*)(ws + off);  off += (size_t)T_TOK * 4;
    int*   mask = (int*)(ws + off);     off += (size_t)T_TOK * 4;
    float* lh = (float*)(ws + off);     off += (size_t)T_TOK * 4;
    float* ll = (float*)(ws + off);     off += (size_t)T_TOK * 4;
    int*   hlist = (int*)(ws + off);    off += (size_t)T_TOK * 4;
    int*   llist = (int*)(ws + off);    off += (size_t)T_TOK * 4;
    int*   counts = (int*)(ws + off);   off += 64;
    float* cs2h = (float*)(ws + off);   off += (size_t)NCH * 4;
    float* cs2l = (float*)(ws + off);   off += (size_t)NCL * 4;
    size_t off_common = off;

    unsigned short* xpB  = (unsigned short*)(ws + off); off += (size_t)T_TOK * DQ * 2;
    unsigned short* cbhB = (unsigned short*)(ws + off); off += (size_t)NCH * DQ * 2;
    unsigned short* cblB = (unsigned short*)(ws + off); off += (size_t)NCL * DQ * 2;
    float* smaxH = (float*)(ws + off);  off += (size_t)T_TOK * SPL_H * 4;
    int*   scntH = (int*)(ws + off);    off += (size_t)T_TOK * SPL_H * 4;
    uint2* candH = (uint2*)(ws + off);  off += (size_t)T_TOK * SPL_H * CAND_CAP * 8;
    float* smaxL = (float*)(ws + off);  off += (size_t)T_TOK * 4;
    int*   scntL = (int*)(ws + off);    off += (size_t)T_TOK * 4;
    uint2* candL = (uint2*)(ws + off);  off += (size_t)T_TOK * CAND_CAP * 8;
    unsigned short* WThi  = (unsigned short*)(ws + off); off += (size_t)DQ * DE * 2;
    unsigned short* WTlo  = (unsigned short*)(ws + off); off += (size_t)DQ * DE * 2;
    unsigned short* WdThi = (unsigned short*)(ws + off); off += (size_t)DD * DQ * 2;
    unsigned short* WdTlo = (unsigned short*)(ws + off); off += (size_t)DD * DQ * 2;
    size_t need_new = off;
    const bool use_mfma = ws_size >= need_new;

    if (use_mfma) {
        prep_all<<<1856, 256, 0, stream>>>(cb_high, cs2h, cbhB, cb_low, cs2l, cblB,
                                           W_proj, WThi, WTlo, W_dec, WdThi, WdTlo);
        gemm_mfma3<DE, DQ, 64><<<dim3(T_TOK / 64, DQ / 64), 256, 0, stream>>>(
            x_tokens, WThi, WTlo, b_proj, xp);
        ln_route<<<T_TOK / 4, 256, 0, stream>>>(xp, ln_g, ln_b, fim, score, mask, xpB);
        scan_compact<<<1, 1024, 0, stream>>>(mask, hlist, llist, counts);
        vq_mfma_all<<<dim3(T_TOK / VQTOK, SPL_H + 1), 256, 0, stream>>>(
            xpB, cbhB, cs2h, hlist, cblB, cs2l, llist, counts,
            smaxH, scntH, candH, smaxL, scntL, candL);
        vq_rescore_all<<<2 * (T_TOK / 4), 256, 0, stream>>>(
            xp, cb_high, smaxH, scntH, candH, hlist,
            cb_low, smaxL, scntL, candL, llist,
            counts, idxb, noise, h_ri, score, lh, ll);
        loss_reduce<<<1, 256, 0, stream>>>(lh, ll, counts, out);
        gemm_mfma3<DQ, DD, 64><<<dim3(T_TOK / 64, DD / 64), 256, 0, stream>>>(
            xp, WdThi, WdTlo, b_dec, out);
    } else {
        code_sumsq<NCH><<<NCH / 4, 256, 0, stream>>>(cb_high, cs2h);
        code_sumsq<NCL><<<NCL / 4, 256, 0, stream>>>(cb_low, cs2l);
        proj_gemm<<<dim3(T_TOK / 64, DQ / 64), 256, 0, stream>>>(x_tokens, W_proj, b_proj, xp);
        ln_route<<<T_TOK / 4, 256, 0, stream>>>(xp, ln_g, ln_b, fim, score, mask, nullptr);
        scan_compact<<<1, 1024, 0, stream>>>(mask, hlist, llist, counts);
        float* part_s = (float*)(ws + off_common);
        int*   part_i = (int*)(ws + off_common + (size_t)T_TOK * 16 * 4);
        vq_partial<NCH, 16><<<dim3(T_TOK / 64, 16), 256, 0, stream>>>(
            xp, cb_high, cs2h, hlist, counts, 0, part_s, part_i);
        vq_reduce<16><<<(T_TOK + 255) / 256, 256, 0, stream>>>(part_s, part_i, hlist, counts, 0, idxb);
        vq_partial<NCL, 4><<<dim3(T_TOK / 64, 4), 256, 0, stream>>>(
            xp, cb_low, cs2l, llist, counts, 1, part_s, part_i);
        vq_reduce<4><<<(T_TOK + 255) / 256, 256, 0, stream>>>(part_s, part_i, llist, counts, 1, idxb);
        gather_loss_y<<<T_TOK / 4, 256, 0, stream>>>(xp, cb_high, cb_low, idxb, score, mask,
                                                     noise, h_ri, lh, ll);
        loss_reduce<<<1, 256, 0, stream>>>(lh, ll, counts, out);
        dec_gemm<<<dim3(T_TOK / 64, DD / 64), 256, 0, stream>>>(xp, W_dec, b_dec, out);
    }
}

// Round 23
// 211.730 us; speedup vs baseline: 1.0373x; 1.0373x over previous
//
#include <hip/hip_runtime.h>
#include <math.h>

#define T_TOK 12544   // 64*196
#define DE 768
#define DQ 512
#define DD 256
#define SEQ 196
#define NCH 4096
#define NCL 256
#define SPL_H 16      // high codebook: 16 slices of 256 codes
#define CODES_PER_BLK 256
#define MARGIN 2.0f
#define CAND_CAP 16
#define VQTOK 32      // tokens per vq block

typedef __attribute__((ext_vector_type(8))) short s16x8;
typedef __attribute__((ext_vector_type(4))) float f32x4;

__device__ __forceinline__ float wave_reduce_sum(float v) {
    #pragma unroll
    for (int off = 32; off > 0; off >>= 1) v += __shfl_xor(v, off);
    return v;
}

__device__ __forceinline__ unsigned short f2bf(float f) {
    unsigned int u = __float_as_uint(f);
    u = (u + 0x7fffu + ((u >> 16) & 1u)) >> 16;
    return (unsigned short)u;
}
__device__ __forceinline__ float bf2f(unsigned short h) {
    return __uint_as_float(((unsigned int)h) << 16);
}

// async global->LDS 16B: dest = wave-uniform base + lane*16 (pre-swizzled source)
__device__ __forceinline__ void gload_lds16(const unsigned short* g, unsigned short* l) {
    __builtin_amdgcn_global_load_lds(
        (const __attribute__((address_space(1))) void*)g,
        (__attribute__((address_space(3))) void*)l,
        16, 0, 0);
}

// ---------------- device helpers for merged preprocessing ----------------
__device__ __forceinline__ void sumsq_body(const float* __restrict__ cb,
                                           float* __restrict__ cs2,
                                           unsigned short* __restrict__ cbB,
                                           int blk, int NC) {
    int row = blk * 4 + (threadIdx.x >> 6);
    int lane = threadIdx.x & 63;
    if (row >= NC) return;
    const float4* p = (const float4*)(cb + (size_t)row * DQ);
    float4 a = p[lane];
    float4 b = p[lane + 64];
    if (cbB) {
        unsigned short* dst = cbB + (size_t)row * DQ;
        ushort4 ha, hb;
        ha.x = f2bf(a.x); ha.y = f2bf(a.y); ha.z = f2bf(a.z); ha.w = f2bf(a.w);
        hb.x = f2bf(b.x); hb.y = f2bf(b.y); hb.z = f2bf(b.z); hb.w = f2bf(b.w);
        *(ushort4*)(dst + lane * 4) = ha;
        *(ushort4*)(dst + 256 + lane * 4) = hb;
    }
    float s = a.x*a.x + a.y*a.y + a.z*a.z + a.w*a.w
            + b.x*b.x + b.y*b.y + b.z*b.z + b.w*b.w;
    s = wave_reduce_sum(s);
    if (lane == 0) cs2[row] = s;
}

__device__ __forceinline__ void split_body(const float* __restrict__ W, int K, int N,
                                           unsigned short* __restrict__ Thi,
                                           unsigned short* __restrict__ Tlo,
                                           int blk, int nb) {
    int total = K * N;
    for (int idx = blk * 256 + threadIdx.x; idx < total; idx += nb * 256) {
        int n = idx / K, k = idx - n * K;
        float v = W[(size_t)k * N + n];
        unsigned short h = f2bf(v);
        Thi[idx] = h;
        Tlo[idx] = f2bf(v - bf2f(h));
    }
}

// ---------------- merged preprocessing: sumsq(H,L) + splitW(proj,dec) ----------------
__global__ __launch_bounds__(256) void prep_all(const float* __restrict__ cb_h,
                                                float* __restrict__ cs2h,
                                                unsigned short* __restrict__ cbhB,
                                                const float* __restrict__ cb_l,
                                                float* __restrict__ cs2l,
                                                unsigned short* __restrict__ cblB,
                                                const float* __restrict__ Wp,
                                                unsigned short* __restrict__ WThi,
                                                unsigned short* __restrict__ WTlo,
                                                const float* __restrict__ Wd,
                                                unsigned short* __restrict__ WdThi,
                                                unsigned short* __restrict__ WdTlo) {
    int blk = blockIdx.x;
    if (blk < 1024)       sumsq_body(cb_h, cs2h, cbhB, blk, NCH);
    else if (blk < 1088)  sumsq_body(cb_l, cs2l, cblB, blk - 1024, NCL);
    else if (blk < 1600)  split_body(Wp, DE, DQ, WThi, WTlo, blk - 1088, 512);
    else                  split_body(Wd, DQ, DD, WdThi, WdTlo, blk - 1600, 256);
}

// ---------------- fallback code_sumsq (fp32 path only) ----------------
template<int NC>
__global__ __launch_bounds__(256) void code_sumsq(const float* __restrict__ cb,
                                                  float* __restrict__ cs2) {
    sumsq_body(cb, cs2, nullptr, blockIdx.x, NC);
}

// ---------------- proj via 3-term split-bf16 MFMA, 128x128 tile ----------------
// m93/m97 ladder step: 4 waves x (64x64 quadrant, 4x4 frags), BK=32, single-buffer
// 32KB LDS. B staged via global_load_lds (pre-swizzled global source, zero VGPR),
// A reg-staged with on-the-fly f32->bf16 hi/lo split. Per-element accumulation
// chain identical to the 64x64 kernel -> outputs bit-identical.
template<int KDIM, int NSTRIDE>
__global__ __launch_bounds__(256) void gemm_mfma3_128(const float* __restrict__ A,
                                                      const unsigned short* __restrict__ BThi,
                                                      const unsigned short* __restrict__ BTlo,
                                                      const float* __restrict__ bias,
                                                      float* __restrict__ out) {
    __shared__ __align__(16) unsigned short Ahi[128 * 32];
    __shared__ __align__(16) unsigned short Alo[128 * 32];
    __shared__ __align__(16) unsigned short Bhi[128 * 32];
    __shared__ __align__(16) unsigned short Blo[128 * 32];
    const int m0 = blockIdx.x * 128, n0 = blockIdx.y * 128;
    const int tid = threadIdx.x, lane = tid & 63, w = tid >> 6;
    const int wr = w >> 1, wc = w & 1;
    const int arow = tid >> 1, ahalf = tid & 1;

    // B per-lane pre-swizzled global sources: wave w stages colblocks 2w, 2w+1
    // (16 cols x 32 k each = one 1KB wave-instruction per buffer type).
    const int cb0 = w * 2, cb1 = w * 2 + 1;
    const int gcol0 = n0 + cb0 * 16 + (lane >> 2);
    const int gcol1 = n0 + cb1 * 16 + (lane >> 2);
    const int ch0 = (lane & 3) ^ ((gcol0 >> 1) & 3);
    const int ch1 = (lane & 3) ^ ((gcol1 >> 1) & 3);
    const unsigned short* sH0 = BThi + (size_t)gcol0 * KDIM + ch0 * 8;
    const unsigned short* sH1 = BThi + (size_t)gcol1 * KDIM + ch1 * 8;
    const unsigned short* sL0 = BTlo + (size_t)gcol0 * KDIM + ch0 * 8;
    const unsigned short* sL1 = BTlo + (size_t)gcol1 * KDIM + ch1 * 8;

    f32x4 acc[4][4] = {};
    const int NT = KDIM / 32;
    for (int t = 0; t < NT; t++) {
        const int k0 = t * 32;
        gload_lds16(sH0 + k0, Bhi + cb0 * 512);
        gload_lds16(sH1 + k0, Bhi + cb1 * 512);
        gload_lds16(sL0 + k0, Blo + cb0 * 512);
        gload_lds16(sL1 + k0, Blo + cb1 * 512);
        {
            const float* src = A + (size_t)(m0 + arow) * KDIM + k0 + ahalf * 16;
            float4 v0 = *(const float4*)(src + 0);
            float4 v1 = *(const float4*)(src + 4);
            float4 v2 = *(const float4*)(src + 8);
            float4 v3 = *(const float4*)(src + 12);
            float xv[16] = {v0.x,v0.y,v0.z,v0.w, v1.x,v1.y,v1.z,v1.w,
                            v2.x,v2.y,v2.z,v2.w, v3.x,v3.y,v3.z,v3.w};
            const int swzA = (arow >> 1) & 3;
            #pragma unroll
            for (int cc = 0; cc < 2; cc++) {
                unsigned int hw[4], lw[4];
                #pragma unroll
                for (int j = 0; j < 4; j++) {
                    float f0 = xv[cc*8 + 2*j], f1 = xv[cc*8 + 2*j + 1];
                    unsigned short h0 = f2bf(f0), h1 = f2bf(f1);
                    unsigned short l0 = f2bf(f0 - bf2f(h0));
                    unsigned short l1 = f2bf(f1 - bf2f(h1));
                    hw[j] = (unsigned)h0 | ((unsigned)h1 << 16);
                    lw[j] = (unsigned)l0 | ((unsigned)l1 << 16);
                }
                int c = ahalf * 2 + cc;
                int doff = arow * 32 + (c ^ swzA) * 8;
                *(uint4*)&Ahi[doff] = make_uint4(hw[0], hw[1], hw[2], hw[3]);
                *(uint4*)&Alo[doff] = make_uint4(lw[0], lw[1], lw[2], lw[3]);
            }
        }
        __syncthreads();     // drains gload vmcnt + A ds_writes
        const int fr = lane & 15, fs = lane >> 4;
        s16x8 ah[4], al[4];
        #pragma unroll
        for (int tm = 0; tm < 4; tm++) {
            int row = wr * 64 + tm * 16 + fr;
            int off = row * 32 + (fs ^ ((row >> 1) & 3)) * 8;
            ah[tm] = *(const s16x8*)&Ahi[off];
            al[tm] = *(const s16x8*)&Alo[off];
        }
        #pragma unroll
        for (int tn = 0; tn < 4; tn++) {
            int col = wc * 64 + tn * 16 + fr;
            int boff = col * 32 + (fs ^ ((col >> 1) & 3)) * 8;
            s16x8 bh = *(const s16x8*)&Bhi[boff];
            s16x8 bl = *(const s16x8*)&Blo[boff];
            #pragma unroll
            for (int tm = 0; tm < 4; tm++) {
                acc[tm][tn] = __builtin_amdgcn_mfma_f32_16x16x32_bf16(ah[tm], bh, acc[tm][tn], 0, 0, 0);
                acc[tm][tn] = __builtin_amdgcn_mfma_f32_16x16x32_bf16(ah[tm], bl, acc[tm][tn], 0, 0, 0);
                acc[tm][tn] = __builtin_amdgcn_mfma_f32_16x16x32_bf16(al[tm], bh, acc[tm][tn], 0, 0, 0);
            }
        }
        __syncthreads();     // seal reads before next overwrite
    }
    const int fr = lane & 15, fg = lane >> 4;
    #pragma unroll
    for (int tn = 0; tn < 4; tn++) {
        const int col = n0 + wc * 64 + tn * 16 + fr;
        const float bb = bias[col];
        #pragma unroll
        for (int tm = 0; tm < 4; tm++) {
            #pragma unroll
            for (int r = 0; r < 4; r++) {
                int row = m0 + wr * 64 + tm * 16 + fg * 4 + r;
                out[(size_t)row * NSTRIDE + col] = acc[tm][tn][r] + bb;
            }
        }
    }
}

// ---------------- dec via 3-term split-bf16 MFMA, 64x64 (proven, VGPR 44) ----------------
template<int KDIM, int NSTRIDE, int BN>
__global__ __launch_bounds__(256) void gemm_mfma3(const float* __restrict__ A,
                                                  const unsigned short* __restrict__ BThi,
                                                  const unsigned short* __restrict__ BTlo,
                                                  const float* __restrict__ bias,
                                                  float* __restrict__ out) {
    constexpr int CPW = BN / 64;
    __shared__ __align__(16) unsigned short Ahi[2][64 * 32];
    __shared__ __align__(16) unsigned short Alo[2][64 * 32];
    __shared__ __align__(16) unsigned short Bhi[2][BN * 32];
    __shared__ __align__(16) unsigned short Blo[2][BN * 32];
    const int m0 = blockIdx.x * 64, n0 = blockIdx.y * BN;
    const int tid = threadIdx.x, lane = tid & 63, w = tid >> 6;
    const int stok = tid >> 2, sslot = tid & 3;

    f32x4 acc[4][CPW] = {};
    float4 av0, av1;
    uint4 bh4[CPW], bl4[CPW];

    auto loadStep = [&](int k0) {
        const float* src = A + (size_t)(m0 + stok) * KDIM + k0 + sslot * 8;
        av0 = *(const float4*)src;
        av1 = *(const float4*)(src + 4);
        #pragma unroll
        for (int c = 0; c < CPW; c++) {
            size_t soff = (size_t)(n0 + c * 64 + stok) * KDIM + k0 + sslot * 8;
            bh4[c] = *(const uint4*)(BThi + soff);
            bl4[c] = *(const uint4*)(BTlo + soff);
        }
    };
    auto writeStep = [&](int buf) {
        float xv[8] = {av0.x, av0.y, av0.z, av0.w, av1.x, av1.y, av1.z, av1.w};
        unsigned int hw[4], lw[4];
        #pragma unroll
        for (int j = 0; j < 4; j++) {
            unsigned short h0 = f2bf(xv[2*j]),   h1 = f2bf(xv[2*j+1]);
            unsigned short l0 = f2bf(xv[2*j] - bf2f(h0));
            unsigned short l1 = f2bf(xv[2*j+1] - bf2f(h1));
            hw[j] = (unsigned)h0 | ((unsigned)h1 << 16);
            lw[j] = (unsigned)l0 | ((unsigned)l1 << 16);
        }
        int doffA = stok * 32 + (sslot ^ ((stok >> 1) & 3)) * 8;
        *(uint4*)&Ahi[buf][doffA] = make_uint4(hw[0], hw[1], hw[2], hw[3]);
        *(uint4*)&Alo[buf][doffA] = make_uint4(lw[0], lw[1], lw[2], lw[3]);
        #pragma unroll
        for (int c = 0; c < CPW; c++) {
            int col = c * 64 + stok;
            int doffB = col * 32 + (sslot ^ ((col >> 1) & 3)) * 8;
            *(uint4*)&Bhi[buf][doffB] = bh4[c];
            *(uint4*)&Blo[buf][doffB] = bl4[c];
        }
    };

    loadStep(0); writeStep(0); __syncthreads();
    const int NT = KDIM / 32;
    for (int t = 0; t < NT; t++) {
        const int cur = t & 1;
        if (t + 1 < NT) loadStep((t + 1) * 32);
        const int fr = lane & 15, fs = lane >> 4;
        s16x8 ah[4], al[4];
        #pragma unroll
        for (int tm = 0; tm < 4; tm++) {
            int tok = tm * 16 + fr;
            int off = tok * 32 + (fs ^ ((tok >> 1) & 3)) * 8;
            ah[tm] = *(const s16x8*)&Ahi[cur][off];
            al[tm] = *(const s16x8*)&Alo[cur][off];
        }
        #pragma unroll
        for (int n = 0; n < CPW; n++) {
            int col = w * (16 * CPW) + n * 16 + fr;
            int boff = col * 32 + (fs ^ ((col >> 1) & 3)) * 8;
            s16x8 bh = *(const s16x8*)&Bhi[cur][boff];
            s16x8 bl = *(const s16x8*)&Blo[cur][boff];
            #pragma unroll
            for (int tm = 0; tm < 4; tm++) {
                acc[tm][n] = __builtin_amdgcn_mfma_f32_16x16x32_bf16(ah[tm], bh, acc[tm][n], 0, 0, 0);
                acc[tm][n] = __builtin_amdgcn_mfma_f32_16x16x32_bf16(ah[tm], bl, acc[tm][n], 0, 0, 0);
                acc[tm][n] = __builtin_amdgcn_mfma_f32_16x16x32_bf16(al[tm], bh, acc[tm][n], 0, 0, 0);
            }
        }
        if (t + 1 < NT) writeStep(cur ^ 1);
        __syncthreads();
    }
    const int fr = lane & 15, fg = lane >> 4;
    #pragma unroll
    for (int n = 0; n < CPW; n++) {
        const int col = n0 + w * (16 * CPW) + n * 16 + fr;
        const float bb = bias[col];
        #pragma unroll
        for (int tm = 0; tm < 4; tm++) {
            #pragma unroll
            for (int r = 0; r < 4; r++) {
                int row = m0 + tm * 16 + fg * 4 + r;
                out[(size_t)row * NSTRIDE + col] = acc[tm][n][r] + bb;
            }
        }
    }
}

// ---------------- fp32 proj (fallback only) ----------------
__global__ __launch_bounds__(256) void proj_gemm(const float* __restrict__ X,
                                                 const float* __restrict__ W,
                                                 const float* __restrict__ bias,
                                                 float* __restrict__ out) {
    __shared__ float As[32][66];
    __shared__ float Bs[32][64];
    const int m0 = blockIdx.x * 64, n0 = blockIdx.y * 64;
    const int tid = threadIdx.x;
    const int tx = tid & 15, ty = tid >> 4;
    float acc[4][4] = {};
    for (int k0 = 0; k0 < DE; k0 += 32) {
        {
            int e = tid;
            int r = e >> 3, c4 = e & 7;
            float4 v = *(const float4*)(X + (size_t)(m0 + r) * DE + k0 + c4 * 4);
            As[c4*4+0][r] = v.x; As[c4*4+1][r] = v.y; As[c4*4+2][r] = v.z; As[c4*4+3][r] = v.w;
            e = tid + 256;
            r = e >> 3; c4 = e & 7;
            v = *(const float4*)(X + (size_t)(m0 + r) * DE + k0 + c4 * 4);
            As[c4*4+0][r] = v.x; As[c4*4+1][r] = v.y; As[c4*4+2][r] = v.z; As[c4*4+3][r] = v.w;
        }
        {
            int e = tid;
            int kk = e >> 4, c4 = e & 15;
            *(float4*)&Bs[kk][c4*4] = *(const float4*)(W + (size_t)(k0 + kk) * DQ + n0 + c4 * 4);
            e = tid + 256;
            kk = e >> 4; c4 = e & 15;
            *(float4*)&Bs[kk][c4*4] = *(const float4*)(W + (size_t)(k0 + kk) * DQ + n0 + c4 * 4);
        }
        __syncthreads();
        #pragma unroll
        for (int k = 0; k < 32; k++) {
            float2 a01 = *(const float2*)&As[k][ty * 4];
            float2 a23 = *(const float2*)&As[k][ty * 4 + 2];
            float4 b = *(const float4*)&Bs[k][tx * 4];
            float av[4] = {a01.x, a01.y, a23.x, a23.y};
            float bv[4] = {b.x, b.y, b.z, b.w};
            #pragma unroll
            for (int i = 0; i < 4; i++)
                #pragma unroll
                for (int j = 0; j < 4; j++)
                    acc[i][j] += av[i] * bv[j];
        }
        __syncthreads();
    }
    float4 bv4 = *(const float4*)(bias + n0 + tx * 4);
    float bb[4] = {bv4.x, bv4.y, bv4.z, bv4.w};
    #pragma unroll
    for (int i = 0; i < 4; i++) {
        int row = m0 + ty * 4 + i;
        float4 o;
        o.x = acc[i][0] + bb[0];
        o.y = acc[i][1] + bb[1];
        o.z = acc[i][2] + bb[2];
        o.w = acc[i][3] + bb[3];
        *(float4*)(out + (size_t)row * DQ + n0 + tx * 4) = o;
    }
}

// ---------------- LayerNorm (in place) + routing + fused bf16 emit ----------------
__global__ __launch_bounds__(256) void ln_route(float* __restrict__ xp,
                                                const float* __restrict__ g,
                                                const float* __restrict__ b,
                                                const float* __restrict__ logits,
                                                float* __restrict__ score,
                                                int* __restrict__ mask,
                                                unsigned short* __restrict__ xpB) {
    int row = blockIdx.x * 4 + (threadIdx.x >> 6);
    int lane = threadIdx.x & 63;
    float* p = xp + (size_t)row * DQ;
    float4 v0 = *(float4*)(p + lane * 4);
    float4 v1 = *(float4*)(p + 256 + lane * 4);
    float s  = v0.x + v0.y + v0.z + v0.w + v1.x + v1.y + v1.z + v1.w;
    float ss = v0.x*v0.x + v0.y*v0.y + v0.z*v0.z + v0.w*v0.w
             + v1.x*v1.x + v1.y*v1.y + v1.z*v1.z + v1.w*v1.w;
    s = wave_reduce_sum(s);
    ss = wave_reduce_sum(ss);
    float m = s * (1.f / DQ);
    float var = ss * (1.f / DQ) - m * m;
    float scale = rsqrtf(var + 1e-5f);
    float4 g0 = *(const float4*)(g + lane * 4);
    float4 g1 = *(const float4*)(g + 256 + lane * 4);
    float4 b0 = *(const float4*)(b + lane * 4);
    float4 b1 = *(const float4*)(b + 256 + lane * 4);
    float4 o0, o1;
    o0.x = (v0.x - m) * scale * g0.x + b0.x;
    o0.y = (v0.y - m) * scale * g0.y + b0.y;
    o0.z = (v0.z - m) * scale * g0.z + b0.z;
    o0.w = (v0.w - m) * scale * g0.w + b0.w;
    o1.x = (v1.x - m) * scale * g1.x + b1.x;
    o1.y = (v1.y - m) * scale * g1.y + b1.y;
    o1.z = (v1.z - m) * scale * g1.z + b1.z;
    o1.w = (v1.w - m) * scale * g1.w + b1.w;
    *(float4*)(p + lane * 4) = o0;
    *(float4*)(p + 256 + lane * 4) = o1;
    if (xpB) {
        unsigned short* dst = xpB + (size_t)row * DQ;
        ushort4 h0, h1;
        h0.x = f2bf(o0.x); h0.y = f2bf(o0.y); h0.z = f2bf(o0.z); h0.w = f2bf(o0.w);
        h1.x = f2bf(o1.x); h1.y = f2bf(o1.y); h1.z = f2bf(o1.z); h1.w = f2bf(o1.w);
        *(ushort4*)(dst + lane * 4) = h0;
        *(ushort4*)(dst + 256 + lane * 4) = h1;
    }
    if (lane == 0) {
        float lg = logits[row];
        float sc = 1.f / (1.f + expf(-lg));
        score[row] = sc;
        mask[row] = sc > 0.6f ? 1 : 0;
    }
}

// ---------------- deterministic compaction (1024 threads) ----------------
__global__ __launch_bounds__(1024) void scan_compact(const int* __restrict__ mask,
                                                     int* __restrict__ hlist,
                                                     int* __restrict__ llist,
                                                     int* __restrict__ counts) {
    __shared__ int wsum[16];
    __shared__ int base_h, base_l;
    int tid = threadIdx.x, lane = tid & 63, wid = tid >> 6;
    if (tid == 0) { base_h = 0; base_l = 0; }
    __syncthreads();
    for (int t0 = 0; t0 < T_TOK; t0 += 1024) {
        int t = t0 + tid;
        int valid = t < T_TOK;
        int m = valid ? mask[t] : 0;
        unsigned long long bal = __ballot(m);
        int pre = __popcll(bal & ((1ull << lane) - 1ull));
        if (lane == 0) wsum[wid] = __popcll(bal);
        __syncthreads();
        int woff = 0;
        for (int w = 0; w < wid; w++) woff += wsum[w];
        int btot = 0;
        for (int w = 0; w < 16; w++) btot += wsum[w];
        int vcnt = T_TOK - t0; if (vcnt > 1024) vcnt = 1024;
        int bh = base_h, bl = base_l;
        if (valid) {
            if (m) hlist[bh + woff + pre] = t;
            else   llist[bl + (tid - (woff + pre))] = t;
        }
        __syncthreads();
        if (tid == 0) { base_h = bh + btot; base_l = bl + (vcnt - btot); }
        __syncthreads();
    }
    if (tid == 0) { counts[0] = base_h; counts[1] = base_l; }
}

// ---------------- merged MFMA approx-score VQ: 32-token tiles (r22 structure) ----------------
__global__ __launch_bounds__(256) void vq_mfma_all(const unsigned short* __restrict__ xpB,
                                                   const unsigned short* __restrict__ cbhB,
                                                   const float* __restrict__ cs2h,
                                                   const int* __restrict__ hlist,
                                                   const unsigned short* __restrict__ cblB,
                                                   const float* __restrict__ cs2l,
                                                   const int* __restrict__ llist,
                                                   const int* __restrict__ counts,
                                                   float* __restrict__ smaxH,
                                                   int* __restrict__ scntH,
                                                   uint2* __restrict__ candH,
                                                   float* __restrict__ smaxL,
                                                   int* __restrict__ scntL,
                                                   uint2* __restrict__ candL) {
    const int by = blockIdx.y;
    const unsigned short* cbB; const float* cs2; const int* list;
    float* smax; int* scnt; uint2* cand;
    int count, slice, SPLIT;
    if (by < SPL_H) {
        cbB = cbhB; cs2 = cs2h; list = hlist; count = counts[0];
        slice = by; SPLIT = SPL_H; smax = smaxH; scnt = scntH; cand = candH;
    } else {
        cbB = cblB; cs2 = cs2l; list = llist; count = counts[1];
        slice = 0; SPLIT = 1; smax = smaxL; scnt = scntL; cand = candL;
    }
    const int base = blockIdx.x * VQTOK;
    if (base >= count) return;
    const int cbase = slice * CODES_PER_BLK;

    __shared__ __align__(16) unsigned short Abuf[VQTOK * 32];     // 2 KB
    __shared__ __align__(16) unsigned short Bbuf[256 * 32];       // 16 KB
    __shared__ float wmaxs[4][VQTOK];
    __shared__ float tokmax[VQTOK];
    __shared__ int ccnt[VQTOK];
    __shared__ uint2 cland[VQTOK][CAND_CAP];
    __shared__ int rows_s[VQTOK];

    const int tid = threadIdx.x;
    const int lane = tid & 63;
    const int w = tid >> 6;
    const int stok = tid >> 2, sslot = tid & 3;

    if (tid < VQTOK) {
        int tl = base + tid;
        rows_s[tid] = list[tl < count ? tl : (count - 1)];
        ccnt[tid] = 0;
    }
    __syncthreads();

    const int swz = sslot ^ ((stok >> 1) & 3);
    const unsigned short* gA  = xpB + (size_t)rows_s[stok & (VQTOK - 1)] * DQ + swz * 8;
    const unsigned short* gB0 = cbB + (size_t)(cbase + 0 * 64 + stok) * DQ + swz * 8;
    const unsigned short* gB1 = cbB + (size_t)(cbase + 1 * 64 + stok) * DQ + swz * 8;
    const unsigned short* gB2 = cbB + (size_t)(cbase + 2 * 64 + stok) * DQ + swz * 8;
    const unsigned short* gB3 = cbB + (size_t)(cbase + 3 * 64 + stok) * DQ + swz * 8;
    unsigned short* dA = Abuf + w * 512;
    unsigned short* dB = Bbuf + w * 512;

    f32x4 acc[2][4] = {};

    const int NT = DQ / 32;
    for (int t = 0; t < NT; t++) {
        const int k0 = t * 32;
        if (w < 2) gload_lds16(gA + k0, dA);
        gload_lds16(gB0 + k0, dB + 0 * 2048);
        gload_lds16(gB1 + k0, dB + 1 * 2048);
        gload_lds16(gB2 + k0, dB + 2 * 2048);
        gload_lds16(gB3 + k0, dB + 3 * 2048);
        __syncthreads();
        const int fr = lane & 15, fs = lane >> 4;
        s16x8 af[2], bf[4];
        #pragma unroll
        for (int tm = 0; tm < 2; tm++) {
            int tok = tm * 16 + fr;
            af[tm] = *(const s16x8*)&Abuf[tok * 32 + (fs ^ ((tok >> 1) & 3)) * 8];
        }
        #pragma unroll
        for (int tn = 0; tn < 4; tn++) {
            int cl = w * 64 + tn * 16 + fr;
            bf[tn] = *(const s16x8*)&Bbuf[cl * 32 + (fs ^ ((cl >> 1) & 3)) * 8];
        }
        #pragma unroll
        for (int tm = 0; tm < 2; tm++)
            #pragma unroll
            for (int tn = 0; tn < 4; tn++)
                acc[tm][tn] = __builtin_amdgcn_mfma_f32_16x16x32_bf16(af[tm], bf[tn], acc[tm][tn], 0, 0, 0);
        __syncthreads();
    }

    const int fr = lane & 15, fg = lane >> 4;
    float c2[4];
    #pragma unroll
    for (int tn = 0; tn < 4; tn++) c2[tn] = 0.5f * cs2[cbase + w * 64 + tn * 16 + fr];

    #pragma unroll
    for (int tm = 0; tm < 2; tm++) {
        #pragma unroll
        for (int r = 0; r < 4; r++) {
            float m4 = -3.0e38f;
            #pragma unroll
            for (int tn = 0; tn < 4; tn++) {
                float s = acc[tm][tn][r] - c2[tn];
                m4 = fmaxf(m4, s);
            }
            #pragma unroll
            for (int off = 1; off < 16; off <<= 1)
                m4 = fmaxf(m4, __shfl_xor(m4, off));
            if (fr == 0) wmaxs[w][tm * 16 + fg * 4 + r] = m4;
        }
    }
    __syncthreads();
    if (tid < VQTOK)
        tokmax[tid] = fmaxf(fmaxf(wmaxs[0][tid], wmaxs[1][tid]),
                            fmaxf(wmaxs[2][tid], wmaxs[3][tid]));
    __syncthreads();

    #pragma unroll
    for (int tm = 0; tm < 2; tm++) {
        #pragma unroll
        for (int r = 0; r < 4; r++) {
            int token = tm * 16 + fg * 4 + r;
            float thr = tokmax[token] - MARGIN;
            #pragma unroll
            for (int tn = 0; tn < 4; tn++) {
                float s = acc[tm][tn][r] - c2[tn];
                if (s > thr) {
                    int pos = atomicAdd(&ccnt[token], 1);
                    if (pos < CAND_CAP) {
                        uint2 cd;
                        cd.x = __float_as_uint(s);
                        cd.y = (unsigned)(cbase + w * 64 + tn * 16 + fr);
                        cland[token][pos] = cd;
                    }
                }
            }
        }
    }
    __syncthreads();

    if (tid < VQTOK) {
        int tl = base + tid;
        if (tl < count) {
            smax[(size_t)tl * SPLIT + slice] = tokmax[tid];
            scnt[(size_t)tl * SPLIT + slice] = min(ccnt[tid], CAND_CAP);
        }
    }
    for (int i = tid; i < VQTOK * CAND_CAP; i += 256) {
        int token = i >> 4, j = i & (CAND_CAP - 1);
        int tl = base + token;
        if (tl < count && j < min(ccnt[token], CAND_CAP))
            cand[((size_t)tl * SPLIT + slice) * CAND_CAP + j] = cland[token][j];
    }
}

// ---------------- merged exact fp64 rescore + FUSED gather/loss/y ----------------
__global__ __launch_bounds__(256) void vq_rescore_all(float* __restrict__ xp,
                                                      const float* __restrict__ cb_h,
                                                      const float* __restrict__ smaxH,
                                                      const int* __restrict__ scntH,
                                                      const uint2* __restrict__ candH,
                                                      const int* __restrict__ hlist,
                                                      const float* __restrict__ cb_l,
                                                      const float* __restrict__ smaxL,
                                                      const int* __restrict__ scntL,
                                                      const uint2* __restrict__ candL,
                                                      const int* __restrict__ llist,
                                                      const int* __restrict__ counts,
                                                      int* __restrict__ out_idx,
                                                      const float* __restrict__ noise,
                                                      const float* __restrict__ h_ri,
                                                      const float* __restrict__ score,
                                                      float* __restrict__ lh,
                                                      float* __restrict__ ll) {
    const int HB = T_TOK / 4;
    int bx = blockIdx.x;
    const float* cb; const float* smax; const int* scnt; const uint2* cand; const int* list;
    int count, SPLIT, cidx;
    if (bx < HB) {
        cb = cb_h; smax = smaxH; scnt = scntH; cand = candH; list = hlist;
        count = counts[0]; SPLIT = SPL_H; cidx = 0;
    } else {
        bx -= HB;
        cb = cb_l; smax = smaxL; scnt = scntL; cand = candL; list = llist;
        count = counts[1]; SPLIT = 1; cidx = 1;
    }
    const int wid = threadIdx.x >> 6;
    const int lane = threadIdx.x & 63;
    const int tl = bx * 4 + wid;
    if (tl >= count) return;

    float gm = -3.0e38f;
    if (lane < SPLIT) gm = smax[(size_t)tl * SPLIT + lane];
    #pragma unroll
    for (int off = 1; off < 64; off <<= 1)
        gm = fmaxf(gm, __shfl_xor(gm, off));
    const float thr = gm - MARGIN;

    const int t = list[tl];
    float xv[8];
    #pragma unroll
    for (int kk = 0; kk < 8; kk++) xv[kk] = xp[(size_t)t * DQ + lane * 8 + kk];

    double bs = -1.0e300;
    int bi = 0x7fffffff;
    for (int s = 0; s < SPLIT; s++) {
        int cn = scnt[(size_t)tl * SPLIT + s];
        for (int j = 0; j < cn; j++) {
            uint2 cd = cand[((size_t)tl * SPLIT + s) * CAND_CAP + j];
            float av = __uint_as_float(cd.x);
            if (av >= thr) {
                int code = (int)cd.y;
                const float* crow = cb + (size_t)code * DQ;
                double dot = 0.0, nrm = 0.0;
                #pragma unroll
                for (int kk = 0; kk < 8; kk++) {
                    double cv = (double)crow[lane * 8 + kk];
                    dot += (double)xv[kk] * cv;
                    nrm += cv * cv;
                }
                #pragma unroll
                for (int off = 1; off < 64; off <<= 1) {
                    dot += __shfl_xor(dot, off);
                    nrm += __shfl_xor(nrm, off);
                }
                double sc = dot - 0.5 * nrm;
                if (sc > bs || (sc == bs && code < bi)) { bs = sc; bi = code; }
            }
        }
    }
    const float* qrow = cb + (size_t)bi * DQ;
    float4 q0 = *(const float4*)(qrow + lane * 8);
    float4 q1 = *(const float4*)(qrow + lane * 8 + 4);
    const float* nz = noise + (size_t)t * DQ;
    float4 n0 = *(const float4*)(nz + lane * 8);
    float4 n1 = *(const float4*)(nz + lane * 8 + 4);
    float ds = 0.f, dx;
    dx = xv[0] - q0.x; ds += dx * dx;
    dx = xv[1] - q0.y; ds += dx * dx;
    dx = xv[2] - q0.z; ds += dx * dx;
    dx = xv[3] - q0.w; ds += dx * dx;
    dx = xv[4] - q1.x; ds += dx * dx;
    dx = xv[5] - q1.y; ds += dx * dx;
    dx = xv[6] - q1.z; ds += dx * dx;
    dx = xv[7] - q1.w; ds += dx * dx;
    ds = wave_reduce_sum(ds);
    int bbt = t / SEQ;
    float hh0 = h_ri[bbt * 2], hh1 = h_ri[bbt * 2 + 1];
    float hh = sqrtf((hh0 * hh0 + hh1 * hh1) * 0.5f);
    float cc = sqrtf(1e-3f) / hh;
    float4 y0, y1;
    y0.x = q0.x + cc * n0.x; y0.y = q0.y + cc * n0.y;
    y0.z = q0.z + cc * n0.z; y0.w = q0.w + cc * n0.w;
    y1.x = q1.x + cc * n1.x; y1.y = q1.y + cc * n1.y;
    y1.z = q1.z + cc * n1.z; y1.w = q1.w + cc * n1.w;
    *(float4*)(xp + (size_t)t * DQ + lane * 8) = y0;
    *(float4*)(xp + (size_t)t * DQ + lane * 8 + 4) = y1;
    if (lane == 0) {
        out_idx[t] = bi;
        float loss = 1.25f * ds * (1.f / DQ);
        float sc = score[t];
        if (cidx == 0) { lh[t] = loss * sc;  ll[t] = 0.f; }
        else           { lh[t] = 0.f;        ll[t] = loss * (1.f - sc); }
    }
}

// ---------------- FALLBACK fp32 VQ (unchanged) ----------------
template<int NC, int SPLIT>
__global__ __launch_bounds__(256) void vq_partial(const float* __restrict__ xp,
                                                  const float* __restrict__ cb,
                                                  const float* __restrict__ cs2,
                                                  const int* __restrict__ list,
                                                  const int* __restrict__ counts,
                                                  int cidx,
                                                  float* __restrict__ part_s,
                                                  int* __restrict__ part_i) {
    const int count = counts[cidx];
    const int base = blockIdx.x * 64;
    if (base >= count) return;
    const int CODES = NC / SPLIT;
    const int cbase = blockIdx.y * CODES;
    __shared__ float As[32][68];
    __shared__ float Cs[32][68];
    __shared__ int rows_s[64];
    const int tid = threadIdx.x;
    if (tid < 64) {
        int tl = base + tid;
        rows_s[tid] = list[tl < count ? tl : (count - 1)];
    }
    __syncthreads();
    const int tx = tid & 15, ty = tid >> 4;
    float best_s[4];
    int best_i[4];
    #pragma unroll
    for (int i = 0; i < 4; i++) { best_s[i] = -3.0e38f; best_i[i] = 0; }
    for (int c0 = cbase; c0 < cbase + CODES; c0 += 64) {
        float acc[4][4] = {};
        for (int k0 = 0; k0 < DQ; k0 += 32) {
            {
                int e = tid;
                int r = e >> 3, c4 = e & 7;
                float4 v = *(const float4*)(xp + (size_t)rows_s[r] * DQ + k0 + c4 * 4);
                As[c4*4+0][r] = v.x; As[c4*4+1][r] = v.y; As[c4*4+2][r] = v.z; As[c4*4+3][r] = v.w;
                e = tid + 256; r = e >> 3; c4 = e & 7;
                v = *(const float4*)(xp + (size_t)rows_s[r] * DQ + k0 + c4 * 4);
                As[c4*4+0][r] = v.x; As[c4*4+1][r] = v.y; As[c4*4+2][r] = v.z; As[c4*4+3][r] = v.w;
            }
            {
                int e = tid;
                int r = e >> 3, c4 = e & 7;
                float4 v = *(const float4*)(cb + (size_t)(c0 + r) * DQ + k0 + c4 * 4);
                Cs[c4*4+0][r] = v.x; Cs[c4*4+1][r] = v.y; Cs[c4*4+2][r] = v.z; Cs[c4*4+3][r] = v.w;
                e = tid + 256; r = e >> 3; c4 = e & 7;
                v = *(const float4*)(cb + (size_t)(c0 + r) * DQ + k0 + c4 * 4);
                Cs[c4*4+0][r] = v.x; Cs[c4*4+1][r] = v.y; Cs[c4*4+2][r] = v.z; Cs[c4*4+3][r] = v.w;
            }
            __syncthreads();
            #pragma unroll
            for (int k = 0; k < 32; k++) {
                float4 a = *(const float4*)&As[k][ty * 4];
                float4 b = *(const float4*)&Cs[k][tx * 4];
                float av[4] = {a.x, a.y, a.z, a.w};
                float bv[4] = {b.x, b.y, b.z, b.w};
                #pragma unroll
                for (int i = 0; i < 4; i++)
                    #pragma unroll
                    for (int j = 0; j < 4; j++)
                        acc[i][j] += av[i] * bv[j];
            }
            __syncthreads();
        }
        float4 c2v = *(const float4*)(cs2 + c0 + tx * 4);
        float c2[4] = {c2v.x, c2v.y, c2v.z, c2v.w};
        #pragma unroll
        for (int i = 0; i < 4; i++) {
            float s = acc[i][0] - 0.5f * c2[0];
            int bi = c0 + tx * 4;
            #pragma unroll
            for (int j = 1; j < 4; j++) {
                float sj = acc[i][j] - 0.5f * c2[j];
                if (sj > s) { s = sj; bi = c0 + tx * 4 + j; }
            }
            #pragma unroll
            for (int off = 1; off < 16; off <<= 1) {
                float os = __shfl_xor(s, off);
                int oi = __shfl_xor(bi, off);
                if (os > s || (os == s && oi < bi)) { s = os; bi = oi; }
            }
            if (s > best_s[i] || (s == best_s[i] && bi < best_i[i])) {
                best_s[i] = s; best_i[i] = bi;
            }
        }
    }
    if (tx == 0) {
        #pragma unroll
        for (int i = 0; i < 4; i++) {
            int tl = base + ty * 4 + i;
            if (tl < count) {
                part_s[(size_t)tl * SPLIT + blockIdx.y] = best_s[i];
                part_i[(size_t)tl * SPLIT + blockIdx.y] = best_i[i];
            }
        }
    }
}

template<int SPLIT>
__global__ __launch_bounds__(256) void vq_reduce(const float* __restrict__ part_s,
                                                 const int* __restrict__ part_i,
                                                 const int* __restrict__ list,
                                                 const int* __restrict__ counts,
                                                 int cidx,
                                                 int* __restrict__ out_idx) {
    int tl = blockIdx.x * 256 + threadIdx.x;
    if (tl >= counts[cidx]) return;
    float bs = part_s[(size_t)tl * SPLIT];
    int bi = part_i[(size_t)tl * SPLIT];
    #pragma unroll
    for (int s = 1; s < SPLIT; s++) {
        float v = part_s[(size_t)tl * SPLIT + s];
        int vi = part_i[(size_t)tl * SPLIT + s];
        if (v > bs || (v == bs && vi < bi)) { bs = v; bi = vi; }
    }
    out_idx[list[tl]] = bi;
}

// ---------------- gather q, per-token loss, y (fallback path only) ----------------
__global__ __launch_bounds__(256) void gather_loss_y(float* __restrict__ xp,
                                                     const float* __restrict__ cb_h,
                                                     const float* __restrict__ cb_l,
                                                     const int* __restrict__ idx,
                                                     const float* __restrict__ score,
                                                     const int* __restrict__ mask,
                                                     const float* __restrict__ noise,
                                                     const float* __restrict__ h_ri,
                                                     float* __restrict__ lh,
                                                     float* __restrict__ ll) {
    int t = blockIdx.x * 4 + (threadIdx.x >> 6);
    int lane = threadIdx.x & 63;
    int m = mask[t];
    float sc = score[t];
    const float* q = (m ? cb_h : cb_l) + (size_t)idx[t] * DQ;
    float* x = xp + (size_t)t * DQ;
    const float* nz = noise + (size_t)t * DQ;
    int bb = t / SEQ;
    float h0 = h_ri[bb * 2], h1 = h_ri[bb * 2 + 1];
    float h = sqrtf((h0 * h0 + h1 * h1) * 0.5f);
    float c = sqrtf(1e-3f) / h;
    float4 xv0 = *(float4*)(x + lane * 4);
    float4 xv1 = *(float4*)(x + 256 + lane * 4);
    float4 qv0 = *(const float4*)(q + lane * 4);
    float4 qv1 = *(const float4*)(q + 256 + lane * 4);
    float4 nv0 = *(const float4*)(nz + lane * 4);
    float4 nv1 = *(const float4*)(nz + 256 + lane * 4);
    float dx, ds = 0.f;
    dx = xv0.x - qv0.x; ds += dx * dx;
    dx = xv0.y - qv0.y; ds += dx * dx;
    dx = xv0.z - qv0.z; ds += dx * dx;
    dx = xv0.w - qv0.w; ds += dx * dx;
    dx = xv1.x - qv1.x; ds += dx * dx;
    dx = xv1.y - qv1.y; ds += dx * dx;
    dx = xv1.z - qv1.z; ds += dx * dx;
    dx = xv1.w - qv1.w; ds += dx * dx;
    ds = wave_reduce_sum(ds);
    float4 y0, y1;
    y0.x = qv0.x + c * nv0.x; y0.y = qv0.y + c * nv0.y;
    y0.z = qv0.z + c * nv0.z; y0.w = qv0.w + c * nv0.w;
    y1.x = qv1.x + c * nv1.x; y1.y = qv1.y + c * nv1.y;
    y1.z = qv1.z + c * nv1.z; y1.w = qv1.w + c * nv1.w;
    *(float4*)(x + lane * 4) = y0;
    *(float4*)(x + 256 + lane * 4) = y1;
    if (lane == 0) {
        float loss = 1.25f * ds * (1.f / DQ);
        lh[t] = m ? loss * sc : 0.f;
        ll[t] = m ? 0.f : loss * (1.f - sc);
    }
}

// ---------------- deterministic loss reduction (unchanged) ----------------
__global__ __launch_bounds__(256) void loss_reduce(const float* __restrict__ lh,
                                                   const float* __restrict__ ll,
                                                   const int* __restrict__ counts,
                                                   float* __restrict__ out) {
    __shared__ float sh[256], sl[256];
    int tid = threadIdx.x;
    float ah = 0.f, al = 0.f;
    for (int t = tid; t < T_TOK; t += 256) { ah += lh[t]; al += ll[t]; }
    sh[tid] = ah; sl[tid] = al;
    __syncthreads();
    for (int o = 128; o > 0; o >>= 1) {
        if (tid < o) { sh[tid] += sh[tid + o]; sl[tid] += sl[tid + o]; }
        __syncthreads();
    }
    if (tid == 0) {
        int nh = counts[0];
        int nl = T_TOK - nh;
        nh = nh > 1 ? nh : 1;
        nl = nl > 1 ? nl : 1;
        out[(size_t)T_TOK * DD] = 0.5f * (sh[0] / (float)nh + sl[0] / (float)nl);
    }
}

// ---------------- fp32 dec (fallback only) ----------------
__global__ __launch_bounds__(256) void dec_gemm(const float* __restrict__ Y,
                                                const float* __restrict__ W,
                                                const float* __restrict__ bias,
                                                float* __restrict__ out) {
    __shared__ float As[32][66];
    __shared__ float Bs[32][64];
    const int m0 = blockIdx.x * 64, n0 = blockIdx.y * 64;
    const int tid = threadIdx.x;
    const int tx = tid & 15, ty = tid >> 4;
    float acc[4][4] = {};
    for (int k0 = 0; k0 < DQ; k0 += 32) {
        {
            int e = tid;
            int r = e >> 3, c4 = e & 7;
            float4 v = *(const float4*)(Y + (size_t)(m0 + r) * DQ + k0 + c4 * 4);
            As[c4*4+0][r] = v.x; As[c4*4+1][r] = v.y; As[c4*4+2][r] = v.z; As[c4*4+3][r] = v.w;
            e = tid + 256; r = e >> 3; c4 = e & 7;
            v = *(const float4*)(Y + (size_t)(m0 + r) * DQ + k0 + c4 * 4);
            As[c4*4+0][r] = v.x; As[c4*4+1][r] = v.y; As[c4*4+2][r] = v.z; As[c4*4+3][r] = v.w;
        }
        {
            int e = tid;
            int kk = e >> 4, c4 = e & 15;
            *(float4*)&Bs[kk][c4*4] = *(const float4*)(W + (size_t)(k0 + kk) * DD + n0 + c4 * 4);
            e = tid + 256; kk = e >> 4; c4 = e & 15;
            *(float4*)&Bs[kk][c4*4] = *(const float4*)(W + (size_t)(k0 + kk) * DD + n0 + c4 * 4);
        }
        __syncthreads();
        #pragma unroll
        for (int k = 0; k < 32; k++) {
            float2 a01 = *(const float2*)&As[k][ty * 4];
            float2 a23 = *(const float2*)&As[k][ty * 4 + 2];
            float4 b = *(const float4*)&Bs[k][tx * 4];
            float av[4] = {a01.x, a01.y, a23.x, a23.y};
            float bv[4] = {b.x, b.y, b.z, b.w};
            #pragma unroll
            for (int i = 0; i < 4; i++)
                #pragma unroll
                for (int j = 0; j < 4; j++)
                    acc[i][j] += av[i] * bv[j];
        }
        __syncthreads();
    }
    float4 bv4 = *(const float4*)(bias + n0 + tx * 4);
    float bbv[4] = {bv4.x, bv4.y, bv4.z, bv4.w};
    #pragma unroll
    for (int i = 0; i < 4; i++) {
        int row = m0 + ty * 4 + i;
        float4 o;
        o.x = acc[i][0] + bbv[0];
        o.y = acc[i][1] + bbv[1];
        o.z = acc[i][2] + bbv[2];
        o.w = acc[i][3] + bbv[3];
        *(float4*)(out + (size_t)row * DD + n0 + tx * 4) = o;
    }
}

extern "C" void kernel_launch(void* const* d_in, const int* in_sizes, int n_in,
                              void* d_out, int out_size, void* d_ws, size_t ws_size,
                              hipStream_t stream) {
    const float* x_tokens = (const float*)d_in[0];
    const float* fim      = (const float*)d_in[1];
    const float* W_proj   = (const float*)d_in[2];
    const float* b_proj   = (const float*)d_in[3];
    const float* ln_g     = (const float*)d_in[4];
    const float* ln_b     = (const float*)d_in[5];
    const float* cb_high  = (const float*)d_in[6];
    const float* cb_low   = (const float*)d_in[7];
    const float* W_dec    = (const float*)d_in[8];
    const float* b_dec    = (const float*)d_in[9];
    const float* h_ri     = (const float*)d_in[10];
    const float* noise    = (const float*)d_in[11];
    float* out = (float*)d_out;

    char* ws = (char*)d_ws;
    size_t off = 0;
    float* xp = (float*)(ws + off);     off += (size_t)T_TOK * DQ * 4;
    int*   idxb = (int*)(ws + off);     off += (size_t)T_TOK * 4;
    float* score = (float*)(ws + off);  off += (size_t)T_TOK * 4;
    int*   mask = (int*)(ws + off);     off += (size_t)T_TOK * 4;
    float* lh = (float*)(ws + off);     off += (size_t)T_TOK * 4;
    float* ll = (float*)(ws + off);     off += (size_t)T_TOK * 4;
    int*   hlist = (int*)(ws + off);    off += (size_t)T_TOK * 4;
    int*   llist = (int*)(ws + off);    off += (size_t)T_TOK * 4;
    int*   counts = (int*)(ws + off);   off += 64;
    float* cs2h = (float*)(ws + off);   off += (size_t)NCH * 4;
    float* cs2l = (float*)(ws + off);   off += (size_t)NCL * 4;
    size_t off_common = off;

    unsigned short* xpB  = (unsigned short*)(ws + off); off += (size_t)T_TOK * DQ * 2;
    unsigned short* cbhB = (unsigned short*)(ws + off); off += (size_t)NCH * DQ * 2;
    unsigned short* cblB = (unsigned short*)(ws + off); off += (size_t)NCL * DQ * 2;
    float* smaxH = (float*)(ws + off);  off += (size_t)T_TOK * SPL_H * 4;
    int*   scntH = (int*)(ws + off);    off += (size_t)T_TOK * SPL_H * 4;
    uint2* candH = (uint2*)(ws + off);  off += (size_t)T_TOK * SPL_H * CAND_CAP * 8;
    float* smaxL = (float*)(ws + off);  off += (size_t)T_TOK * 4;
    int*   scntL = (int*)(ws + off);    off += (size_t)T_TOK * 4;
    uint2* candL = (uint2*)(ws + off);  off += (size_t)T_TOK * CAND_CAP * 8;
    unsigned short* WThi  = (unsigned short*)(ws + off); off += (size_t)DQ * DE * 2;
    unsigned short* WTlo  = (unsigned short*)(ws + off); off += (size_t)DQ * DE * 2;
    unsigned short* WdThi = (unsigned short*)(ws + off); off += (size_t)DD * DQ * 2;
    unsigned short* WdTlo = (unsigned short*)(ws + off); off += (size_t)DD * DQ * 2;
    size_t need_new = off;
    const bool use_mfma = ws_size >= need_new;

    if (use_mfma) {
        prep_all<<<1856, 256, 0, stream>>>(cb_high, cs2h, cbhB, cb_low, cs2l, cblB,
                                           W_proj, WThi, WTlo, W_dec, WdThi, WdTlo);
        gemm_mfma3_128<DE, DQ><<<dim3(T_TOK / 128, DQ / 128), 256, 0, stream>>>(
            x_tokens, WThi, WTlo, b_proj, xp);
        ln_route<<<T_TOK / 4, 256, 0, stream>>>(xp, ln_g, ln_b, fim, score, mask, xpB);
        scan_compact<<<1, 1024, 0, stream>>>(mask, hlist, llist, counts);
        vq_mfma_all<<<dim3(T_TOK / VQTOK, SPL_H + 1), 256, 0, stream>>>(
            xpB, cbhB, cs2h, hlist, cblB, cs2l, llist, counts,
            smaxH, scntH, candH, smaxL, scntL, candL);
        vq_rescore_all<<<2 * (T_TOK / 4), 256, 0, stream>>>(
            xp, cb_high, smaxH, scntH, candH, hlist,
            cb_low, smaxL, scntL, candL, llist,
            counts, idxb, noise, h_ri, score, lh, ll);
        loss_reduce<<<1, 256, 0, stream>>>(lh, ll, counts, out);
        gemm_mfma3<DQ, DD, 64><<<dim3(T_TOK / 64, DD / 64), 256, 0, stream>>>(
            xp, WdThi, WdTlo, b_dec, out);
    } else {
        code_sumsq<NCH><<<NCH / 4, 256, 0, stream>>>(cb_high, cs2h);
        code_sumsq<NCL><<<NCL / 4, 256, 0, stream>>>(cb_low, cs2l);
        proj_gemm<<<dim3(T_TOK / 64, DQ / 64), 256, 0, stream>>>(x_tokens, W_proj, b_proj, xp);
        ln_route<<<T_TOK / 4, 256, 0, stream>>>(xp, ln_g, ln_b, fim, score, mask, nullptr);
        scan_compact<<<1, 1024, 0, stream>>>(mask, hlist, llist, counts);
        float* part_s = (float*)(ws + off_common);
        int*   part_i = (int*)(ws + off_common + (size_t)T_TOK * 16 * 4);
        vq_partial<NCH, 16><<<dim3(T_TOK / 64, 16), 256, 0, stream>>>(
            xp, cb_high, cs2h, hlist, counts, 0, part_s, part_i);
        vq_reduce<16><<<(T_TOK + 255) / 256, 256, 0, stream>>>(part_s, part_i, hlist, counts, 0, idxb);
        vq_partial<NCL, 4><<<dim3(T_TOK / 64, 4), 256, 0, stream>>>(
            xp, cb_low, cs2l, llist, counts, 1, part_s, part_i);
        vq_reduce<4><<<(T_TOK + 255) / 256, 256, 0, stream>>>(part_s, part_i, llist, counts, 1, idxb);
        gather_loss_y<<<T_TOK / 4, 256, 0, stream>>>(xp, cb_high, cb_low, idxb, score, mask,
                                                     noise, h_ri, lh, ll);
        loss_reduce<<<1, 256, 0, stream>>>(lh, ll, counts, out);
        dec_gemm<<<dim3(T_TOK / 64, DD / 64), 256, 0, stream>>>(xp, W_dec, b_dec, out);
    }
}

// Round 24
// 198.449 us; speedup vs baseline: 1.1068x; 1.0669x over previous
//
#include <hip/hip_runtime.h>
#include <math.h>

#define T_TOK 12544   // 64*196
#define DE 768
#define DQ 512
#define DD 256
#define SEQ 196
#define NCH 4096
#define NCL 256
#define SPL_H 16      // high codebook: 16 slices of 256 codes
#define CODES_PER_BLK 256
#define MARGIN 2.0f
#define CAND_CAP 16
#define VQTOK 32      // tokens per vq block

typedef __attribute__((ext_vector_type(8))) short s16x8;
typedef __attribute__((ext_vector_type(4))) float f32x4;

__device__ __forceinline__ float wave_reduce_sum(float v) {
    #pragma unroll
    for (int off = 32; off > 0; off >>= 1) v += __shfl_xor(v, off);
    return v;
}

__device__ __forceinline__ unsigned short f2bf(float f) {
    unsigned int u = __float_as_uint(f);
    u = (u + 0x7fffu + ((u >> 16) & 1u)) >> 16;
    return (unsigned short)u;
}
__device__ __forceinline__ float bf2f(unsigned short h) {
    return __uint_as_float(((unsigned int)h) << 16);
}

// async global->LDS 16B: dest = wave-uniform base + lane*16 (pre-swizzled source)
__device__ __forceinline__ void gload_lds16(const unsigned short* g, unsigned short* l) {
    __builtin_amdgcn_global_load_lds(
        (const __attribute__((address_space(1))) void*)g,
        (__attribute__((address_space(3))) void*)l,
        16, 0, 0);
}

// ---------------- device helpers for merged preprocessing ----------------
__device__ __forceinline__ void sumsq_body(const float* __restrict__ cb,
                                           float* __restrict__ cs2,
                                           unsigned short* __restrict__ cbB,
                                           int blk, int NC) {
    int row = blk * 4 + (threadIdx.x >> 6);
    int lane = threadIdx.x & 63;
    if (row >= NC) return;
    const float4* p = (const float4*)(cb + (size_t)row * DQ);
    float4 a = p[lane];
    float4 b = p[lane + 64];
    if (cbB) {
        unsigned short* dst = cbB + (size_t)row * DQ;
        ushort4 ha, hb;
        ha.x = f2bf(a.x); ha.y = f2bf(a.y); ha.z = f2bf(a.z); ha.w = f2bf(a.w);
        hb.x = f2bf(b.x); hb.y = f2bf(b.y); hb.z = f2bf(b.z); hb.w = f2bf(b.w);
        *(ushort4*)(dst + lane * 4) = ha;
        *(ushort4*)(dst + 256 + lane * 4) = hb;
    }
    float s = a.x*a.x + a.y*a.y + a.z*a.z + a.w*a.w
            + b.x*b.x + b.y*b.y + b.z*b.z + b.w*b.w;
    s = wave_reduce_sum(s);
    if (lane == 0) cs2[row] = s;
}

__device__ __forceinline__ void split_body(const float* __restrict__ W, int K, int N,
                                           unsigned short* __restrict__ Thi,
                                           unsigned short* __restrict__ Tlo,
                                           int blk, int nb) {
    int total = K * N;
    for (int idx = blk * 256 + threadIdx.x; idx < total; idx += nb * 256) {
        int n = idx / K, k = idx - n * K;
        float v = W[(size_t)k * N + n];
        unsigned short h = f2bf(v);
        Thi[idx] = h;
        Tlo[idx] = f2bf(v - bf2f(h));
    }
}

// ---------------- merged preprocessing: sumsq(H,L) + splitW(proj,dec) + counter zero ----------------
__global__ __launch_bounds__(256) void prep_all(const float* __restrict__ cb_h,
                                                float* __restrict__ cs2h,
                                                unsigned short* __restrict__ cbhB,
                                                const float* __restrict__ cb_l,
                                                float* __restrict__ cs2l,
                                                unsigned short* __restrict__ cblB,
                                                const float* __restrict__ Wp,
                                                unsigned short* __restrict__ WThi,
                                                unsigned short* __restrict__ WTlo,
                                                const float* __restrict__ Wd,
                                                unsigned short* __restrict__ WdThi,
                                                unsigned short* __restrict__ WdTlo,
                                                int* __restrict__ counts) {
    int blk = blockIdx.x;
    if (blk == 0 && threadIdx.x == 0) { counts[0] = 0; counts[1] = 0; }
    if (blk < 1024)       sumsq_body(cb_h, cs2h, cbhB, blk, NCH);
    else if (blk < 1088)  sumsq_body(cb_l, cs2l, cblB, blk - 1024, NCL);
    else if (blk < 1600)  split_body(Wp, DE, DQ, WThi, WTlo, blk - 1088, 512);
    else                  split_body(Wd, DQ, DD, WdThi, WdTlo, blk - 1600, 256);
}

// ---------------- fallback code_sumsq (fp32 path only) ----------------
template<int NC>
__global__ __launch_bounds__(256) void code_sumsq(const float* __restrict__ cb,
                                                  float* __restrict__ cs2) {
    sumsq_body(cb, cs2, nullptr, blockIdx.x, NC);
}

// ---------------- proj via 3-term split-bf16 MFMA, 128x128 tile (r23 proven) ----------------
template<int KDIM, int NSTRIDE>
__global__ __launch_bounds__(256) void gemm_mfma3_128(const float* __restrict__ A,
                                                      const unsigned short* __restrict__ BThi,
                                                      const unsigned short* __restrict__ BTlo,
                                                      const float* __restrict__ bias,
                                                      float* __restrict__ out) {
    __shared__ __align__(16) unsigned short Ahi[128 * 32];
    __shared__ __align__(16) unsigned short Alo[128 * 32];
    __shared__ __align__(16) unsigned short Bhi[128 * 32];
    __shared__ __align__(16) unsigned short Blo[128 * 32];
    const int m0 = blockIdx.x * 128, n0 = blockIdx.y * 128;
    const int tid = threadIdx.x, lane = tid & 63, w = tid >> 6;
    const int wr = w >> 1, wc = w & 1;
    const int arow = tid >> 1, ahalf = tid & 1;

    const int cb0 = w * 2, cb1 = w * 2 + 1;
    const int gcol0 = n0 + cb0 * 16 + (lane >> 2);
    const int gcol1 = n0 + cb1 * 16 + (lane >> 2);
    const int ch0 = (lane & 3) ^ ((gcol0 >> 1) & 3);
    const int ch1 = (lane & 3) ^ ((gcol1 >> 1) & 3);
    const unsigned short* sH0 = BThi + (size_t)gcol0 * KDIM + ch0 * 8;
    const unsigned short* sH1 = BThi + (size_t)gcol1 * KDIM + ch1 * 8;
    const unsigned short* sL0 = BTlo + (size_t)gcol0 * KDIM + ch0 * 8;
    const unsigned short* sL1 = BTlo + (size_t)gcol1 * KDIM + ch1 * 8;

    f32x4 acc[4][4] = {};
    const int NT = KDIM / 32;
    for (int t = 0; t < NT; t++) {
        const int k0 = t * 32;
        gload_lds16(sH0 + k0, Bhi + cb0 * 512);
        gload_lds16(sH1 + k0, Bhi + cb1 * 512);
        gload_lds16(sL0 + k0, Blo + cb0 * 512);
        gload_lds16(sL1 + k0, Blo + cb1 * 512);
        {
            const float* src = A + (size_t)(m0 + arow) * KDIM + k0 + ahalf * 16;
            float4 v0 = *(const float4*)(src + 0);
            float4 v1 = *(const float4*)(src + 4);
            float4 v2 = *(const float4*)(src + 8);
            float4 v3 = *(const float4*)(src + 12);
            float xv[16] = {v0.x,v0.y,v0.z,v0.w, v1.x,v1.y,v1.z,v1.w,
                            v2.x,v2.y,v2.z,v2.w, v3.x,v3.y,v3.z,v3.w};
            const int swzA = (arow >> 1) & 3;
            #pragma unroll
            for (int cc = 0; cc < 2; cc++) {
                unsigned int hw[4], lw[4];
                #pragma unroll
                for (int j = 0; j < 4; j++) {
                    float f0 = xv[cc*8 + 2*j], f1 = xv[cc*8 + 2*j + 1];
                    unsigned short h0 = f2bf(f0), h1 = f2bf(f1);
                    unsigned short l0 = f2bf(f0 - bf2f(h0));
                    unsigned short l1 = f2bf(f1 - bf2f(h1));
                    hw[j] = (unsigned)h0 | ((unsigned)h1 << 16);
                    lw[j] = (unsigned)l0 | ((unsigned)l1 << 16);
                }
                int c = ahalf * 2 + cc;
                int doff = arow * 32 + (c ^ swzA) * 8;
                *(uint4*)&Ahi[doff] = make_uint4(hw[0], hw[1], hw[2], hw[3]);
                *(uint4*)&Alo[doff] = make_uint4(lw[0], lw[1], lw[2], lw[3]);
            }
        }
        __syncthreads();
        const int fr = lane & 15, fs = lane >> 4;
        s16x8 ah[4], al[4];
        #pragma unroll
        for (int tm = 0; tm < 4; tm++) {
            int row = wr * 64 + tm * 16 + fr;
            int off = row * 32 + (fs ^ ((row >> 1) & 3)) * 8;
            ah[tm] = *(const s16x8*)&Ahi[off];
            al[tm] = *(const s16x8*)&Alo[off];
        }
        #pragma unroll
        for (int tn = 0; tn < 4; tn++) {
            int col = wc * 64 + tn * 16 + fr;
            int boff = col * 32 + (fs ^ ((col >> 1) & 3)) * 8;
            s16x8 bh = *(const s16x8*)&Bhi[boff];
            s16x8 bl = *(const s16x8*)&Blo[boff];
            #pragma unroll
            for (int tm = 0; tm < 4; tm++) {
                acc[tm][tn] = __builtin_amdgcn_mfma_f32_16x16x32_bf16(ah[tm], bh, acc[tm][tn], 0, 0, 0);
                acc[tm][tn] = __builtin_amdgcn_mfma_f32_16x16x32_bf16(ah[tm], bl, acc[tm][tn], 0, 0, 0);
                acc[tm][tn] = __builtin_amdgcn_mfma_f32_16x16x32_bf16(al[tm], bh, acc[tm][tn], 0, 0, 0);
            }
        }
        __syncthreads();
    }
    const int fr = lane & 15, fg = lane >> 4;
    #pragma unroll
    for (int tn = 0; tn < 4; tn++) {
        const int col = n0 + wc * 64 + tn * 16 + fr;
        const float bb = bias[col];
        #pragma unroll
        for (int tm = 0; tm < 4; tm++) {
            #pragma unroll
            for (int r = 0; r < 4; r++) {
                int row = m0 + wr * 64 + tm * 16 + fg * 4 + r;
                out[(size_t)row * NSTRIDE + col] = acc[tm][tn][r] + bb;
            }
        }
    }
}

// ---------------- dec (64x64, proven) + FUSED loss reduction block ----------------
__global__ __launch_bounds__(256) void dec_mfma3_loss(const float* __restrict__ A,
                                                      const unsigned short* __restrict__ BThi,
                                                      const unsigned short* __restrict__ BTlo,
                                                      const float* __restrict__ bias,
                                                      float* __restrict__ out,
                                                      const float* __restrict__ lh,
                                                      const float* __restrict__ ll,
                                                      const int* __restrict__ counts) {
    __shared__ __align__(16) unsigned short Ahi[2][64 * 32];
    __shared__ __align__(16) unsigned short Alo[2][64 * 32];
    __shared__ __align__(16) unsigned short Bhi[2][64 * 32];
    __shared__ __align__(16) unsigned short Blo[2][64 * 32];
    if (blockIdx.x == T_TOK / 64) {
        // extra block column: loss reduction (same summation order as loss_reduce)
        if (blockIdx.y != 0) return;
        float* sh = (float*)&Ahi[0][0];
        float* sl = sh + 256;
        int tid = threadIdx.x;
        float ah = 0.f, al = 0.f;
        for (int t = tid; t < T_TOK; t += 256) { ah += lh[t]; al += ll[t]; }
        sh[tid] = ah; sl[tid] = al;
        __syncthreads();
        for (int o = 128; o > 0; o >>= 1) {
            if (tid < o) { sh[tid] += sh[tid + o]; sl[tid] += sl[tid + o]; }
            __syncthreads();
        }
        if (tid == 0) {
            int nh = counts[0];
            int nl = T_TOK - nh;
            nh = nh > 1 ? nh : 1;
            nl = nl > 1 ? nl : 1;
            out[(size_t)T_TOK * DD] = 0.5f * (sh[0] / (float)nh + sl[0] / (float)nl);
        }
        return;
    }
    const int m0 = blockIdx.x * 64, n0 = blockIdx.y * 64;
    const int tid = threadIdx.x, lane = tid & 63, w = tid >> 6;
    const int stok = tid >> 2, sslot = tid & 3;

    f32x4 acc[4] = {};
    float4 av0, av1;
    uint4 bh4, bl4;

    auto loadStep = [&](int k0) {
        const float* src = A + (size_t)(m0 + stok) * DQ + k0 + sslot * 8;
        av0 = *(const float4*)src;
        av1 = *(const float4*)(src + 4);
        size_t soff = (size_t)(n0 + stok) * DQ + k0 + sslot * 8;
        bh4 = *(const uint4*)(BThi + soff);
        bl4 = *(const uint4*)(BTlo + soff);
    };
    auto writeStep = [&](int buf) {
        float xv[8] = {av0.x, av0.y, av0.z, av0.w, av1.x, av1.y, av1.z, av1.w};
        unsigned int hw[4], lw[4];
        #pragma unroll
        for (int j = 0; j < 4; j++) {
            unsigned short h0 = f2bf(xv[2*j]),   h1 = f2bf(xv[2*j+1]);
            unsigned short l0 = f2bf(xv[2*j] - bf2f(h0));
            unsigned short l1 = f2bf(xv[2*j+1] - bf2f(h1));
            hw[j] = (unsigned)h0 | ((unsigned)h1 << 16);
            lw[j] = (unsigned)l0 | ((unsigned)l1 << 16);
        }
        int doffA = stok * 32 + (sslot ^ ((stok >> 1) & 3)) * 8;
        *(uint4*)&Ahi[buf][doffA] = make_uint4(hw[0], hw[1], hw[2], hw[3]);
        *(uint4*)&Alo[buf][doffA] = make_uint4(lw[0], lw[1], lw[2], lw[3]);
        *(uint4*)&Bhi[buf][doffA] = bh4;
        *(uint4*)&Blo[buf][doffA] = bl4;
    };

    loadStep(0); writeStep(0); __syncthreads();
    const int NT = DQ / 32;
    for (int t = 0; t < NT; t++) {
        const int cur = t & 1;
        if (t + 1 < NT) loadStep((t + 1) * 32);
        const int fr = lane & 15, fs = lane >> 4;
        s16x8 ah[4], al[4];
        #pragma unroll
        for (int tm = 0; tm < 4; tm++) {
            int tok = tm * 16 + fr;
            int off = tok * 32 + (fs ^ ((tok >> 1) & 3)) * 8;
            ah[tm] = *(const s16x8*)&Ahi[cur][off];
            al[tm] = *(const s16x8*)&Alo[cur][off];
        }
        {
            int col = w * 16 + fr;
            int boff = col * 32 + (fs ^ ((col >> 1) & 3)) * 8;
            s16x8 bh = *(const s16x8*)&Bhi[cur][boff];
            s16x8 bl = *(const s16x8*)&Blo[cur][boff];
            #pragma unroll
            for (int tm = 0; tm < 4; tm++) {
                acc[tm] = __builtin_amdgcn_mfma_f32_16x16x32_bf16(ah[tm], bh, acc[tm], 0, 0, 0);
                acc[tm] = __builtin_amdgcn_mfma_f32_16x16x32_bf16(ah[tm], bl, acc[tm], 0, 0, 0);
                acc[tm] = __builtin_amdgcn_mfma_f32_16x16x32_bf16(al[tm], bh, acc[tm], 0, 0, 0);
            }
        }
        if (t + 1 < NT) writeStep(cur ^ 1);
        __syncthreads();
    }
    const int fr = lane & 15, fg = lane >> 4;
    {
        const int col = n0 + w * 16 + fr;
        const float bb = bias[col];
        #pragma unroll
        for (int tm = 0; tm < 4; tm++) {
            #pragma unroll
            for (int r = 0; r < 4; r++) {
                int row = m0 + tm * 16 + fg * 4 + r;
                out[(size_t)row * DD + col] = acc[tm][r] + bb;
            }
        }
    }
}

// ---------------- fp32 proj (fallback only) ----------------
__global__ __launch_bounds__(256) void proj_gemm(const float* __restrict__ X,
                                                 const float* __restrict__ W,
                                                 const float* __restrict__ bias,
                                                 float* __restrict__ out) {
    __shared__ float As[32][66];
    __shared__ float Bs[32][64];
    const int m0 = blockIdx.x * 64, n0 = blockIdx.y * 64;
    const int tid = threadIdx.x;
    const int tx = tid & 15, ty = tid >> 4;
    float acc[4][4] = {};
    for (int k0 = 0; k0 < DE; k0 += 32) {
        {
            int e = tid;
            int r = e >> 3, c4 = e & 7;
            float4 v = *(const float4*)(X + (size_t)(m0 + r) * DE + k0 + c4 * 4);
            As[c4*4+0][r] = v.x; As[c4*4+1][r] = v.y; As[c4*4+2][r] = v.z; As[c4*4+3][r] = v.w;
            e = tid + 256;
            r = e >> 3; c4 = e & 7;
            v = *(const float4*)(X + (size_t)(m0 + r) * DE + k0 + c4 * 4);
            As[c4*4+0][r] = v.x; As[c4*4+1][r] = v.y; As[c4*4+2][r] = v.z; As[c4*4+3][r] = v.w;
        }
        {
            int e = tid;
            int kk = e >> 4, c4 = e & 15;
            *(float4*)&Bs[kk][c4*4] = *(const float4*)(W + (size_t)(k0 + kk) * DQ + n0 + c4 * 4);
            e = tid + 256;
            kk = e >> 4; c4 = e & 15;
            *(float4*)&Bs[kk][c4*4] = *(const float4*)(W + (size_t)(k0 + kk) * DQ + n0 + c4 * 4);
        }
        __syncthreads();
        #pragma unroll
        for (int k = 0; k < 32; k++) {
            float2 a01 = *(const float2*)&As[k][ty * 4];
            float2 a23 = *(const float2*)&As[k][ty * 4 + 2];
            float4 b = *(const float4*)&Bs[k][tx * 4];
            float av[4] = {a01.x, a01.y, a23.x, a23.y};
            float bv[4] = {b.x, b.y, b.z, b.w};
            #pragma unroll
            for (int i = 0; i < 4; i++)
                #pragma unroll
                for (int j = 0; j < 4; j++)
                    acc[i][j] += av[i] * bv[j];
        }
        __syncthreads();
    }
    float4 bv4 = *(const float4*)(bias + n0 + tx * 4);
    float bb[4] = {bv4.x, bv4.y, bv4.z, bv4.w};
    #pragma unroll
    for (int i = 0; i < 4; i++) {
        int row = m0 + ty * 4 + i;
        float4 o;
        o.x = acc[i][0] + bb[0];
        o.y = acc[i][1] + bb[1];
        o.z = acc[i][2] + bb[2];
        o.w = acc[i][3] + bb[3];
        *(float4*)(out + (size_t)row * DQ + n0 + tx * 4) = o;
    }
}

// ---------------- LayerNorm + routing + bf16 emit + FUSED atomic compaction ----------------
// 32 rows/block (wave w handles rows rbase+8w..+8w+7). hlist/llist order is
// NON-deterministic but all downstream results are indexed by token t and are
// order-independent (per-row MFMA scores exact per token; counts deterministic).
__global__ __launch_bounds__(256) void ln_route_compact(float* __restrict__ xp,
                                                        const float* __restrict__ g,
                                                        const float* __restrict__ b,
                                                        const float* __restrict__ logits,
                                                        float* __restrict__ score,
                                                        unsigned short* __restrict__ xpB,
                                                        int* __restrict__ hlist,
                                                        int* __restrict__ llist,
                                                        int* __restrict__ counts) {
    __shared__ int hloc[32], lloc[32];
    __shared__ int nh_s, nl_s, bh_s, bl_s;
    const int tid = threadIdx.x, lane = tid & 63, wv = tid >> 6;
    if (tid == 0) { nh_s = 0; nl_s = 0; }
    __syncthreads();
    float4 g0 = *(const float4*)(g + lane * 4);
    float4 g1 = *(const float4*)(g + 256 + lane * 4);
    float4 b0 = *(const float4*)(b + lane * 4);
    float4 b1 = *(const float4*)(b + 256 + lane * 4);
    const int rbase = blockIdx.x * 32 + wv * 8;
    for (int i = 0; i < 8; i++) {
        int row = rbase + i;
        float* p = xp + (size_t)row * DQ;
        float4 v0 = *(float4*)(p + lane * 4);
        float4 v1 = *(float4*)(p + 256 + lane * 4);
        float s  = v0.x + v0.y + v0.z + v0.w + v1.x + v1.y + v1.z + v1.w;
        float ss = v0.x*v0.x + v0.y*v0.y + v0.z*v0.z + v0.w*v0.w
                 + v1.x*v1.x + v1.y*v1.y + v1.z*v1.z + v1.w*v1.w;
        s = wave_reduce_sum(s);
        ss = wave_reduce_sum(ss);
        float m = s * (1.f / DQ);
        float var = ss * (1.f / DQ) - m * m;
        float scale = rsqrtf(var + 1e-5f);
        float4 o0, o1;
        o0.x = (v0.x - m) * scale * g0.x + b0.x;
        o0.y = (v0.y - m) * scale * g0.y + b0.y;
        o0.z = (v0.z - m) * scale * g0.z + b0.z;
        o0.w = (v0.w - m) * scale * g0.w + b0.w;
        o1.x = (v1.x - m) * scale * g1.x + b1.x;
        o1.y = (v1.y - m) * scale * g1.y + b1.y;
        o1.z = (v1.z - m) * scale * g1.z + b1.z;
        o1.w = (v1.w - m) * scale * g1.w + b1.w;
        *(float4*)(p + lane * 4) = o0;
        *(float4*)(p + 256 + lane * 4) = o1;
        unsigned short* dst = xpB + (size_t)row * DQ;
        ushort4 h0, h1;
        h0.x = f2bf(o0.x); h0.y = f2bf(o0.y); h0.z = f2bf(o0.z); h0.w = f2bf(o0.w);
        h1.x = f2bf(o1.x); h1.y = f2bf(o1.y); h1.z = f2bf(o1.z); h1.w = f2bf(o1.w);
        *(ushort4*)(dst + lane * 4) = h0;
        *(ushort4*)(dst + 256 + lane * 4) = h1;
        if (lane == 0) {
            float lg = logits[row];
            float sc = 1.f / (1.f + expf(-lg));
            score[row] = sc;
            if (sc > 0.6f) { int pp = atomicAdd(&nh_s, 1); hloc[pp] = row; }
            else           { int pp = atomicAdd(&nl_s, 1); lloc[pp] = row; }
        }
    }
    __syncthreads();
    if (tid == 0) {
        bh_s = atomicAdd(&counts[0], nh_s);
        bl_s = atomicAdd(&counts[1], nl_s);
    }
    __syncthreads();
    if (tid < 32) {
        if (tid < nh_s) hlist[bh_s + tid] = hloc[tid];
    } else if (tid < 64) {
        int j = tid - 32;
        if (j < nl_s) llist[bl_s + j] = lloc[j];
    }
}

// ---------------- fallback LayerNorm + routing (mask-based) ----------------
__global__ __launch_bounds__(256) void ln_route(float* __restrict__ xp,
                                                const float* __restrict__ g,
                                                const float* __restrict__ b,
                                                const float* __restrict__ logits,
                                                float* __restrict__ score,
                                                int* __restrict__ mask,
                                                unsigned short* __restrict__ xpB) {
    int row = blockIdx.x * 4 + (threadIdx.x >> 6);
    int lane = threadIdx.x & 63;
    float* p = xp + (size_t)row * DQ;
    float4 v0 = *(float4*)(p + lane * 4);
    float4 v1 = *(float4*)(p + 256 + lane * 4);
    float s  = v0.x + v0.y + v0.z + v0.w + v1.x + v1.y + v1.z + v1.w;
    float ss = v0.x*v0.x + v0.y*v0.y + v0.z*v0.z + v0.w*v0.w
             + v1.x*v1.x + v1.y*v1.y + v1.z*v1.z + v1.w*v1.w;
    s = wave_reduce_sum(s);
    ss = wave_reduce_sum(ss);
    float m = s * (1.f / DQ);
    float var = ss * (1.f / DQ) - m * m;
    float scale = rsqrtf(var + 1e-5f);
    float4 g0 = *(const float4*)(g + lane * 4);
    float4 g1 = *(const float4*)(g + 256 + lane * 4);
    float4 b0 = *(const float4*)(b + lane * 4);
    float4 b1 = *(const float4*)(b + 256 + lane * 4);
    float4 o0, o1;
    o0.x = (v0.x - m) * scale * g0.x + b0.x;
    o0.y = (v0.y - m) * scale * g0.y + b0.y;
    o0.z = (v0.z - m) * scale * g0.z + b0.z;
    o0.w = (v0.w - m) * scale * g0.w + b0.w;
    o1.x = (v1.x - m) * scale * g1.x + b1.x;
    o1.y = (v1.y - m) * scale * g1.y + b1.y;
    o1.z = (v1.z - m) * scale * g1.z + b1.z;
    o1.w = (v1.w - m) * scale * g1.w + b1.w;
    *(float4*)(p + lane * 4) = o0;
    *(float4*)(p + 256 + lane * 4) = o1;
    if (xpB) {
        unsigned short* dst = xpB + (size_t)row * DQ;
        ushort4 h0, h1;
        h0.x = f2bf(o0.x); h0.y = f2bf(o0.y); h0.z = f2bf(o0.z); h0.w = f2bf(o0.w);
        h1.x = f2bf(o1.x); h1.y = f2bf(o1.y); h1.z = f2bf(o1.z); h1.w = f2bf(o1.w);
        *(ushort4*)(dst + lane * 4) = h0;
        *(ushort4*)(dst + 256 + lane * 4) = h1;
    }
    if (lane == 0) {
        float lg = logits[row];
        float sc = 1.f / (1.f + expf(-lg));
        score[row] = sc;
        mask[row] = sc > 0.6f ? 1 : 0;
    }
}

// ---------------- deterministic compaction (fallback path only) ----------------
__global__ __launch_bounds__(1024) void scan_compact(const int* __restrict__ mask,
                                                     int* __restrict__ hlist,
                                                     int* __restrict__ llist,
                                                     int* __restrict__ counts) {
    __shared__ int wsum[16];
    __shared__ int base_h, base_l;
    int tid = threadIdx.x, lane = tid & 63, wid = tid >> 6;
    if (tid == 0) { base_h = 0; base_l = 0; }
    __syncthreads();
    for (int t0 = 0; t0 < T_TOK; t0 += 1024) {
        int t = t0 + tid;
        int valid = t < T_TOK;
        int m = valid ? mask[t] : 0;
        unsigned long long bal = __ballot(m);
        int pre = __popcll(bal & ((1ull << lane) - 1ull));
        if (lane == 0) wsum[wid] = __popcll(bal);
        __syncthreads();
        int woff = 0;
        for (int w = 0; w < wid; w++) woff += wsum[w];
        int btot = 0;
        for (int w = 0; w < 16; w++) btot += wsum[w];
        int vcnt = T_TOK - t0; if (vcnt > 1024) vcnt = 1024;
        int bh = base_h, bl = base_l;
        if (valid) {
            if (m) hlist[bh + woff + pre] = t;
            else   llist[bl + (tid - (woff + pre))] = t;
        }
        __syncthreads();
        if (tid == 0) { base_h = bh + btot; base_l = bl + (vcnt - btot); }
        __syncthreads();
    }
    if (tid == 0) { counts[0] = base_h; counts[1] = base_l; }
}

// ---------------- merged MFMA approx-score VQ: 32-token tiles (r22 structure) ----------------
__global__ __launch_bounds__(256) void vq_mfma_all(const unsigned short* __restrict__ xpB,
                                                   const unsigned short* __restrict__ cbhB,
                                                   const float* __restrict__ cs2h,
                                                   const int* __restrict__ hlist,
                                                   const unsigned short* __restrict__ cblB,
                                                   const float* __restrict__ cs2l,
                                                   const int* __restrict__ llist,
                                                   const int* __restrict__ counts,
                                                   float* __restrict__ smaxH,
                                                   int* __restrict__ scntH,
                                                   uint2* __restrict__ candH,
                                                   float* __restrict__ smaxL,
                                                   int* __restrict__ scntL,
                                                   uint2* __restrict__ candL) {
    const int by = blockIdx.y;
    const unsigned short* cbB; const float* cs2; const int* list;
    float* smax; int* scnt; uint2* cand;
    int count, slice, SPLIT;
    if (by < SPL_H) {
        cbB = cbhB; cs2 = cs2h; list = hlist; count = counts[0];
        slice = by; SPLIT = SPL_H; smax = smaxH; scnt = scntH; cand = candH;
    } else {
        cbB = cblB; cs2 = cs2l; list = llist; count = counts[1];
        slice = 0; SPLIT = 1; smax = smaxL; scnt = scntL; cand = candL;
    }
    const int base = blockIdx.x * VQTOK;
    if (base >= count) return;
    const int cbase = slice * CODES_PER_BLK;

    __shared__ __align__(16) unsigned short Abuf[VQTOK * 32];
    __shared__ __align__(16) unsigned short Bbuf[256 * 32];
    __shared__ float wmaxs[4][VQTOK];
    __shared__ float tokmax[VQTOK];
    __shared__ int ccnt[VQTOK];
    __shared__ uint2 cland[VQTOK][CAND_CAP];
    __shared__ int rows_s[VQTOK];

    const int tid = threadIdx.x;
    const int lane = tid & 63;
    const int w = tid >> 6;
    const int stok = tid >> 2, sslot = tid & 3;

    if (tid < VQTOK) {
        int tl = base + tid;
        rows_s[tid] = list[tl < count ? tl : (count - 1)];
        ccnt[tid] = 0;
    }
    __syncthreads();

    const int swz = sslot ^ ((stok >> 1) & 3);
    const unsigned short* gA  = xpB + (size_t)rows_s[stok & (VQTOK - 1)] * DQ + swz * 8;
    const unsigned short* gB0 = cbB + (size_t)(cbase + 0 * 64 + stok) * DQ + swz * 8;
    const unsigned short* gB1 = cbB + (size_t)(cbase + 1 * 64 + stok) * DQ + swz * 8;
    const unsigned short* gB2 = cbB + (size_t)(cbase + 2 * 64 + stok) * DQ + swz * 8;
    const unsigned short* gB3 = cbB + (size_t)(cbase + 3 * 64 + stok) * DQ + swz * 8;
    unsigned short* dA = Abuf + w * 512;
    unsigned short* dB = Bbuf + w * 512;

    f32x4 acc[2][4] = {};

    const int NT = DQ / 32;
    for (int t = 0; t < NT; t++) {
        const int k0 = t * 32;
        if (w < 2) gload_lds16(gA + k0, dA);
        gload_lds16(gB0 + k0, dB + 0 * 2048);
        gload_lds16(gB1 + k0, dB + 1 * 2048);
        gload_lds16(gB2 + k0, dB + 2 * 2048);
        gload_lds16(gB3 + k0, dB + 3 * 2048);
        __syncthreads();
        const int fr = lane & 15, fs = lane >> 4;
        s16x8 af[2], bf[4];
        #pragma unroll
        for (int tm = 0; tm < 2; tm++) {
            int tok = tm * 16 + fr;
            af[tm] = *(const s16x8*)&Abuf[tok * 32 + (fs ^ ((tok >> 1) & 3)) * 8];
        }
        #pragma unroll
        for (int tn = 0; tn < 4; tn++) {
            int cl = w * 64 + tn * 16 + fr;
            bf[tn] = *(const s16x8*)&Bbuf[cl * 32 + (fs ^ ((cl >> 1) & 3)) * 8];
        }
        #pragma unroll
        for (int tm = 0; tm < 2; tm++)
            #pragma unroll
            for (int tn = 0; tn < 4; tn++)
                acc[tm][tn] = __builtin_amdgcn_mfma_f32_16x16x32_bf16(af[tm], bf[tn], acc[tm][tn], 0, 0, 0);
        __syncthreads();
    }

    const int fr = lane & 15, fg = lane >> 4;
    float c2[4];
    #pragma unroll
    for (int tn = 0; tn < 4; tn++) c2[tn] = 0.5f * cs2[cbase + w * 64 + tn * 16 + fr];

    #pragma unroll
    for (int tm = 0; tm < 2; tm++) {
        #pragma unroll
        for (int r = 0; r < 4; r++) {
            float m4 = -3.0e38f;
            #pragma unroll
            for (int tn = 0; tn < 4; tn++) {
                float s = acc[tm][tn][r] - c2[tn];
                m4 = fmaxf(m4, s);
            }
            #pragma unroll
            for (int off = 1; off < 16; off <<= 1)
                m4 = fmaxf(m4, __shfl_xor(m4, off));
            if (fr == 0) wmaxs[w][tm * 16 + fg * 4 + r] = m4;
        }
    }
    __syncthreads();
    if (tid < VQTOK)
        tokmax[tid] = fmaxf(fmaxf(wmaxs[0][tid], wmaxs[1][tid]),
                            fmaxf(wmaxs[2][tid], wmaxs[3][tid]));
    __syncthreads();

    #pragma unroll
    for (int tm = 0; tm < 2; tm++) {
        #pragma unroll
        for (int r = 0; r < 4; r++) {
            int token = tm * 16 + fg * 4 + r;
            float thr = tokmax[token] - MARGIN;
            #pragma unroll
            for (int tn = 0; tn < 4; tn++) {
                float s = acc[tm][tn][r] - c2[tn];
                if (s > thr) {
                    int pos = atomicAdd(&ccnt[token], 1);
                    if (pos < CAND_CAP) {
                        uint2 cd;
                        cd.x = __float_as_uint(s);
                        cd.y = (unsigned)(cbase + w * 64 + tn * 16 + fr);
                        cland[token][pos] = cd;
                    }
                }
            }
        }
    }
    __syncthreads();

    if (tid < VQTOK) {
        int tl = base + tid;
        if (tl < count) {
            smax[(size_t)tl * SPLIT + slice] = tokmax[tid];
            scnt[(size_t)tl * SPLIT + slice] = min(ccnt[tid], CAND_CAP);
        }
    }
    for (int i = tid; i < VQTOK * CAND_CAP; i += 256) {
        int token = i >> 4, j = i & (CAND_CAP - 1);
        int tl = base + token;
        if (tl < count && j < min(ccnt[token], CAND_CAP))
            cand[((size_t)tl * SPLIT + slice) * CAND_CAP + j] = cland[token][j];
    }
}

// ---------------- merged exact fp64 rescore + FUSED gather/loss/y ----------------
__global__ __launch_bounds__(256) void vq_rescore_all(float* __restrict__ xp,
                                                      const float* __restrict__ cb_h,
                                                      const float* __restrict__ smaxH,
                                                      const int* __restrict__ scntH,
                                                      const uint2* __restrict__ candH,
                                                      const int* __restrict__ hlist,
                                                      const float* __restrict__ cb_l,
                                                      const float* __restrict__ smaxL,
                                                      const int* __restrict__ scntL,
                                                      const uint2* __restrict__ candL,
                                                      const int* __restrict__ llist,
                                                      const int* __restrict__ counts,
                                                      int* __restrict__ out_idx,
                                                      const float* __restrict__ noise,
                                                      const float* __restrict__ h_ri,
                                                      const float* __restrict__ score,
                                                      float* __restrict__ lh,
                                                      float* __restrict__ ll) {
    const int HB = T_TOK / 4;
    int bx = blockIdx.x;
    const float* cb; const float* smax; const int* scnt; const uint2* cand; const int* list;
    int count, SPLIT, cidx;
    if (bx < HB) {
        cb = cb_h; smax = smaxH; scnt = scntH; cand = candH; list = hlist;
        count = counts[0]; SPLIT = SPL_H; cidx = 0;
    } else {
        bx -= HB;
        cb = cb_l; smax = smaxL; scnt = scntL; cand = candL; list = llist;
        count = counts[1]; SPLIT = 1; cidx = 1;
    }
    const int wid = threadIdx.x >> 6;
    const int lane = threadIdx.x & 63;
    const int tl = bx * 4 + wid;
    if (tl >= count) return;

    float gm = -3.0e38f;
    if (lane < SPLIT) gm = smax[(size_t)tl * SPLIT + lane];
    #pragma unroll
    for (int off = 1; off < 64; off <<= 1)
        gm = fmaxf(gm, __shfl_xor(gm, off));
    const float thr = gm - MARGIN;

    const int t = list[tl];
    float xv[8];
    #pragma unroll
    for (int kk = 0; kk < 8; kk++) xv[kk] = xp[(size_t)t * DQ + lane * 8 + kk];

    double bs = -1.0e300;
    int bi = 0x7fffffff;
    for (int s = 0; s < SPLIT; s++) {
        int cn = scnt[(size_t)tl * SPLIT + s];
        for (int j = 0; j < cn; j++) {
            uint2 cd = cand[((size_t)tl * SPLIT + s) * CAND_CAP + j];
            float av = __uint_as_float(cd.x);
            if (av >= thr) {
                int code = (int)cd.y;
                const float* crow = cb + (size_t)code * DQ;
                double dot = 0.0, nrm = 0.0;
                #pragma unroll
                for (int kk = 0; kk < 8; kk++) {
                    double cv = (double)crow[lane * 8 + kk];
                    dot += (double)xv[kk] * cv;
                    nrm += cv * cv;
                }
                #pragma unroll
                for (int off = 1; off < 64; off <<= 1) {
                    dot += __shfl_xor(dot, off);
                    nrm += __shfl_xor(nrm, off);
                }
                double sc = dot - 0.5 * nrm;
                if (sc > bs || (sc == bs && code < bi)) { bs = sc; bi = code; }
            }
        }
    }
    const float* qrow = cb + (size_t)bi * DQ;
    float4 q0 = *(const float4*)(qrow + lane * 8);
    float4 q1 = *(const float4*)(qrow + lane * 8 + 4);
    const float* nz = noise + (size_t)t * DQ;
    float4 n0 = *(const float4*)(nz + lane * 8);
    float4 n1 = *(const float4*)(nz + lane * 8 + 4);
    float ds = 0.f, dx;
    dx = xv[0] - q0.x; ds += dx * dx;
    dx = xv[1] - q0.y; ds += dx * dx;
    dx = xv[2] - q0.z; ds += dx * dx;
    dx = xv[3] - q0.w; ds += dx * dx;
    dx = xv[4] - q1.x; ds += dx * dx;
    dx = xv[5] - q1.y; ds += dx * dx;
    dx = xv[6] - q1.z; ds += dx * dx;
    dx = xv[7] - q1.w; ds += dx * dx;
    ds = wave_reduce_sum(ds);
    int bbt = t / SEQ;
    float hh0 = h_ri[bbt * 2], hh1 = h_ri[bbt * 2 + 1];
    float hh = sqrtf((hh0 * hh0 + hh1 * hh1) * 0.5f);
    float cc = sqrtf(1e-3f) / hh;
    float4 y0, y1;
    y0.x = q0.x + cc * n0.x; y0.y = q0.y + cc * n0.y;
    y0.z = q0.z + cc * n0.z; y0.w = q0.w + cc * n0.w;
    y1.x = q1.x + cc * n1.x; y1.y = q1.y + cc * n1.y;
    y1.z = q1.z + cc * n1.z; y1.w = q1.w + cc * n1.w;
    *(float4*)(xp + (size_t)t * DQ + lane * 8) = y0;
    *(float4*)(xp + (size_t)t * DQ + lane * 8 + 4) = y1;
    if (lane == 0) {
        out_idx[t] = bi;
        float loss = 1.25f * ds * (1.f / DQ);
        float sc = score[t];
        if (cidx == 0) { lh[t] = loss * sc;  ll[t] = 0.f; }
        else           { lh[t] = 0.f;        ll[t] = loss * (1.f - sc); }
    }
}

// ---------------- FALLBACK fp32 VQ (unchanged) ----------------
template<int NC, int SPLIT>
__global__ __launch_bounds__(256) void vq_partial(const float* __restrict__ xp,
                                                  const float* __restrict__ cb,
                                                  const float* __restrict__ cs2,
                                                  const int* __restrict__ list,
                                                  const int* __restrict__ counts,
                                                  int cidx,
                                                  float* __restrict__ part_s,
                                                  int* __restrict__ part_i) {
    const int count = counts[cidx];
    const int base = blockIdx.x * 64;
    if (base >= count) return;
    const int CODES = NC / SPLIT;
    const int cbase = blockIdx.y * CODES;
    __shared__ float As[32][68];
    __shared__ float Cs[32][68];
    __shared__ int rows_s[64];
    const int tid = threadIdx.x;
    if (tid < 64) {
        int tl = base + tid;
        rows_s[tid] = list[tl < count ? tl : (count - 1)];
    }
    __syncthreads();
    const int tx = tid & 15, ty = tid >> 4;
    float best_s[4];
    int best_i[4];
    #pragma unroll
    for (int i = 0; i < 4; i++) { best_s[i] = -3.0e38f; best_i[i] = 0; }
    for (int c0 = cbase; c0 < cbase + CODES; c0 += 64) {
        float acc[4][4] = {};
        for (int k0 = 0; k0 < DQ; k0 += 32) {
            {
                int e = tid;
                int r = e >> 3, c4 = e & 7;
                float4 v = *(const float4*)(xp + (size_t)rows_s[r] * DQ + k0 + c4 * 4);
                As[c4*4+0][r] = v.x; As[c4*4+1][r] = v.y; As[c4*4+2][r] = v.z; As[c4*4+3][r] = v.w;
                e = tid + 256; r = e >> 3; c4 = e & 7;
                v = *(const float4*)(xp + (size_t)rows_s[r] * DQ + k0 + c4 * 4);
                As[c4*4+0][r] = v.x; As[c4*4+1][r] = v.y; As[c4*4+2][r] = v.z; As[c4*4+3][r] = v.w;
            }
            {
                int e = tid;
                int r = e >> 3, c4 = e & 7;
                float4 v = *(const float4*)(cb + (size_t)(c0 + r) * DQ + k0 + c4 * 4);
                Cs[c4*4+0][r] = v.x; Cs[c4*4+1][r] = v.y; Cs[c4*4+2][r] = v.z; Cs[c4*4+3][r] = v.w;
                e = tid + 256; r = e >> 3; c4 = e & 7;
                v = *(const float4*)(cb + (size_t)(c0 + r) * DQ + k0 + c4 * 4);
                Cs[c4*4+0][r] = v.x; Cs[c4*4+1][r] = v.y; Cs[c4*4+2][r] = v.z; Cs[c4*4+3][r] = v.w;
            }
            __syncthreads();
            #pragma unroll
            for (int k = 0; k < 32; k++) {
                float4 a = *(const float4*)&As[k][ty * 4];
                float4 b = *(const float4*)&Cs[k][tx * 4];
                float av[4] = {a.x, a.y, a.z, a.w};
                float bv[4] = {b.x, b.y, b.z, b.w};
                #pragma unroll
                for (int i = 0; i < 4; i++)
                    #pragma unroll
                    for (int j = 0; j < 4; j++)
                        acc[i][j] += av[i] * bv[j];
            }
            __syncthreads();
        }
        float4 c2v = *(const float4*)(cs2 + c0 + tx * 4);
        float c2[4] = {c2v.x, c2v.y, c2v.z, c2v.w};
        #pragma unroll
        for (int i = 0; i < 4; i++) {
            float s = acc[i][0] - 0.5f * c2[0];
            int bi = c0 + tx * 4;
            #pragma unroll
            for (int j = 1; j < 4; j++) {
                float sj = acc[i][j] - 0.5f * c2[j];
                if (sj > s) { s = sj; bi = c0 + tx * 4 + j; }
            }
            #pragma unroll
            for (int off = 1; off < 16; off <<= 1) {
                float os = __shfl_xor(s, off);
                int oi = __shfl_xor(bi, off);
                if (os > s || (os == s && oi < bi)) { s = os; bi = oi; }
            }
            if (s > best_s[i] || (s == best_s[i] && bi < best_i[i])) {
                best_s[i] = s; best_i[i] = bi;
            }
        }
    }
    if (tx == 0) {
        #pragma unroll
        for (int i = 0; i < 4; i++) {
            int tl = base + ty * 4 + i;
            if (tl < count) {
                part_s[(size_t)tl * SPLIT + blockIdx.y] = best_s[i];
                part_i[(size_t)tl * SPLIT + blockIdx.y] = best_i[i];
            }
        }
    }
}

template<int SPLIT>
__global__ __launch_bounds__(256) void vq_reduce(const float* __restrict__ part_s,
                                                 const int* __restrict__ part_i,
                                                 const int* __restrict__ list,
                                                 const int* __restrict__ counts,
                                                 int cidx,
                                                 int* __restrict__ out_idx) {
    int tl = blockIdx.x * 256 + threadIdx.x;
    if (tl >= counts[cidx]) return;
    float bs = part_s[(size_t)tl * SPLIT];
    int bi = part_i[(size_t)tl * SPLIT];
    #pragma unroll
    for (int s = 1; s < SPLIT; s++) {
        float v = part_s[(size_t)tl * SPLIT + s];
        int vi = part_i[(size_t)tl * SPLIT + s];
        if (v > bs || (v == bs && vi < bi)) { bs = v; bi = vi; }
    }
    out_idx[list[tl]] = bi;
}

// ---------------- gather q, per-token loss, y (fallback path only) ----------------
__global__ __launch_bounds__(256) void gather_loss_y(float* __restrict__ xp,
                                                     const float* __restrict__ cb_h,
                                                     const float* __restrict__ cb_l,
                                                     const int* __restrict__ idx,
                                                     const float* __restrict__ score,
                                                     const int* __restrict__ mask,
                                                     const float* __restrict__ noise,
                                                     const float* __restrict__ h_ri,
                                                     float* __restrict__ lh,
                                                     float* __restrict__ ll) {
    int t = blockIdx.x * 4 + (threadIdx.x >> 6);
    int lane = threadIdx.x & 63;
    int m = mask[t];
    float sc = score[t];
    const float* q = (m ? cb_h : cb_l) + (size_t)idx[t] * DQ;
    float* x = xp + (size_t)t * DQ;
    const float* nz = noise + (size_t)t * DQ;
    int bb = t / SEQ;
    float h0 = h_ri[bb * 2], h1 = h_ri[bb * 2 + 1];
    float h = sqrtf((h0 * h0 + h1 * h1) * 0.5f);
    float c = sqrtf(1e-3f) / h;
    float4 xv0 = *(float4*)(x + lane * 4);
    float4 xv1 = *(float4*)(x + 256 + lane * 4);
    float4 qv0 = *(const float4*)(q + lane * 4);
    float4 qv1 = *(const float4*)(q + 256 + lane * 4);
    float4 nv0 = *(const float4*)(nz + lane * 4);
    float4 nv1 = *(const float4*)(nz + 256 + lane * 4);
    float dx, ds = 0.f;
    dx = xv0.x - qv0.x; ds += dx * dx;
    dx = xv0.y - qv0.y; ds += dx * dx;
    dx = xv0.z - qv0.z; ds += dx * dx;
    dx = xv0.w - qv0.w; ds += dx * dx;
    dx = xv1.x - qv1.x; ds += dx * dx;
    dx = xv1.y - qv1.y; ds += dx * dx;
    dx = xv1.z - qv1.z; ds += dx * dx;
    dx = xv1.w - qv1.w; ds += dx * dx;
    ds = wave_reduce_sum(ds);
    float4 y0, y1;
    y0.x = qv0.x + c * nv0.x; y0.y = qv0.y + c * nv0.y;
    y0.z = qv0.z + c * nv0.z; y0.w = qv0.w + c * nv0.w;
    y1.x = qv1.x + c * nv1.x; y1.y = qv1.y + c * nv1.y;
    y1.z = qv1.z + c * nv1.z; y1.w = qv1.w + c * nv1.w;
    *(float4*)(x + lane * 4) = y0;
    *(float4*)(x + 256 + lane * 4) = y1;
    if (lane == 0) {
        float loss = 1.25f * ds * (1.f / DQ);
        lh[t] = m ? loss * sc : 0.f;
        ll[t] = m ? 0.f : loss * (1.f - sc);
    }
}

// ---------------- deterministic loss reduction (fallback path only) ----------------
__global__ __launch_bounds__(256) void loss_reduce(const float* __restrict__ lh,
                                                   const float* __restrict__ ll,
                                                   const int* __restrict__ counts,
                                                   float* __restrict__ out) {
    __shared__ float sh[256], sl[256];
    int tid = threadIdx.x;
    float ah = 0.f, al = 0.f;
    for (int t = tid; t < T_TOK; t += 256) { ah += lh[t]; al += ll[t]; }
    sh[tid] = ah; sl[tid] = al;
    __syncthreads();
    for (int o = 128; o > 0; o >>= 1) {
        if (tid < o) { sh[tid] += sh[tid + o]; sl[tid] += sl[tid + o]; }
        __syncthreads();
    }
    if (tid == 0) {
        int nh = counts[0];
        int nl = T_TOK - nh;
        nh = nh > 1 ? nh : 1;
        nl = nl > 1 ? nl : 1;
        out[(size_t)T_TOK * DD] = 0.5f * (sh[0] / (float)nh + sl[0] / (float)nl);
    }
}

// ---------------- fp32 dec (fallback only) ----------------
__global__ __launch_bounds__(256) void dec_gemm(const float* __restrict__ Y,
                                                const float* __restrict__ W,
                                                const float* __restrict__ bias,
                                                float* __restrict__ out) {
    __shared__ float As[32][66];
    __shared__ float Bs[32][64];
    const int m0 = blockIdx.x * 64, n0 = blockIdx.y * 64;
    const int tid = threadIdx.x;
    const int tx = tid & 15, ty = tid >> 4;
    float acc[4][4] = {};
    for (int k0 = 0; k0 < DQ; k0 += 32) {
        {
            int e = tid;
            int r = e >> 3, c4 = e & 7;
            float4 v = *(const float4*)(Y + (size_t)(m0 + r) * DQ + k0 + c4 * 4);
            As[c4*4+0][r] = v.x; As[c4*4+1][r] = v.y; As[c4*4+2][r] = v.z; As[c4*4+3][r] = v.w;
            e = tid + 256; r = e >> 3; c4 = e & 7;
            v = *(const float4*)(Y + (size_t)(m0 + r) * DQ + k0 + c4 * 4);
            As[c4*4+0][r] = v.x; As[c4*4+1][r] = v.y; As[c4*4+2][r] = v.z; As[c4*4+3][r] = v.w;
        }
        {
            int e = tid;
            int kk = e >> 4, c4 = e & 15;
            *(float4*)&Bs[kk][c4*4] = *(const float4*)(W + (size_t)(k0 + kk) * DD + n0 + c4 * 4);
            e = tid + 256; kk = e >> 4; c4 = e & 15;
            *(float4*)&Bs[kk][c4*4] = *(const float4*)(W + (size_t)(k0 + kk) * DD + n0 + c4 * 4);
        }
        __syncthreads();
        #pragma unroll
        for (int k = 0; k < 32; k++) {
            float2 a01 = *(const float2*)&As[k][ty * 4];
            float2 a23 = *(const float2*)&As[k][ty * 4 + 2];
            float4 b = *(const float4*)&Bs[k][tx * 4];
            float av[4] = {a01.x, a01.y, a23.x, a23.y};
            float bv[4] = {b.x, b.y, b.z, b.w};
            #pragma unroll
            for (int i = 0; i < 4; i++)
                #pragma unroll
                for (int j = 0; j < 4; j++)
                    acc[i][j] += av[i] * bv[j];
        }
        __syncthreads();
    }
    float4 bv4 = *(const float4*)(bias + n0 + tx * 4);
    float bbv[4] = {bv4.x, bv4.y, bv4.z, bv4.w};
    #pragma unroll
    for (int i = 0; i < 4; i++) {
        int row = m0 + ty * 4 + i;
        float4 o;
        o.x = acc[i][0] + bbv[0];
        o.y = acc[i][1] + bbv[1];
        o.z = acc[i][2] + bbv[2];
        o.w = acc[i][3] + bbv[3];
        *(float4*)(out + (size_t)row * DD + n0 + tx * 4) = o;
    }
}

extern "C" void kernel_launch(void* const* d_in, const int* in_sizes, int n_in,
                              void* d_out, int out_size, void* d_ws, size_t ws_size,
                              hipStream_t stream) {
    const float* x_tokens = (const float*)d_in[0];
    const float* fim      = (const float*)d_in[1];
    const float* W_proj   = (const float*)d_in[2];
    const float* b_proj   = (const float*)d_in[3];
    const float* ln_g     = (const float*)d_in[4];
    const float* ln_b     = (const float*)d_in[5];
    const float* cb_high  = (const float*)d_in[6];
    const float* cb_low   = (const float*)d_in[7];
    const float* W_dec    = (const float*)d_in[8];
    const float* b_dec    = (const float*)d_in[9];
    const float* h_ri     = (const float*)d_in[10];
    const float* noise    = (const float*)d_in[11];
    float* out = (float*)d_out;

    char* ws = (char*)d_ws;
    size_t off = 0;
    float* xp = (float*)(ws + off);     off += (size_t)T_TOK * DQ * 4;
    int*   idxb = (int*)(ws + off);     off += (size_t)T_TOK * 4;
    float* score = (float*)(ws + off);  off += (size_t)T_TOK * 4;
    int*   mask = (int*)(ws + off);     off += (size_t)T_TOK * 4;
    float* lh = (float*)(ws + off);     off += (size_t)T_TOK * 4;
    float* ll = (float*)(ws + off);     off += (size_t)T_TOK * 4;
    int*   hlist = (int*)(ws + off);    off += (size_t)T_TOK * 4;
    int*   llist = (int*)(ws + off);    off += (size_t)T_TOK * 4;
    int*   counts = (int*)(ws + off);   off += 64;
    float* cs2h = (float*)(ws + off);   off += (size_t)NCH * 4;
    float* cs2l = (float*)(ws + off);   off += (size_t)NCL * 4;
    size_t off_common = off;

    unsigned short* xpB  = (unsigned short*)(ws + off); off += (size_t)T_TOK * DQ * 2;
    unsigned short* cbhB = (unsigned short*)(ws + off); off += (size_t)NCH * DQ * 2;
    unsigned short* cblB = (unsigned short*)(ws + off); off += (size_t)NCL * DQ * 2;
    float* smaxH = (float*)(ws + off);  off += (size_t)T_TOK * SPL_H * 4;
    int*   scntH = (int*)(ws + off);    off += (size_t)T_TOK * SPL_H * 4;
    uint2* candH = (uint2*)(ws + off);  off += (size_t)T_TOK * SPL_H * CAND_CAP * 8;
    float* smaxL = (float*)(ws + off);  off += (size_t)T_TOK * 4;
    int*   scntL = (int*)(ws + off);    off += (size_t)T_TOK * 4;
    uint2* candL = (uint2*)(ws + off);  off += (size_t)T_TOK * CAND_CAP * 8;
    unsigned short* WThi  = (unsigned short*)(ws + off); off += (size_t)DQ * DE * 2;
    unsigned short* WTlo  = (unsigned short*)(ws + off); off += (size_t)DQ * DE * 2;
    unsigned short* WdThi = (unsigned short*)(ws + off); off += (size_t)DD * DQ * 2;
    unsigned short* WdTlo = (unsigned short*)(ws + off); off += (size_t)DD * DQ * 2;
    size_t need_new = off;
    const bool use_mfma = ws_size >= need_new;

    if (use_mfma) {
        prep_all<<<1856, 256, 0, stream>>>(cb_high, cs2h, cbhB, cb_low, cs2l, cblB,
                                           W_proj, WThi, WTlo, W_dec, WdThi, WdTlo, counts);
        gemm_mfma3_128<DE, DQ><<<dim3(T_TOK / 128, DQ / 128), 256, 0, stream>>>(
            x_tokens, WThi, WTlo, b_proj, xp);
        ln_route_compact<<<T_TOK / 32, 256, 0, stream>>>(
            xp, ln_g, ln_b, fim, score, xpB, hlist, llist, counts);
        vq_mfma_all<<<dim3(T_TOK / VQTOK, SPL_H + 1), 256, 0, stream>>>(
            xpB, cbhB, cs2h, hlist, cblB, cs2l, llist, counts,
            smaxH, scntH, candH, smaxL, scntL, candL);
        vq_rescore_all<<<2 * (T_TOK / 4), 256, 0, stream>>>(
            xp, cb_high, smaxH, scntH, candH, hlist,
            cb_low, smaxL, scntL, candL, llist,
            counts, idxb, noise, h_ri, score, lh, ll);
        dec_mfma3_loss<<<dim3(T_TOK / 64 + 1, DD / 64), 256, 0, stream>>>(
            xp, WdThi, WdTlo, b_dec, out, lh, ll, counts);
    } else {
        code_sumsq<NCH><<<NCH / 4, 256, 0, stream>>>(cb_high, cs2h);
        code_sumsq<NCL><<<NCL / 4, 256, 0, stream>>>(cb_low, cs2l);
        proj_gemm<<<dim3(T_TOK / 64, DQ / 64), 256, 0, stream>>>(x_tokens, W_proj, b_proj, xp);
        ln_route<<<T_TOK / 4, 256, 0, stream>>>(xp, ln_g, ln_b, fim, score, mask, nullptr);
        scan_compact<<<1, 1024, 0, stream>>>(mask, hlist, llist, counts);
        float* part_s = (float*)(ws + off_common);
        int*   part_i = (int*)(ws + off_common + (size_t)T_TOK * 16 * 4);
        vq_partial<NCH, 16><<<dim3(T_TOK / 64, 16), 256, 0, stream>>>(
            xp, cb_high, cs2h, hlist, counts, 0, part_s, part_i);
        vq_reduce<16><<<(T_TOK + 255) / 256, 256, 0, stream>>>(part_s, part_i, hlist, counts, 0, idxb);
        vq_partial<NCL, 4><<<dim3(T_TOK / 64, 4), 256, 0, stream>>>(
            xp, cb_low, cs2l, llist, counts, 1, part_s, part_i);
        vq_reduce<4><<<(T_TOK + 255) / 256, 256, 0, stream>>>(part_s, part_i, llist, counts, 1, idxb);
        gather_loss_y<<<T_TOK / 4, 256, 0, stream>>>(xp, cb_high, cb_low, idxb, score, mask,
                                                     noise, h_ri, lh, ll);
        loss_reduce<<<1, 256, 0, stream>>>(lh, ll, counts, out);
        dec_gemm<<<dim3(T_TOK / 64, DD / 64), 256, 0, stream>>>(xp, W_dec, b_dec, out);
    }
}

// Round 25
// 197.970 us; speedup vs baseline: 1.1094x; 1.0024x over previous
//
#include <hip/hip_runtime.h>
#include <math.h>

#define T_TOK 12544   // 64*196
#define DE 768
#define DQ 512
#define DD 256
#define SEQ 196
#define NCH 4096
#define NCL 256
#define SPL_H 16      // high codebook: 16 slices of 256 codes
#define CODES_PER_BLK 256
#define MARGIN 2.0f
#define CAND_CAP 16
#define VQTOK 128     // tokens per vq block (128x256 tile, 8 waves)

typedef __attribute__((ext_vector_type(8))) short s16x8;
typedef __attribute__((ext_vector_type(4))) float f32x4;

__device__ __forceinline__ float wave_reduce_sum(float v) {
    #pragma unroll
    for (int off = 32; off > 0; off >>= 1) v += __shfl_xor(v, off);
    return v;
}

__device__ __forceinline__ unsigned short f2bf(float f) {
    unsigned int u = __float_as_uint(f);
    u = (u + 0x7fffu + ((u >> 16) & 1u)) >> 16;
    return (unsigned short)u;
}
__device__ __forceinline__ float bf2f(unsigned short h) {
    return __uint_as_float(((unsigned int)h) << 16);
}

// async global->LDS 16B: dest = wave-uniform base + lane*16 (pre-swizzled source)
__device__ __forceinline__ void gload_lds16(const unsigned short* g, unsigned short* l) {
    __builtin_amdgcn_global_load_lds(
        (const __attribute__((address_space(1))) void*)g,
        (__attribute__((address_space(3))) void*)l,
        16, 0, 0);
}

// ---------------- device helpers for merged preprocessing ----------------
__device__ __forceinline__ void sumsq_body(const float* __restrict__ cb,
                                           float* __restrict__ cs2,
                                           unsigned short* __restrict__ cbB,
                                           int blk, int NC) {
    int row = blk * 4 + (threadIdx.x >> 6);
    int lane = threadIdx.x & 63;
    if (row >= NC) return;
    const float4* p = (const float4*)(cb + (size_t)row * DQ);
    float4 a = p[lane];
    float4 b = p[lane + 64];
    if (cbB) {
        unsigned short* dst = cbB + (size_t)row * DQ;
        ushort4 ha, hb;
        ha.x = f2bf(a.x); ha.y = f2bf(a.y); ha.z = f2bf(a.z); ha.w = f2bf(a.w);
        hb.x = f2bf(b.x); hb.y = f2bf(b.y); hb.z = f2bf(b.z); hb.w = f2bf(b.w);
        *(ushort4*)(dst + lane * 4) = ha;
        *(ushort4*)(dst + 256 + lane * 4) = hb;
    }
    float s = a.x*a.x + a.y*a.y + a.z*a.z + a.w*a.w
            + b.x*b.x + b.y*b.y + b.z*b.z + b.w*b.w;
    s = wave_reduce_sum(s);
    if (lane == 0) cs2[row] = s;
}

__device__ __forceinline__ void split_body(const float* __restrict__ W, int K, int N,
                                           unsigned short* __restrict__ Thi,
                                           unsigned short* __restrict__ Tlo,
                                           int blk, int nb) {
    int total = K * N;
    for (int idx = blk * 256 + threadIdx.x; idx < total; idx += nb * 256) {
        int n = idx / K, k = idx - n * K;
        float v = W[(size_t)k * N + n];
        unsigned short h = f2bf(v);
        Thi[idx] = h;
        Tlo[idx] = f2bf(v - bf2f(h));
    }
}

// ---------------- merged preprocessing: sumsq(H,L) + splitW(proj,dec) + counter zero ----------------
__global__ __launch_bounds__(256) void prep_all(const float* __restrict__ cb_h,
                                                float* __restrict__ cs2h,
                                                unsigned short* __restrict__ cbhB,
                                                const float* __restrict__ cb_l,
                                                float* __restrict__ cs2l,
                                                unsigned short* __restrict__ cblB,
                                                const float* __restrict__ Wp,
                                                unsigned short* __restrict__ WThi,
                                                unsigned short* __restrict__ WTlo,
                                                const float* __restrict__ Wd,
                                                unsigned short* __restrict__ WdThi,
                                                unsigned short* __restrict__ WdTlo,
                                                int* __restrict__ counts) {
    int blk = blockIdx.x;
    if (blk == 0 && threadIdx.x == 0) { counts[0] = 0; counts[1] = 0; }
    if (blk < 1024)       sumsq_body(cb_h, cs2h, cbhB, blk, NCH);
    else if (blk < 1088)  sumsq_body(cb_l, cs2l, cblB, blk - 1024, NCL);
    else if (blk < 1600)  split_body(Wp, DE, DQ, WThi, WTlo, blk - 1088, 512);
    else                  split_body(Wd, DQ, DD, WdThi, WdTlo, blk - 1600, 256);
}

// ---------------- fallback code_sumsq (fp32 path only) ----------------
template<int NC>
__global__ __launch_bounds__(256) void code_sumsq(const float* __restrict__ cb,
                                                  float* __restrict__ cs2) {
    sumsq_body(cb, cs2, nullptr, blockIdx.x, NC);
}

// ---------------- proj via 3-term split-bf16 MFMA, 128x128 tile (r23 proven) ----------------
template<int KDIM, int NSTRIDE>
__global__ __launch_bounds__(256) void gemm_mfma3_128(const float* __restrict__ A,
                                                      const unsigned short* __restrict__ BThi,
                                                      const unsigned short* __restrict__ BTlo,
                                                      const float* __restrict__ bias,
                                                      float* __restrict__ out) {
    __shared__ __align__(16) unsigned short Ahi[128 * 32];
    __shared__ __align__(16) unsigned short Alo[128 * 32];
    __shared__ __align__(16) unsigned short Bhi[128 * 32];
    __shared__ __align__(16) unsigned short Blo[128 * 32];
    const int m0 = blockIdx.x * 128, n0 = blockIdx.y * 128;
    const int tid = threadIdx.x, lane = tid & 63, w = tid >> 6;
    const int wr = w >> 1, wc = w & 1;
    const int arow = tid >> 1, ahalf = tid & 1;

    const int cb0 = w * 2, cb1 = w * 2 + 1;
    const int gcol0 = n0 + cb0 * 16 + (lane >> 2);
    const int gcol1 = n0 + cb1 * 16 + (lane >> 2);
    const int ch0 = (lane & 3) ^ ((gcol0 >> 1) & 3);
    const int ch1 = (lane & 3) ^ ((gcol1 >> 1) & 3);
    const unsigned short* sH0 = BThi + (size_t)gcol0 * KDIM + ch0 * 8;
    const unsigned short* sH1 = BThi + (size_t)gcol1 * KDIM + ch1 * 8;
    const unsigned short* sL0 = BTlo + (size_t)gcol0 * KDIM + ch0 * 8;
    const unsigned short* sL1 = BTlo + (size_t)gcol1 * KDIM + ch1 * 8;

    f32x4 acc[4][4] = {};
    const int NT = KDIM / 32;
    for (int t = 0; t < NT; t++) {
        const int k0 = t * 32;
        gload_lds16(sH0 + k0, Bhi + cb0 * 512);
        gload_lds16(sH1 + k0, Bhi + cb1 * 512);
        gload_lds16(sL0 + k0, Blo + cb0 * 512);
        gload_lds16(sL1 + k0, Blo + cb1 * 512);
        {
            const float* src = A + (size_t)(m0 + arow) * KDIM + k0 + ahalf * 16;
            float4 v0 = *(const float4*)(src + 0);
            float4 v1 = *(const float4*)(src + 4);
            float4 v2 = *(const float4*)(src + 8);
            float4 v3 = *(const float4*)(src + 12);
            float xv[16] = {v0.x,v0.y,v0.z,v0.w, v1.x,v1.y,v1.z,v1.w,
                            v2.x,v2.y,v2.z,v2.w, v3.x,v3.y,v3.z,v3.w};
            const int swzA = (arow >> 1) & 3;
            #pragma unroll
            for (int cc = 0; cc < 2; cc++) {
                unsigned int hw[4], lw[4];
                #pragma unroll
                for (int j = 0; j < 4; j++) {
                    float f0 = xv[cc*8 + 2*j], f1 = xv[cc*8 + 2*j + 1];
                    unsigned short h0 = f2bf(f0), h1 = f2bf(f1);
                    unsigned short l0 = f2bf(f0 - bf2f(h0));
                    unsigned short l1 = f2bf(f1 - bf2f(h1));
                    hw[j] = (unsigned)h0 | ((unsigned)h1 << 16);
                    lw[j] = (unsigned)l0 | ((unsigned)l1 << 16);
                }
                int c = ahalf * 2 + cc;
                int doff = arow * 32 + (c ^ swzA) * 8;
                *(uint4*)&Ahi[doff] = make_uint4(hw[0], hw[1], hw[2], hw[3]);
                *(uint4*)&Alo[doff] = make_uint4(lw[0], lw[1], lw[2], lw[3]);
            }
        }
        __syncthreads();
        const int fr = lane & 15, fs = lane >> 4;
        s16x8 ah[4], al[4];
        #pragma unroll
        for (int tm = 0; tm < 4; tm++) {
            int row = wr * 64 + tm * 16 + fr;
            int off = row * 32 + (fs ^ ((row >> 1) & 3)) * 8;
            ah[tm] = *(const s16x8*)&Ahi[off];
            al[tm] = *(const s16x8*)&Alo[off];
        }
        #pragma unroll
        for (int tn = 0; tn < 4; tn++) {
            int col = wc * 64 + tn * 16 + fr;
            int boff = col * 32 + (fs ^ ((col >> 1) & 3)) * 8;
            s16x8 bh = *(const s16x8*)&Bhi[boff];
            s16x8 bl = *(const s16x8*)&Blo[boff];
            #pragma unroll
            for (int tm = 0; tm < 4; tm++) {
                acc[tm][tn] = __builtin_amdgcn_mfma_f32_16x16x32_bf16(ah[tm], bh, acc[tm][tn], 0, 0, 0);
                acc[tm][tn] = __builtin_amdgcn_mfma_f32_16x16x32_bf16(ah[tm], bl, acc[tm][tn], 0, 0, 0);
                acc[tm][tn] = __builtin_amdgcn_mfma_f32_16x16x32_bf16(al[tm], bh, acc[tm][tn], 0, 0, 0);
            }
        }
        __syncthreads();
    }
    const int fr = lane & 15, fg = lane >> 4;
    #pragma unroll
    for (int tn = 0; tn < 4; tn++) {
        const int col = n0 + wc * 64 + tn * 16 + fr;
        const float bb = bias[col];
        #pragma unroll
        for (int tm = 0; tm < 4; tm++) {
            #pragma unroll
            for (int r = 0; r < 4; r++) {
                int row = m0 + wr * 64 + tm * 16 + fg * 4 + r;
                out[(size_t)row * NSTRIDE + col] = acc[tm][tn][r] + bb;
            }
        }
    }
}

// ---------------- dec (64x64, proven) + FUSED loss reduction block ----------------
__global__ __launch_bounds__(256) void dec_mfma3_loss(const float* __restrict__ A,
                                                      const unsigned short* __restrict__ BThi,
                                                      const unsigned short* __restrict__ BTlo,
                                                      const float* __restrict__ bias,
                                                      float* __restrict__ out,
                                                      const float* __restrict__ lh,
                                                      const float* __restrict__ ll,
                                                      const int* __restrict__ counts) {
    __shared__ __align__(16) unsigned short Ahi[2][64 * 32];
    __shared__ __align__(16) unsigned short Alo[2][64 * 32];
    __shared__ __align__(16) unsigned short Bhi[2][64 * 32];
    __shared__ __align__(16) unsigned short Blo[2][64 * 32];
    if (blockIdx.x == T_TOK / 64) {
        if (blockIdx.y != 0) return;
        float* sh = (float*)&Ahi[0][0];
        float* sl = sh + 256;
        int tid = threadIdx.x;
        float ah = 0.f, al = 0.f;
        for (int t = tid; t < T_TOK; t += 256) { ah += lh[t]; al += ll[t]; }
        sh[tid] = ah; sl[tid] = al;
        __syncthreads();
        for (int o = 128; o > 0; o >>= 1) {
            if (tid < o) { sh[tid] += sh[tid + o]; sl[tid] += sl[tid + o]; }
            __syncthreads();
        }
        if (tid == 0) {
            int nh = counts[0];
            int nl = T_TOK - nh;
            nh = nh > 1 ? nh : 1;
            nl = nl > 1 ? nl : 1;
            out[(size_t)T_TOK * DD] = 0.5f * (sh[0] / (float)nh + sl[0] / (float)nl);
        }
        return;
    }
    const int m0 = blockIdx.x * 64, n0 = blockIdx.y * 64;
    const int tid = threadIdx.x, lane = tid & 63, w = tid >> 6;
    const int stok = tid >> 2, sslot = tid & 3;

    f32x4 acc[4] = {};
    float4 av0, av1;
    uint4 bh4, bl4;

    auto loadStep = [&](int k0) {
        const float* src = A + (size_t)(m0 + stok) * DQ + k0 + sslot * 8;
        av0 = *(const float4*)src;
        av1 = *(const float4*)(src + 4);
        size_t soff = (size_t)(n0 + stok) * DQ + k0 + sslot * 8;
        bh4 = *(const uint4*)(BThi + soff);
        bl4 = *(const uint4*)(BTlo + soff);
    };
    auto writeStep = [&](int buf) {
        float xv[8] = {av0.x, av0.y, av0.z, av0.w, av1.x, av1.y, av1.z, av1.w};
        unsigned int hw[4], lw[4];
        #pragma unroll
        for (int j = 0; j < 4; j++) {
            unsigned short h0 = f2bf(xv[2*j]),   h1 = f2bf(xv[2*j+1]);
            unsigned short l0 = f2bf(xv[2*j] - bf2f(h0));
            unsigned short l1 = f2bf(xv[2*j+1] - bf2f(h1));
            hw[j] = (unsigned)h0 | ((unsigned)h1 << 16);
            lw[j] = (unsigned)l0 | ((unsigned)l1 << 16);
        }
        int doffA = stok * 32 + (sslot ^ ((stok >> 1) & 3)) * 8;
        *(uint4*)&Ahi[buf][doffA] = make_uint4(hw[0], hw[1], hw[2], hw[3]);
        *(uint4*)&Alo[buf][doffA] = make_uint4(lw[0], lw[1], lw[2], lw[3]);
        *(uint4*)&Bhi[buf][doffA] = bh4;
        *(uint4*)&Blo[buf][doffA] = bl4;
    };

    loadStep(0); writeStep(0); __syncthreads();
    const int NT = DQ / 32;
    for (int t = 0; t < NT; t++) {
        const int cur = t & 1;
        if (t + 1 < NT) loadStep((t + 1) * 32);
        const int fr = lane & 15, fs = lane >> 4;
        s16x8 ah[4], al[4];
        #pragma unroll
        for (int tm = 0; tm < 4; tm++) {
            int tok = tm * 16 + fr;
            int off = tok * 32 + (fs ^ ((tok >> 1) & 3)) * 8;
            ah[tm] = *(const s16x8*)&Ahi[cur][off];
            al[tm] = *(const s16x8*)&Alo[cur][off];
        }
        {
            int col = w * 16 + fr;
            int boff = col * 32 + (fs ^ ((col >> 1) & 3)) * 8;
            s16x8 bh = *(const s16x8*)&Bhi[cur][boff];
            s16x8 bl = *(const s16x8*)&Blo[cur][boff];
            #pragma unroll
            for (int tm = 0; tm < 4; tm++) {
                acc[tm] = __builtin_amdgcn_mfma_f32_16x16x32_bf16(ah[tm], bh, acc[tm], 0, 0, 0);
                acc[tm] = __builtin_amdgcn_mfma_f32_16x16x32_bf16(ah[tm], bl, acc[tm], 0, 0, 0);
                acc[tm] = __builtin_amdgcn_mfma_f32_16x16x32_bf16(al[tm], bh, acc[tm], 0, 0, 0);
            }
        }
        if (t + 1 < NT) writeStep(cur ^ 1);
        __syncthreads();
    }
    const int fr = lane & 15, fg = lane >> 4;
    {
        const int col = n0 + w * 16 + fr;
        const float bb = bias[col];
        #pragma unroll
        for (int tm = 0; tm < 4; tm++) {
            #pragma unroll
            for (int r = 0; r < 4; r++) {
                int row = m0 + tm * 16 + fg * 4 + r;
                out[(size_t)row * DD + col] = acc[tm][r] + bb;
            }
        }
    }
}

// ---------------- fp32 proj (fallback only) ----------------
__global__ __launch_bounds__(256) void proj_gemm(const float* __restrict__ X,
                                                 const float* __restrict__ W,
                                                 const float* __restrict__ bias,
                                                 float* __restrict__ out) {
    __shared__ float As[32][66];
    __shared__ float Bs[32][64];
    const int m0 = blockIdx.x * 64, n0 = blockIdx.y * 64;
    const int tid = threadIdx.x;
    const int tx = tid & 15, ty = tid >> 4;
    float acc[4][4] = {};
    for (int k0 = 0; k0 < DE; k0 += 32) {
        {
            int e = tid;
            int r = e >> 3, c4 = e & 7;
            float4 v = *(const float4*)(X + (size_t)(m0 + r) * DE + k0 + c4 * 4);
            As[c4*4+0][r] = v.x; As[c4*4+1][r] = v.y; As[c4*4+2][r] = v.z; As[c4*4+3][r] = v.w;
            e = tid + 256;
            r = e >> 3; c4 = e & 7;
            v = *(const float4*)(X + (size_t)(m0 + r) * DE + k0 + c4 * 4);
            As[c4*4+0][r] = v.x; As[c4*4+1][r] = v.y; As[c4*4+2][r] = v.z; As[c4*4+3][r] = v.w;
        }
        {
            int e = tid;
            int kk = e >> 4, c4 = e & 15;
            *(float4*)&Bs[kk][c4*4] = *(const float4*)(W + (size_t)(k0 + kk) * DQ + n0 + c4 * 4);
            e = tid + 256;
            kk = e >> 4; c4 = e & 15;
            *(float4*)&Bs[kk][c4*4] = *(const float4*)(W + (size_t)(k0 + kk) * DQ + n0 + c4 * 4);
        }
        __syncthreads();
        #pragma unroll
        for (int k = 0; k < 32; k++) {
            float2 a01 = *(const float2*)&As[k][ty * 4];
            float2 a23 = *(const float2*)&As[k][ty * 4 + 2];
            float4 b = *(const float4*)&Bs[k][tx * 4];
            float av[4] = {a01.x, a01.y, a23.x, a23.y};
            float bv[4] = {b.x, b.y, b.z, b.w};
            #pragma unroll
            for (int i = 0; i < 4; i++)
                #pragma unroll
                for (int j = 0; j < 4; j++)
                    acc[i][j] += av[i] * bv[j];
        }
        __syncthreads();
    }
    float4 bv4 = *(const float4*)(bias + n0 + tx * 4);
    float bb[4] = {bv4.x, bv4.y, bv4.z, bv4.w};
    #pragma unroll
    for (int i = 0; i < 4; i++) {
        int row = m0 + ty * 4 + i;
        float4 o;
        o.x = acc[i][0] + bb[0];
        o.y = acc[i][1] + bb[1];
        o.z = acc[i][2] + bb[2];
        o.w = acc[i][3] + bb[3];
        *(float4*)(out + (size_t)row * DQ + n0 + tx * 4) = o;
    }
}

// ---------------- LayerNorm + routing + bf16 emit + FUSED atomic compaction ----------------
__global__ __launch_bounds__(256) void ln_route_compact(float* __restrict__ xp,
                                                        const float* __restrict__ g,
                                                        const float* __restrict__ b,
                                                        const float* __restrict__ logits,
                                                        float* __restrict__ score,
                                                        unsigned short* __restrict__ xpB,
                                                        int* __restrict__ hlist,
                                                        int* __restrict__ llist,
                                                        int* __restrict__ counts) {
    __shared__ int hloc[32], lloc[32];
    __shared__ int nh_s, nl_s, bh_s, bl_s;
    const int tid = threadIdx.x, lane = tid & 63, wv = tid >> 6;
    if (tid == 0) { nh_s = 0; nl_s = 0; }
    __syncthreads();
    float4 g0 = *(const float4*)(g + lane * 4);
    float4 g1 = *(const float4*)(g + 256 + lane * 4);
    float4 b0 = *(const float4*)(b + lane * 4);
    float4 b1 = *(const float4*)(b + 256 + lane * 4);
    const int rbase = blockIdx.x * 32 + wv * 8;
    for (int i = 0; i < 8; i++) {
        int row = rbase + i;
        float* p = xp + (size_t)row * DQ;
        float4 v0 = *(float4*)(p + lane * 4);
        float4 v1 = *(float4*)(p + 256 + lane * 4);
        float s  = v0.x + v0.y + v0.z + v0.w + v1.x + v1.y + v1.z + v1.w;
        float ss = v0.x*v0.x + v0.y*v0.y + v0.z*v0.z + v0.w*v0.w
                 + v1.x*v1.x + v1.y*v1.y + v1.z*v1.z + v1.w*v1.w;
        s = wave_reduce_sum(s);
        ss = wave_reduce_sum(ss);
        float m = s * (1.f / DQ);
        float var = ss * (1.f / DQ) - m * m;
        float scale = rsqrtf(var + 1e-5f);
        float4 o0, o1;
        o0.x = (v0.x - m) * scale * g0.x + b0.x;
        o0.y = (v0.y - m) * scale * g0.y + b0.y;
        o0.z = (v0.z - m) * scale * g0.z + b0.z;
        o0.w = (v0.w - m) * scale * g0.w + b0.w;
        o1.x = (v1.x - m) * scale * g1.x + b1.x;
        o1.y = (v1.y - m) * scale * g1.y + b1.y;
        o1.z = (v1.z - m) * scale * g1.z + b1.z;
        o1.w = (v1.w - m) * scale * g1.w + b1.w;
        *(float4*)(p + lane * 4) = o0;
        *(float4*)(p + 256 + lane * 4) = o1;
        unsigned short* dst = xpB + (size_t)row * DQ;
        ushort4 h0, h1;
        h0.x = f2bf(o0.x); h0.y = f2bf(o0.y); h0.z = f2bf(o0.z); h0.w = f2bf(o0.w);
        h1.x = f2bf(o1.x); h1.y = f2bf(o1.y); h1.z = f2bf(o1.z); h1.w = f2bf(o1.w);
        *(ushort4*)(dst + lane * 4) = h0;
        *(ushort4*)(dst + 256 + lane * 4) = h1;
        if (lane == 0) {
            float lg = logits[row];
            float sc = 1.f / (1.f + expf(-lg));
            score[row] = sc;
            if (sc > 0.6f) { int pp = atomicAdd(&nh_s, 1); hloc[pp] = row; }
            else           { int pp = atomicAdd(&nl_s, 1); lloc[pp] = row; }
        }
    }
    __syncthreads();
    if (tid == 0) {
        bh_s = atomicAdd(&counts[0], nh_s);
        bl_s = atomicAdd(&counts[1], nl_s);
    }
    __syncthreads();
    if (tid < 32) {
        if (tid < nh_s) hlist[bh_s + tid] = hloc[tid];
    } else if (tid < 64) {
        int j = tid - 32;
        if (j < nl_s) llist[bl_s + j] = lloc[j];
    }
}

// ---------------- fallback LayerNorm + routing (mask-based) ----------------
__global__ __launch_bounds__(256) void ln_route(float* __restrict__ xp,
                                                const float* __restrict__ g,
                                                const float* __restrict__ b,
                                                const float* __restrict__ logits,
                                                float* __restrict__ score,
                                                int* __restrict__ mask,
                                                unsigned short* __restrict__ xpB) {
    int row = blockIdx.x * 4 + (threadIdx.x >> 6);
    int lane = threadIdx.x & 63;
    float* p = xp + (size_t)row * DQ;
    float4 v0 = *(float4*)(p + lane * 4);
    float4 v1 = *(float4*)(p + 256 + lane * 4);
    float s  = v0.x + v0.y + v0.z + v0.w + v1.x + v1.y + v1.z + v1.w;
    float ss = v0.x*v0.x + v0.y*v0.y + v0.z*v0.z + v0.w*v0.w
             + v1.x*v1.x + v1.y*v1.y + v1.z*v1.z + v1.w*v1.w;
    s = wave_reduce_sum(s);
    ss = wave_reduce_sum(ss);
    float m = s * (1.f / DQ);
    float var = ss * (1.f / DQ) - m * m;
    float scale = rsqrtf(var + 1e-5f);
    float4 g0 = *(const float4*)(g + lane * 4);
    float4 g1 = *(const float4*)(g + 256 + lane * 4);
    float4 b0 = *(const float4*)(b + lane * 4);
    float4 b1 = *(const float4*)(b + 256 + lane * 4);
    float4 o0, o1;
    o0.x = (v0.x - m) * scale * g0.x + b0.x;
    o0.y = (v0.y - m) * scale * g0.y + b0.y;
    o0.z = (v0.z - m) * scale * g0.z + b0.z;
    o0.w = (v0.w - m) * scale * g0.w + b0.w;
    o1.x = (v1.x - m) * scale * g1.x + b1.x;
    o1.y = (v1.y - m) * scale * g1.y + b1.y;
    o1.z = (v1.z - m) * scale * g1.z + b1.z;
    o1.w = (v1.w - m) * scale * g1.w + b1.w;
    *(float4*)(p + lane * 4) = o0;
    *(float4*)(p + 256 + lane * 4) = o1;
    if (xpB) {
        unsigned short* dst = xpB + (size_t)row * DQ;
        ushort4 h0, h1;
        h0.x = f2bf(o0.x); h0.y = f2bf(o0.y); h0.z = f2bf(o0.z); h0.w = f2bf(o0.w);
        h1.x = f2bf(o1.x); h1.y = f2bf(o1.y); h1.z = f2bf(o1.z); h1.w = f2bf(o1.w);
        *(ushort4*)(dst + lane * 4) = h0;
        *(ushort4*)(dst + 256 + lane * 4) = h1;
    }
    if (lane == 0) {
        float lg = logits[row];
        float sc = 1.f / (1.f + expf(-lg));
        score[row] = sc;
        mask[row] = sc > 0.6f ? 1 : 0;
    }
}

// ---------------- deterministic compaction (fallback path only) ----------------
__global__ __launch_bounds__(1024) void scan_compact(const int* __restrict__ mask,
                                                     int* __restrict__ hlist,
                                                     int* __restrict__ llist,
                                                     int* __restrict__ counts) {
    __shared__ int wsum[16];
    __shared__ int base_h, base_l;
    int tid = threadIdx.x, lane = tid & 63, wid = tid >> 6;
    if (tid == 0) { base_h = 0; base_l = 0; }
    __syncthreads();
    for (int t0 = 0; t0 < T_TOK; t0 += 1024) {
        int t = t0 + tid;
        int valid = t < T_TOK;
        int m = valid ? mask[t] : 0;
        unsigned long long bal = __ballot(m);
        int pre = __popcll(bal & ((1ull << lane) - 1ull));
        if (lane == 0) wsum[wid] = __popcll(bal);
        __syncthreads();
        int woff = 0;
        for (int w = 0; w < wid; w++) woff += wsum[w];
        int btot = 0;
        for (int w = 0; w < 16; w++) btot += wsum[w];
        int vcnt = T_TOK - t0; if (vcnt > 1024) vcnt = 1024;
        int bh = base_h, bl = base_l;
        if (valid) {
            if (m) hlist[bh + woff + pre] = t;
            else   llist[bl + (tid - (woff + pre))] = t;
        }
        __syncthreads();
        if (tid == 0) { base_h = bh + btot; base_l = bl + (vcnt - btot); }
        __syncthreads();
    }
    if (tid == 0) { counts[0] = base_h; counts[1] = base_l; }
}

// ---------------- merged MFMA approx-score VQ: 128-token x 256-code tile, 8 waves ----------------
// Pure-bf16 GEMM at the r23 proj geometry: per wave-step 16 MFMA vs 8 ds_reads
// (2x the MFMA:barrier density of the 32-token version). Per-(token,code) score
// is the same 16-step k-ascending MFMA chain -> scores bit-identical; candidate
// sets identical; rescore is order-independent -> outputs bit-identical.
__global__ __launch_bounds__(512) void vq_mfma_all(const unsigned short* __restrict__ xpB,
                                                   const unsigned short* __restrict__ cbhB,
                                                   const float* __restrict__ cs2h,
                                                   const int* __restrict__ hlist,
                                                   const unsigned short* __restrict__ cblB,
                                                   const float* __restrict__ cs2l,
                                                   const int* __restrict__ llist,
                                                   const int* __restrict__ counts,
                                                   float* __restrict__ smaxH,
                                                   int* __restrict__ scntH,
                                                   uint2* __restrict__ candH,
                                                   float* __restrict__ smaxL,
                                                   int* __restrict__ scntL,
                                                   uint2* __restrict__ candL) {
    const int by = blockIdx.y;
    const unsigned short* cbB; const float* cs2; const int* list;
    float* smax; int* scnt; uint2* cand;
    int count, slice, SPLIT;
    if (by < SPL_H) {
        cbB = cbhB; cs2 = cs2h; list = hlist; count = counts[0];
        slice = by; SPLIT = SPL_H; smax = smaxH; scnt = scntH; cand = candH;
    } else {
        cbB = cblB; cs2 = cs2l; list = llist; count = counts[1];
        slice = 0; SPLIT = 1; smax = smaxL; scnt = scntL; cand = candL;
    }
    const int base = blockIdx.x * VQTOK;
    if (base >= count) return;
    const int cbase = slice * CODES_PER_BLK;

    __shared__ __align__(16) unsigned short Abuf[VQTOK * 32];     // 8 KB
    __shared__ __align__(16) unsigned short Bbuf[256 * 32];       // 16 KB
    __shared__ float wmaxs[8][64];
    __shared__ float tokmax[VQTOK];
    __shared__ int ccnt[VQTOK];
    __shared__ uint2 cland[VQTOK][CAND_CAP];                      // 16 KB
    __shared__ int rows_s[VQTOK];

    const int tid = threadIdx.x;
    const int lane = tid & 63;
    const int w = tid >> 6;            // 0..7
    const int wr = w >> 2, wc = w & 3; // wave quadrant: 64 tokens x 64 codes
    const int stok = tid >> 2, sslot = tid & 3;   // staging row 0..127, chunk 0..3

    if (tid < VQTOK) {
        int tl = base + tid;
        rows_s[tid] = list[tl < count ? tl : (count - 1)];
        ccnt[tid] = 0;
    }
    __syncthreads();

    // pre-swizzled global sources (chunk XOR matches LDS read-side swizzle)
    const int swz = sslot ^ ((stok >> 1) & 3);   // note: ((128+stok)>>1)&3 == (stok>>1)&3
    const unsigned short* gA  = xpB + (size_t)rows_s[stok] * DQ + swz * 8;
    const unsigned short* gB0 = cbB + (size_t)(cbase + stok) * DQ + swz * 8;
    const unsigned short* gB1 = cbB + (size_t)(cbase + 128 + stok) * DQ + swz * 8;
    unsigned short* dA  = Abuf + w * 512;
    unsigned short* dB0 = Bbuf + w * 512;
    unsigned short* dB1 = Bbuf + 128 * 32 + w * 512;

    f32x4 acc[4][4] = {};

    const int NT = DQ / 32;            // 16
    for (int t = 0; t < NT; t++) {
        const int k0 = t * 32;
        gload_lds16(gA  + k0, dA);
        gload_lds16(gB0 + k0, dB0);
        gload_lds16(gB1 + k0, dB1);
        __syncthreads();               // drains loads: tiles ready
        const int fr = lane & 15, fs = lane >> 4;
        s16x8 af[4], bf[4];
        #pragma unroll
        for (int tm = 0; tm < 4; tm++) {
            int tok = wr * 64 + tm * 16 + fr;
            af[tm] = *(const s16x8*)&Abuf[tok * 32 + (fs ^ ((tok >> 1) & 3)) * 8];
        }
        #pragma unroll
        for (int tn = 0; tn < 4; tn++) {
            int cl = wc * 64 + tn * 16 + fr;
            bf[tn] = *(const s16x8*)&Bbuf[cl * 32 + (fs ^ ((cl >> 1) & 3)) * 8];
        }
        #pragma unroll
        for (int tm = 0; tm < 4; tm++)
            #pragma unroll
            for (int tn = 0; tn < 4; tn++)
                acc[tm][tn] = __builtin_amdgcn_mfma_f32_16x16x32_bf16(af[tm], bf[tn], acc[tm][tn], 0, 0, 0);
        __syncthreads();               // seals reads before next overwrite
    }

    const int fr = lane & 15, fg = lane >> 4;
    float c2[4];
    #pragma unroll
    for (int tn = 0; tn < 4; tn++) c2[tn] = 0.5f * cs2[cbase + wc * 64 + tn * 16 + fr];

    #pragma unroll
    for (int tm = 0; tm < 4; tm++) {
        #pragma unroll
        for (int r = 0; r < 4; r++) {
            float m4 = -3.0e38f;
            #pragma unroll
            for (int tn = 0; tn < 4; tn++) {
                float s = acc[tm][tn][r] - c2[tn];
                m4 = fmaxf(m4, s);
            }
            #pragma unroll
            for (int off = 1; off < 16; off <<= 1)
                m4 = fmaxf(m4, __shfl_xor(m4, off));
            if (fr == 0) wmaxs[w][tm * 16 + fg * 4 + r] = m4;
        }
    }
    __syncthreads();
    if (tid < VQTOK) {
        int wrt = tid >> 6, tlc = tid & 63;
        tokmax[tid] = fmaxf(fmaxf(wmaxs[wrt * 4 + 0][tlc], wmaxs[wrt * 4 + 1][tlc]),
                            fmaxf(wmaxs[wrt * 4 + 2][tlc], wmaxs[wrt * 4 + 3][tlc]));
    }
    __syncthreads();

    #pragma unroll
    for (int tm = 0; tm < 4; tm++) {
        #pragma unroll
        for (int r = 0; r < 4; r++) {
            int token = wr * 64 + tm * 16 + fg * 4 + r;
            float thr = tokmax[token] - MARGIN;
            #pragma unroll
            for (int tn = 0; tn < 4; tn++) {
                float s = acc[tm][tn][r] - c2[tn];
                if (s > thr) {
                    int pos = atomicAdd(&ccnt[token], 1);
                    if (pos < CAND_CAP) {
                        uint2 cd;
                        cd.x = __float_as_uint(s);
                        cd.y = (unsigned)(cbase + wc * 64 + tn * 16 + fr);
                        cland[token][pos] = cd;
                    }
                }
            }
        }
    }
    __syncthreads();

    if (tid < VQTOK) {
        int tl = base + tid;
        if (tl < count) {
            smax[(size_t)tl * SPLIT + slice] = tokmax[tid];
            scnt[(size_t)tl * SPLIT + slice] = min(ccnt[tid], CAND_CAP);
        }
    }
    for (int i = tid; i < VQTOK * CAND_CAP; i += 512) {
        int token = i >> 4, j = i & (CAND_CAP - 1);
        int tl = base + token;
        if (tl < count && j < min(ccnt[token], CAND_CAP))
            cand[((size_t)tl * SPLIT + slice) * CAND_CAP + j] = cland[token][j];
    }
}

// ---------------- merged exact fp64 rescore + FUSED gather/loss/y ----------------
__global__ __launch_bounds__(256) void vq_rescore_all(float* __restrict__ xp,
                                                      const float* __restrict__ cb_h,
                                                      const float* __restrict__ smaxH,
                                                      const int* __restrict__ scntH,
                                                      const uint2* __restrict__ candH,
                                                      const int* __restrict__ hlist,
                                                      const float* __restrict__ cb_l,
                                                      const float* __restrict__ smaxL,
                                                      const int* __restrict__ scntL,
                                                      const uint2* __restrict__ candL,
                                                      const int* __restrict__ llist,
                                                      const int* __restrict__ counts,
                                                      int* __restrict__ out_idx,
                                                      const float* __restrict__ noise,
                                                      const float* __restrict__ h_ri,
                                                      const float* __restrict__ score,
                                                      float* __restrict__ lh,
                                                      float* __restrict__ ll) {
    const int HB = T_TOK / 4;
    int bx = blockIdx.x;
    const float* cb; const float* smax; const int* scnt; const uint2* cand; const int* list;
    int count, SPLIT, cidx;
    if (bx < HB) {
        cb = cb_h; smax = smaxH; scnt = scntH; cand = candH; list = hlist;
        count = counts[0]; SPLIT = SPL_H; cidx = 0;
    } else {
        bx -= HB;
        cb = cb_l; smax = smaxL; scnt = scntL; cand = candL; list = llist;
        count = counts[1]; SPLIT = 1; cidx = 1;
    }
    const int wid = threadIdx.x >> 6;
    const int lane = threadIdx.x & 63;
    const int tl = bx * 4 + wid;
    if (tl >= count) return;

    float gm = -3.0e38f;
    if (lane < SPLIT) gm = smax[(size_t)tl * SPLIT + lane];
    #pragma unroll
    for (int off = 1; off < 64; off <<= 1)
        gm = fmaxf(gm, __shfl_xor(gm, off));
    const float thr = gm - MARGIN;

    const int t = list[tl];
    float xv[8];
    #pragma unroll
    for (int kk = 0; kk < 8; kk++) xv[kk] = xp[(size_t)t * DQ + lane * 8 + kk];

    double bs = -1.0e300;
    int bi = 0x7fffffff;
    for (int s = 0; s < SPLIT; s++) {
        int cn = scnt[(size_t)tl * SPLIT + s];
        for (int j = 0; j < cn; j++) {
            uint2 cd = cand[((size_t)tl * SPLIT + s) * CAND_CAP + j];
            float av = __uint_as_float(cd.x);
            if (av >= thr) {
                int code = (int)cd.y;
                const float* crow = cb + (size_t)code * DQ;
                double dot = 0.0, nrm = 0.0;
                #pragma unroll
                for (int kk = 0; kk < 8; kk++) {
                    double cv = (double)crow[lane * 8 + kk];
                    dot += (double)xv[kk] * cv;
                    nrm += cv * cv;
                }
                #pragma unroll
                for (int off = 1; off < 64; off <<= 1) {
                    dot += __shfl_xor(dot, off);
                    nrm += __shfl_xor(nrm, off);
                }
                double sc = dot - 0.5 * nrm;
                if (sc > bs || (sc == bs && code < bi)) { bs = sc; bi = code; }
            }
        }
    }
    const float* qrow = cb + (size_t)bi * DQ;
    float4 q0 = *(const float4*)(qrow + lane * 8);
    float4 q1 = *(const float4*)(qrow + lane * 8 + 4);
    const float* nz = noise + (size_t)t * DQ;
    float4 n0 = *(const float4*)(nz + lane * 8);
    float4 n1 = *(const float4*)(nz + lane * 8 + 4);
    float ds = 0.f, dx;
    dx = xv[0] - q0.x; ds += dx * dx;
    dx = xv[1] - q0.y; ds += dx * dx;
    dx = xv[2] - q0.z; ds += dx * dx;
    dx = xv[3] - q0.w; ds += dx * dx;
    dx = xv[4] - q1.x; ds += dx * dx;
    dx = xv[5] - q1.y; ds += dx * dx;
    dx = xv[6] - q1.z; ds += dx * dx;
    dx = xv[7] - q1.w; ds += dx * dx;
    ds = wave_reduce_sum(ds);
    int bbt = t / SEQ;
    float hh0 = h_ri[bbt * 2], hh1 = h_ri[bbt * 2 + 1];
    float hh = sqrtf((hh0 * hh0 + hh1 * hh1) * 0.5f);
    float cc = sqrtf(1e-3f) / hh;
    float4 y0, y1;
    y0.x = q0.x + cc * n0.x; y0.y = q0.y + cc * n0.y;
    y0.z = q0.z + cc * n0.z; y0.w = q0.w + cc * n0.w;
    y1.x = q1.x + cc * n1.x; y1.y = q1.y + cc * n1.y;
    y1.z = q1.z + cc * n1.z; y1.w = q1.w + cc * n1.w;
    *(float4*)(xp + (size_t)t * DQ + lane * 8) = y0;
    *(float4*)(xp + (size_t)t * DQ + lane * 8 + 4) = y1;
    if (lane == 0) {
        out_idx[t] = bi;
        float loss = 1.25f * ds * (1.f / DQ);
        float sc = score[t];
        if (cidx == 0) { lh[t] = loss * sc;  ll[t] = 0.f; }
        else           { lh[t] = 0.f;        ll[t] = loss * (1.f - sc); }
    }
}

// ---------------- FALLBACK fp32 VQ (unchanged) ----------------
template<int NC, int SPLIT>
__global__ __launch_bounds__(256) void vq_partial(const float* __restrict__ xp,
                                                  const float* __restrict__ cb,
                                                  const float* __restrict__ cs2,
                                                  const int* __restrict__ list,
                                                  const int* __restrict__ counts,
                                                  int cidx,
                                                  float* __restrict__ part_s,
                                                  int* __restrict__ part_i) {
    const int count = counts[cidx];
    const int base = blockIdx.x * 64;
    if (base >= count) return;
    const int CODES = NC / SPLIT;
    const int cbase = blockIdx.y * CODES;
    __shared__ float As[32][68];
    __shared__ float Cs[32][68];
    __shared__ int rows_s[64];
    const int tid = threadIdx.x;
    if (tid < 64) {
        int tl = base + tid;
        rows_s[tid] = list[tl < count ? tl : (count - 1)];
    }
    __syncthreads();
    const int tx = tid & 15, ty = tid >> 4;
    float best_s[4];
    int best_i[4];
    #pragma unroll
    for (int i = 0; i < 4; i++) { best_s[i] = -3.0e38f; best_i[i] = 0; }
    for (int c0 = cbase; c0 < cbase + CODES; c0 += 64) {
        float acc[4][4] = {};
        for (int k0 = 0; k0 < DQ; k0 += 32) {
            {
                int e = tid;
                int r = e >> 3, c4 = e & 7;
                float4 v = *(const float4*)(xp + (size_t)rows_s[r] * DQ + k0 + c4 * 4);
                As[c4*4+0][r] = v.x; As[c4*4+1][r] = v.y; As[c4*4+2][r] = v.z; As[c4*4+3][r] = v.w;
                e = tid + 256; r = e >> 3; c4 = e & 7;
                v = *(const float4*)(xp + (size_t)rows_s[r] * DQ + k0 + c4 * 4);
                As[c4*4+0][r] = v.x; As[c4*4+1][r] = v.y; As[c4*4+2][r] = v.z; As[c4*4+3][r] = v.w;
            }
            {
                int e = tid;
                int r = e >> 3, c4 = e & 7;
                float4 v = *(const float4*)(cb + (size_t)(c0 + r) * DQ + k0 + c4 * 4);
                Cs[c4*4+0][r] = v.x; Cs[c4*4+1][r] = v.y; Cs[c4*4+2][r] = v.z; Cs[c4*4+3][r] = v.w;
                e = tid + 256; r = e >> 3; c4 = e & 7;
                v = *(const float4*)(cb + (size_t)(c0 + r) * DQ + k0 + c4 * 4);
                Cs[c4*4+0][r] = v.x; Cs[c4*4+1][r] = v.y; Cs[c4*4+2][r] = v.z; Cs[c4*4+3][r] = v.w;
            }
            __syncthreads();
            #pragma unroll
            for (int k = 0; k < 32; k++) {
                float4 a = *(const float4*)&As[k][ty * 4];
                float4 b = *(const float4*)&Cs[k][tx * 4];
                float av[4] = {a.x, a.y, a.z, a.w};
                float bv[4] = {b.x, b.y, b.z, b.w};
                #pragma unroll
                for (int i = 0; i < 4; i++)
                    #pragma unroll
                    for (int j = 0; j < 4; j++)
                        acc[i][j] += av[i] * bv[j];
            }
            __syncthreads();
        }
        float4 c2v = *(const float4*)(cs2 + c0 + tx * 4);
        float c2[4] = {c2v.x, c2v.y, c2v.z, c2v.w};
        #pragma unroll
        for (int i = 0; i < 4; i++) {
            float s = acc[i][0] - 0.5f * c2[0];
            int bi = c0 + tx * 4;
            #pragma unroll
            for (int j = 1; j < 4; j++) {
                float sj = acc[i][j] - 0.5f * c2[j];
                if (sj > s) { s = sj; bi = c0 + tx * 4 + j; }
            }
            #pragma unroll
            for (int off = 1; off < 16; off <<= 1) {
                float os = __shfl_xor(s, off);
                int oi = __shfl_xor(bi, off);
                if (os > s || (os == s && oi < bi)) { s = os; bi = oi; }
            }
            if (s > best_s[i] || (s == best_s[i] && bi < best_i[i])) {
                best_s[i] = s; best_i[i] = bi;
            }
        }
    }
    if (tx == 0) {
        #pragma unroll
        for (int i = 0; i < 4; i++) {
            int tl = base + ty * 4 + i;
            if (tl < count) {
                part_s[(size_t)tl * SPLIT + blockIdx.y] = best_s[i];
                part_i[(size_t)tl * SPLIT + blockIdx.y] = best_i[i];
            }
        }
    }
}

template<int SPLIT>
__global__ __launch_bounds__(256) void vq_reduce(const float* __restrict__ part_s,
                                                 const int* __restrict__ part_i,
                                                 const int* __restrict__ list,
                                                 const int* __restrict__ counts,
                                                 int cidx,
                                                 int* __restrict__ out_idx) {
    int tl = blockIdx.x * 256 + threadIdx.x;
    if (tl >= counts[cidx]) return;
    float bs = part_s[(size_t)tl * SPLIT];
    int bi = part_i[(size_t)tl * SPLIT];
    #pragma unroll
    for (int s = 1; s < SPLIT; s++) {
        float v = part_s[(size_t)tl * SPLIT + s];
        int vi = part_i[(size_t)tl * SPLIT + s];
        if (v > bs || (v == bs && vi < bi)) { bs = v; bi = vi; }
    }
    out_idx[list[tl]] = bi;
}

// ---------------- gather q, per-token loss, y (fallback path only) ----------------
__global__ __launch_bounds__(256) void gather_loss_y(float* __restrict__ xp,
                                                     const float* __restrict__ cb_h,
                                                     const float* __restrict__ cb_l,
                                                     const int* __restrict__ idx,
                                                     const float* __restrict__ score,
                                                     const int* __restrict__ mask,
                                                     const float* __restrict__ noise,
                                                     const float* __restrict__ h_ri,
                                                     float* __restrict__ lh,
                                                     float* __restrict__ ll) {
    int t = blockIdx.x * 4 + (threadIdx.x >> 6);
    int lane = threadIdx.x & 63;
    int m = mask[t];
    float sc = score[t];
    const float* q = (m ? cb_h : cb_l) + (size_t)idx[t] * DQ;
    float* x = xp + (size_t)t * DQ;
    const float* nz = noise + (size_t)t * DQ;
    int bb = t / SEQ;
    float h0 = h_ri[bb * 2], h1 = h_ri[bb * 2 + 1];
    float h = sqrtf((h0 * h0 + h1 * h1) * 0.5f);
    float c = sqrtf(1e-3f) / h;
    float4 xv0 = *(float4*)(x + lane * 4);
    float4 xv1 = *(float4*)(x + 256 + lane * 4);
    float4 qv0 = *(const float4*)(q + lane * 4);
    float4 qv1 = *(const float4*)(q + 256 + lane * 4);
    float4 nv0 = *(const float4*)(nz + lane * 4);
    float4 nv1 = *(const float4*)(nz + 256 + lane * 4);
    float dx, ds = 0.f;
    dx = xv0.x - qv0.x; ds += dx * dx;
    dx = xv0.y - qv0.y; ds += dx * dx;
    dx = xv0.z - qv0.z; ds += dx * dx;
    dx = xv0.w - qv0.w; ds += dx * dx;
    dx = xv1.x - qv1.x; ds += dx * dx;
    dx = xv1.y - qv1.y; ds += dx * dx;
    dx = xv1.z - qv1.z; ds += dx * dx;
    dx = xv1.w - qv1.w; ds += dx * dx;
    ds = wave_reduce_sum(ds);
    float4 y0, y1;
    y0.x = qv0.x + c * nv0.x; y0.y = qv0.y + c * nv0.y;
    y0.z = qv0.z + c * nv0.z; y0.w = qv0.w + c * nv0.w;
    y1.x = qv1.x + c * nv1.x; y1.y = qv1.y + c * nv1.y;
    y1.z = qv1.z + c * nv1.z; y1.w = qv1.w + c * nv1.w;
    *(float4*)(x + lane * 4) = y0;
    *(float4*)(x + 256 + lane * 4) = y1;
    if (lane == 0) {
        float loss = 1.25f * ds * (1.f / DQ);
        lh[t] = m ? loss * sc : 0.f;
        ll[t] = m ? 0.f : loss * (1.f - sc);
    }
}

// ---------------- deterministic loss reduction (fallback path only) ----------------
__global__ __launch_bounds__(256) void loss_reduce(const float* __restrict__ lh,
                                                   const float* __restrict__ ll,
                                                   const int* __restrict__ counts,
                                                   float* __restrict__ out) {
    __shared__ float sh[256], sl[256];
    int tid = threadIdx.x;
    float ah = 0.f, al = 0.f;
    for (int t = tid; t < T_TOK; t += 256) { ah += lh[t]; al += ll[t]; }
    sh[tid] = ah; sl[tid] = al;
    __syncthreads();
    for (int o = 128; o > 0; o >>= 1) {
        if (tid < o) { sh[tid] += sh[tid + o]; sl[tid] += sl[tid + o]; }
        __syncthreads();
    }
    if (tid == 0) {
        int nh = counts[0];
        int nl = T_TOK - nh;
        nh = nh > 1 ? nh : 1;
        nl = nl > 1 ? nl : 1;
        out[(size_t)T_TOK * DD] = 0.5f * (sh[0] / (float)nh + sl[0] / (float)nl);
    }
}

// ---------------- fp32 dec (fallback only) ----------------
__global__ __launch_bounds__(256) void dec_gemm(const float* __restrict__ Y,
                                                const float* __restrict__ W,
                                                const float* __restrict__ bias,
                                                float* __restrict__ out) {
    __shared__ float As[32][66];
    __shared__ float Bs[32][64];
    const int m0 = blockIdx.x * 64, n0 = blockIdx.y * 64;
    const int tid = threadIdx.x;
    const int tx = tid & 15, ty = tid >> 4;
    float acc[4][4] = {};
    for (int k0 = 0; k0 < DQ; k0 += 32) {
        {
            int e = tid;
            int r = e >> 3, c4 = e & 7;
            float4 v = *(const float4*)(Y + (size_t)(m0 + r) * DQ + k0 + c4 * 4);
            As[c4*4+0][r] = v.x; As[c4*4+1][r] = v.y; As[c4*4+2][r] = v.z; As[c4*4+3][r] = v.w;
            e = tid + 256; r = e >> 3; c4 = e & 7;
            v = *(const float4*)(Y + (size_t)(m0 + r) * DQ + k0 + c4 * 4);
            As[c4*4+0][r] = v.x; As[c4*4+1][r] = v.y; As[c4*4+2][r] = v.z; As[c4*4+3][r] = v.w;
        }
        {
            int e = tid;
            int kk = e >> 4, c4 = e & 15;
            *(float4*)&Bs[kk][c4*4] = *(const float4*)(W + (size_t)(k0 + kk) * DD + n0 + c4 * 4);
            e = tid + 256; kk = e >> 4; c4 = e & 15;
            *(float4*)&Bs[kk][c4*4] = *(const float4*)(W + (size_t)(k0 + kk) * DD + n0 + c4 * 4);
        }
        __syncthreads();
        #pragma unroll
        for (int k = 0; k < 32; k++) {
            float2 a01 = *(const float2*)&As[k][ty * 4];
            float2 a23 = *(const float2*)&As[k][ty * 4 + 2];
            float4 b = *(const float4*)&Bs[k][tx * 4];
            float av[4] = {a01.x, a01.y, a23.x, a23.y};
            float bv[4] = {b.x, b.y, b.z, b.w};
            #pragma unroll
            for (int i = 0; i < 4; i++)
                #pragma unroll
                for (int j = 0; j < 4; j++)
                    acc[i][j] += av[i] * bv[j];
        }
        __syncthreads();
    }
    float4 bv4 = *(const float4*)(bias + n0 + tx * 4);
    float bbv[4] = {bv4.x, bv4.y, bv4.z, bv4.w};
    #pragma unroll
    for (int i = 0; i < 4; i++) {
        int row = m0 + ty * 4 + i;
        float4 o;
        o.x = acc[i][0] + bbv[0];
        o.y = acc[i][1] + bbv[1];
        o.z = acc[i][2] + bbv[2];
        o.w = acc[i][3] + bbv[3];
        *(float4*)(out + (size_t)row * DD + n0 + tx * 4) = o;
    }
}

extern "C" void kernel_launch(void* const* d_in, const int* in_sizes, int n_in,
                              void* d_out, int out_size, void* d_ws, size_t ws_size,
                              hipStream_t stream) {
    const float* x_tokens = (const float*)d_in[0];
    const float* fim      = (const float*)d_in[1];
    const float* W_proj   = (const float*)d_in[2];
    const float* b_proj   = (const float*)d_in[3];
    const float* ln_g     = (const float*)d_in[4];
    const float* ln_b     = (const float*)d_in[5];
    const float* cb_high  = (const float*)d_in[6];
    const float* cb_low   = (const float*)d_in[7];
    const float* W_dec    = (const float*)d_in[8];
    const float* b_dec    = (const float*)d_in[9];
    const float* h_ri     = (const float*)d_in[10];
    const float* noise    = (const float*)d_in[11];
    float* out = (float*)d_out;

    char* ws = (char*)d_ws;
    size_t off = 0;
    float* xp = (float*)(ws + off);     off += (size_t)T_TOK * DQ * 4;
    int*   idxb = (int*)(ws + off);     off += (size_t)T_TOK * 4;
    float* score = (float*)(ws + off);  off += (size_t)T_TOK * 4;
    int*   mask = (int*)(ws + off);     off += (size_t)T_TOK * 4;
    float* lh = (float*)(ws + off);     off += (size_t)T_TOK * 4;
    float* ll = (float*)(ws + off);     off += (size_t)T_TOK * 4;
    int*   hlist = (int*)(ws + off);    off += (size_t)T_TOK * 4;
    int*   llist = (int*)(ws + off);    off += (size_t)T_TOK * 4;
    int*   counts = (int*)(ws + off);   off += 64;
    float* cs2h = (float*)(ws + off);   off += (size_t)NCH * 4;
    float* cs2l = (float*)(ws + off);   off += (size_t)NCL * 4;
    size_t off_common = off;

    unsigned short* xpB  = (unsigned short*)(ws + off); off += (size_t)T_TOK * DQ * 2;
    unsigned short* cbhB = (unsigned short*)(ws + off); off += (size_t)NCH * DQ * 2;
    unsigned short* cblB = (unsigned short*)(ws + off); off += (size_t)NCL * DQ * 2;
    float* smaxH = (float*)(ws + off);  off += (size_t)T_TOK * SPL_H * 4;
    int*   scntH = (int*)(ws + off);    off += (size_t)T_TOK * SPL_H * 4;
    uint2* candH = (uint2*)(ws + off);  off += (size_t)T_TOK * SPL_H * CAND_CAP * 8;
    float* smaxL = (float*)(ws + off);  off += (size_t)T_TOK * 4;
    int*   scntL = (int*)(ws + off);    off += (size_t)T_TOK * 4;
    uint2* candL = (uint2*)(ws + off);  off += (size_t)T_TOK * CAND_CAP * 8;
    unsigned short* WThi  = (unsigned short*)(ws + off); off += (size_t)DQ * DE * 2;
    unsigned short* WTlo  = (unsigned short*)(ws + off); off += (size_t)DQ * DE * 2;
    unsigned short* WdThi = (unsigned short*)(ws + off); off += (size_t)DD * DQ * 2;
    unsigned short* WdTlo = (unsigned short*)(ws + off); off += (size_t)DD * DQ * 2;
    size_t need_new = off;
    const bool use_mfma = ws_size >= need_new;

    if (use_mfma) {
        prep_all<<<1856, 256, 0, stream>>>(cb_high, cs2h, cbhB, cb_low, cs2l, cblB,
                                           W_proj, WThi, WTlo, W_dec, WdThi, WdTlo, counts);
        gemm_mfma3_128<DE, DQ><<<dim3(T_TOK / 128, DQ / 128), 256, 0, stream>>>(
            x_tokens, WThi, WTlo, b_proj, xp);
        ln_route_compact<<<T_TOK / 32, 256, 0, stream>>>(
            xp, ln_g, ln_b, fim, score, xpB, hlist, llist, counts);
        vq_mfma_all<<<dim3(T_TOK / VQTOK, SPL_H + 1), 512, 0, stream>>>(
            xpB, cbhB, cs2h, hlist, cblB, cs2l, llist, counts,
            smaxH, scntH, candH, smaxL, scntL, candL);
        vq_rescore_all<<<2 * (T_TOK / 4), 256, 0, stream>>>(
            xp, cb_high, smaxH, scntH, candH, hlist,
            cb_low, smaxL, scntL, candL, llist,
            counts, idxb, noise, h_ri, score, lh, ll);
        dec_mfma3_loss<<<dim3(T_TOK / 64 + 1, DD / 64), 256, 0, stream>>>(
            xp, WdThi, WdTlo, b_dec, out, lh, ll, counts);
    } else {
        code_sumsq<NCH><<<NCH / 4, 256, 0, stream>>>(cb_high, cs2h);
        code_sumsq<NCL><<<NCL / 4, 256, 0, stream>>>(cb_low, cs2l);
        proj_gemm<<<dim3(T_TOK / 64, DQ / 64), 256, 0, stream>>>(x_tokens, W_proj, b_proj, xp);
        ln_route<<<T_TOK / 4, 256, 0, stream>>>(xp, ln_g, ln_b, fim, score, mask, nullptr);
        scan_compact<<<1, 1024, 0, stream>>>(mask, hlist, llist, counts);
        float* part_s = (float*)(ws + off_common);
        int*   part_i = (int*)(ws + off_common + (size_t)T_TOK * 16 * 4);
        vq_partial<NCH, 16><<<dim3(T_TOK / 64, 16), 256, 0, stream>>>(
            xp, cb_high, cs2h, hlist, counts, 0, part_s, part_i);
        vq_reduce<16><<<(T_TOK + 255) / 256, 256, 0, stream>>>(part_s, part_i, hlist, counts, 0, idxb);
        vq_partial<NCL, 4><<<dim3(T_TOK / 64, 4), 256, 0, stream>>>(
            xp, cb_low, cs2l, llist, counts, 1, part_s, part_i);
        vq_reduce<4><<<(T_TOK + 255) / 256, 256, 0, stream>>>(part_s, part_i, llist, counts, 1, idxb);
        gather_loss_y<<<T_TOK / 4, 256, 0, stream>>>(xp, cb_high, cb_low, idxb, score, mask,
                                                     noise, h_ri, lh, ll);
        loss_reduce<<<1, 256, 0, stream>>>(lh, ll, counts, out);
        dec_gemm<<<dim3(T_TOK / 64, DD / 64), 256, 0, stream>>>(xp, W_dec, b_dec, out);
    }
}

// Round 26
// 183.307 us; speedup vs baseline: 1.1982x; 1.0800x over previous
//
#include <hip/hip_runtime.h>
#include <math.h>

#define T_TOK 12544   // 64*196
#define DE 768
#define DQ 512
#define DD 256
#define SEQ 196
#define NCH 4096
#define NCL 256
#define SPL_H 16      // high codebook: 16 slices of 256 codes
#define CODES_PER_BLK 256
#define MARGIN 2.0f
#define CAND_CAP 16
#define VQTOK 128     // tokens per vq block (128x256 tile, 8 waves)

typedef __attribute__((ext_vector_type(8))) short s16x8;
typedef __attribute__((ext_vector_type(4))) float f32x4;

__device__ __forceinline__ float wave_reduce_sum(float v) {
    #pragma unroll
    for (int off = 32; off > 0; off >>= 1) v += __shfl_xor(v, off);
    return v;
}

__device__ __forceinline__ unsigned short f2bf(float f) {
    unsigned int u = __float_as_uint(f);
    u = (u + 0x7fffu + ((u >> 16) & 1u)) >> 16;
    return (unsigned short)u;
}
__device__ __forceinline__ float bf2f(unsigned short h) {
    return __uint_as_float(((unsigned int)h) << 16);
}

// async global->LDS 16B: dest = wave-uniform base + lane*16 (pre-swizzled source)
__device__ __forceinline__ void gload_lds16(const unsigned short* g, unsigned short* l) {
    __builtin_amdgcn_global_load_lds(
        (const __attribute__((address_space(1))) void*)g,
        (__attribute__((address_space(3))) void*)l,
        16, 0, 0);
}

// ---------------- device helpers for merged preprocessing ----------------
__device__ __forceinline__ void sumsq_body(const float* __restrict__ cb,
                                           float* __restrict__ cs2,
                                           unsigned short* __restrict__ cbB,
                                           int blk, int NC) {
    int row = blk * 4 + (threadIdx.x >> 6);
    int lane = threadIdx.x & 63;
    if (row >= NC) return;
    const float4* p = (const float4*)(cb + (size_t)row * DQ);
    float4 a = p[lane];
    float4 b = p[lane + 64];
    if (cbB) {
        unsigned short* dst = cbB + (size_t)row * DQ;
        ushort4 ha, hb;
        ha.x = f2bf(a.x); ha.y = f2bf(a.y); ha.z = f2bf(a.z); ha.w = f2bf(a.w);
        hb.x = f2bf(b.x); hb.y = f2bf(b.y); hb.z = f2bf(b.z); hb.w = f2bf(b.w);
        *(ushort4*)(dst + lane * 4) = ha;
        *(ushort4*)(dst + 256 + lane * 4) = hb;
    }
    float s = a.x*a.x + a.y*a.y + a.z*a.z + a.w*a.w
            + b.x*b.x + b.y*b.y + b.z*b.z + b.w*b.w;
    s = wave_reduce_sum(s);
    if (lane == 0) cs2[row] = s;
}

__device__ __forceinline__ void split_body(const float* __restrict__ W, int K, int N,
                                           unsigned short* __restrict__ Thi,
                                           unsigned short* __restrict__ Tlo,
                                           int blk, int nb) {
    int total = K * N;
    for (int idx = blk * 256 + threadIdx.x; idx < total; idx += nb * 256) {
        int n = idx / K, k = idx - n * K;
        float v = W[(size_t)k * N + n];
        unsigned short h = f2bf(v);
        Thi[idx] = h;
        Tlo[idx] = f2bf(v - bf2f(h));
    }
}

// ---------------- merged preprocessing: sumsq(H,L) + splitW(proj,dec) + counter zero ----------------
__global__ __launch_bounds__(256) void prep_all(const float* __restrict__ cb_h,
                                                float* __restrict__ cs2h,
                                                unsigned short* __restrict__ cbhB,
                                                const float* __restrict__ cb_l,
                                                float* __restrict__ cs2l,
                                                unsigned short* __restrict__ cblB,
                                                const float* __restrict__ Wp,
                                                unsigned short* __restrict__ WThi,
                                                unsigned short* __restrict__ WTlo,
                                                const float* __restrict__ Wd,
                                                unsigned short* __restrict__ WdThi,
                                                unsigned short* __restrict__ WdTlo,
                                                int* __restrict__ counts) {
    int blk = blockIdx.x;
    if (blk == 0 && threadIdx.x == 0) { counts[0] = 0; counts[1] = 0; }
    if (blk < 1024)       sumsq_body(cb_h, cs2h, cbhB, blk, NCH);
    else if (blk < 1088)  sumsq_body(cb_l, cs2l, cblB, blk - 1024, NCL);
    else if (blk < 1600)  split_body(Wp, DE, DQ, WThi, WTlo, blk - 1088, 512);
    else                  split_body(Wd, DQ, DD, WdThi, WdTlo, blk - 1600, 256);
}

// ---------------- fallback code_sumsq (fp32 path only) ----------------
template<int NC>
__global__ __launch_bounds__(256) void code_sumsq(const float* __restrict__ cb,
                                                  float* __restrict__ cs2) {
    sumsq_body(cb, cs2, nullptr, blockIdx.x, NC);
}

// ---------------- proj via 3-term split-bf16 MFMA, 128x128 tile (r23 proven) ----------------
template<int KDIM, int NSTRIDE>
__global__ __launch_bounds__(256) void gemm_mfma3_128(const float* __restrict__ A,
                                                      const unsigned short* __restrict__ BThi,
                                                      const unsigned short* __restrict__ BTlo,
                                                      const float* __restrict__ bias,
                                                      float* __restrict__ out) {
    __shared__ __align__(16) unsigned short Ahi[128 * 32];
    __shared__ __align__(16) unsigned short Alo[128 * 32];
    __shared__ __align__(16) unsigned short Bhi[128 * 32];
    __shared__ __align__(16) unsigned short Blo[128 * 32];
    const int m0 = blockIdx.x * 128, n0 = blockIdx.y * 128;
    const int tid = threadIdx.x, lane = tid & 63, w = tid >> 6;
    const int wr = w >> 1, wc = w & 1;
    const int arow = tid >> 1, ahalf = tid & 1;

    const int cb0 = w * 2, cb1 = w * 2 + 1;
    const int gcol0 = n0 + cb0 * 16 + (lane >> 2);
    const int gcol1 = n0 + cb1 * 16 + (lane >> 2);
    const int ch0 = (lane & 3) ^ ((gcol0 >> 1) & 3);
    const int ch1 = (lane & 3) ^ ((gcol1 >> 1) & 3);
    const unsigned short* sH0 = BThi + (size_t)gcol0 * KDIM + ch0 * 8;
    const unsigned short* sH1 = BThi + (size_t)gcol1 * KDIM + ch1 * 8;
    const unsigned short* sL0 = BTlo + (size_t)gcol0 * KDIM + ch0 * 8;
    const unsigned short* sL1 = BTlo + (size_t)gcol1 * KDIM + ch1 * 8;

    f32x4 acc[4][4] = {};
    const int NT = KDIM / 32;
    for (int t = 0; t < NT; t++) {
        const int k0 = t * 32;
        gload_lds16(sH0 + k0, Bhi + cb0 * 512);
        gload_lds16(sH1 + k0, Bhi + cb1 * 512);
        gload_lds16(sL0 + k0, Blo + cb0 * 512);
        gload_lds16(sL1 + k0, Blo + cb1 * 512);
        {
            const float* src = A + (size_t)(m0 + arow) * KDIM + k0 + ahalf * 16;
            float4 v0 = *(const float4*)(src + 0);
            float4 v1 = *(const float4*)(src + 4);
            float4 v2 = *(const float4*)(src + 8);
            float4 v3 = *(const float4*)(src + 12);
            float xv[16] = {v0.x,v0.y,v0.z,v0.w, v1.x,v1.y,v1.z,v1.w,
                            v2.x,v2.y,v2.z,v2.w, v3.x,v3.y,v3.z,v3.w};
            const int swzA = (arow >> 1) & 3;
            #pragma unroll
            for (int cc = 0; cc < 2; cc++) {
                unsigned int hw[4], lw[4];
                #pragma unroll
                for (int j = 0; j < 4; j++) {
                    float f0 = xv[cc*8 + 2*j], f1 = xv[cc*8 + 2*j + 1];
                    unsigned short h0 = f2bf(f0), h1 = f2bf(f1);
                    unsigned short l0 = f2bf(f0 - bf2f(h0));
                    unsigned short l1 = f2bf(f1 - bf2f(h1));
                    hw[j] = (unsigned)h0 | ((unsigned)h1 << 16);
                    lw[j] = (unsigned)l0 | ((unsigned)l1 << 16);
                }
                int c = ahalf * 2 + cc;
                int doff = arow * 32 + (c ^ swzA) * 8;
                *(uint4*)&Ahi[doff] = make_uint4(hw[0], hw[1], hw[2], hw[3]);
                *(uint4*)&Alo[doff] = make_uint4(lw[0], lw[1], lw[2], lw[3]);
            }
        }
        __syncthreads();
        const int fr = lane & 15, fs = lane >> 4;
        s16x8 ah[4], al[4];
        #pragma unroll
        for (int tm = 0; tm < 4; tm++) {
            int row = wr * 64 + tm * 16 + fr;
            int off = row * 32 + (fs ^ ((row >> 1) & 3)) * 8;
            ah[tm] = *(const s16x8*)&Ahi[off];
            al[tm] = *(const s16x8*)&Alo[off];
        }
        #pragma unroll
        for (int tn = 0; tn < 4; tn++) {
            int col = wc * 64 + tn * 16 + fr;
            int boff = col * 32 + (fs ^ ((col >> 1) & 3)) * 8;
            s16x8 bh = *(const s16x8*)&Bhi[boff];
            s16x8 bl = *(const s16x8*)&Blo[boff];
            #pragma unroll
            for (int tm = 0; tm < 4; tm++) {
                acc[tm][tn] = __builtin_amdgcn_mfma_f32_16x16x32_bf16(ah[tm], bh, acc[tm][tn], 0, 0, 0);
                acc[tm][tn] = __builtin_amdgcn_mfma_f32_16x16x32_bf16(ah[tm], bl, acc[tm][tn], 0, 0, 0);
                acc[tm][tn] = __builtin_amdgcn_mfma_f32_16x16x32_bf16(al[tm], bh, acc[tm][tn], 0, 0, 0);
            }
        }
        __syncthreads();
    }
    const int fr = lane & 15, fg = lane >> 4;
    #pragma unroll
    for (int tn = 0; tn < 4; tn++) {
        const int col = n0 + wc * 64 + tn * 16 + fr;
        const float bb = bias[col];
        #pragma unroll
        for (int tm = 0; tm < 4; tm++) {
            #pragma unroll
            for (int r = 0; r < 4; r++) {
                int row = m0 + wr * 64 + tm * 16 + fg * 4 + r;
                out[(size_t)row * NSTRIDE + col] = acc[tm][tn][r] + bb;
            }
        }
    }
}

// ---------------- dec (64x64, proven) + FUSED loss reduction block ----------------
__global__ __launch_bounds__(256) void dec_mfma3_loss(const float* __restrict__ A,
                                                      const unsigned short* __restrict__ BThi,
                                                      const unsigned short* __restrict__ BTlo,
                                                      const float* __restrict__ bias,
                                                      float* __restrict__ out,
                                                      const float* __restrict__ lh,
                                                      const float* __restrict__ ll,
                                                      const int* __restrict__ counts) {
    __shared__ __align__(16) unsigned short Ahi[2][64 * 32];
    __shared__ __align__(16) unsigned short Alo[2][64 * 32];
    __shared__ __align__(16) unsigned short Bhi[2][64 * 32];
    __shared__ __align__(16) unsigned short Blo[2][64 * 32];
    if (blockIdx.x == T_TOK / 64) {
        if (blockIdx.y != 0) return;
        float* sh = (float*)&Ahi[0][0];
        float* sl = sh + 256;
        int tid = threadIdx.x;
        float ah = 0.f, al = 0.f;
        for (int t = tid; t < T_TOK; t += 256) { ah += lh[t]; al += ll[t]; }
        sh[tid] = ah; sl[tid] = al;
        __syncthreads();
        for (int o = 128; o > 0; o >>= 1) {
            if (tid < o) { sh[tid] += sh[tid + o]; sl[tid] += sl[tid + o]; }
            __syncthreads();
        }
        if (tid == 0) {
            int nh = counts[0];
            int nl = T_TOK - nh;
            nh = nh > 1 ? nh : 1;
            nl = nl > 1 ? nl : 1;
            out[(size_t)T_TOK * DD] = 0.5f * (sh[0] / (float)nh + sl[0] / (float)nl);
        }
        return;
    }
    const int m0 = blockIdx.x * 64, n0 = blockIdx.y * 64;
    const int tid = threadIdx.x, lane = tid & 63, w = tid >> 6;
    const int stok = tid >> 2, sslot = tid & 3;

    f32x4 acc[4] = {};
    float4 av0, av1;
    uint4 bh4, bl4;

    auto loadStep = [&](int k0) {
        const float* src = A + (size_t)(m0 + stok) * DQ + k0 + sslot * 8;
        av0 = *(const float4*)src;
        av1 = *(const float4*)(src + 4);
        size_t soff = (size_t)(n0 + stok) * DQ + k0 + sslot * 8;
        bh4 = *(const uint4*)(BThi + soff);
        bl4 = *(const uint4*)(BTlo + soff);
    };
    auto writeStep = [&](int buf) {
        float xv[8] = {av0.x, av0.y, av0.z, av0.w, av1.x, av1.y, av1.z, av1.w};
        unsigned int hw[4], lw[4];
        #pragma unroll
        for (int j = 0; j < 4; j++) {
            unsigned short h0 = f2bf(xv[2*j]),   h1 = f2bf(xv[2*j+1]);
            unsigned short l0 = f2bf(xv[2*j] - bf2f(h0));
            unsigned short l1 = f2bf(xv[2*j+1] - bf2f(h1));
            hw[j] = (unsigned)h0 | ((unsigned)h1 << 16);
            lw[j] = (unsigned)l0 | ((unsigned)l1 << 16);
        }
        int doffA = stok * 32 + (sslot ^ ((stok >> 1) & 3)) * 8;
        *(uint4*)&Ahi[buf][doffA] = make_uint4(hw[0], hw[1], hw[2], hw[3]);
        *(uint4*)&Alo[buf][doffA] = make_uint4(lw[0], lw[1], lw[2], lw[3]);
        *(uint4*)&Bhi[buf][doffA] = bh4;
        *(uint4*)&Blo[buf][doffA] = bl4;
    };

    loadStep(0); writeStep(0); __syncthreads();
    const int NT = DQ / 32;
    for (int t = 0; t < NT; t++) {
        const int cur = t & 1;
        if (t + 1 < NT) loadStep((t + 1) * 32);
        const int fr = lane & 15, fs = lane >> 4;
        s16x8 ah[4], al[4];
        #pragma unroll
        for (int tm = 0; tm < 4; tm++) {
            int tok = tm * 16 + fr;
            int off = tok * 32 + (sslot, fs ^ ((tok >> 1) & 3)) * 8;
            (void)off;
            off = tok * 32 + (fs ^ ((tok >> 1) & 3)) * 8;
            ah[tm] = *(const s16x8*)&Ahi[cur][off];
            al[tm] = *(const s16x8*)&Alo[cur][off];
        }
        {
            int col = w * 16 + fr;
            int boff = col * 32 + (fs ^ ((col >> 1) & 3)) * 8;
            s16x8 bh = *(const s16x8*)&Bhi[cur][boff];
            s16x8 bl = *(const s16x8*)&Blo[cur][boff];
            #pragma unroll
            for (int tm = 0; tm < 4; tm++) {
                acc[tm] = __builtin_amdgcn_mfma_f32_16x16x32_bf16(ah[tm], bh, acc[tm], 0, 0, 0);
                acc[tm] = __builtin_amdgcn_mfma_f32_16x16x32_bf16(ah[tm], bl, acc[tm], 0, 0, 0);
                acc[tm] = __builtin_amdgcn_mfma_f32_16x16x32_bf16(al[tm], bh, acc[tm], 0, 0, 0);
            }
        }
        if (t + 1 < NT) writeStep(cur ^ 1);
        __syncthreads();
    }
    const int fr = lane & 15, fg = lane >> 4;
    {
        const int col = n0 + w * 16 + fr;
        const float bb = bias[col];
        #pragma unroll
        for (int tm = 0; tm < 4; tm++) {
            #pragma unroll
            for (int r = 0; r < 4; r++) {
                int row = m0 + tm * 16 + fg * 4 + r;
                out[(size_t)row * DD + col] = acc[tm][r] + bb;
            }
        }
    }
}

// ---------------- fp32 proj (fallback only) ----------------
__global__ __launch_bounds__(256) void proj_gemm(const float* __restrict__ X,
                                                 const float* __restrict__ W,
                                                 const float* __restrict__ bias,
                                                 float* __restrict__ out) {
    __shared__ float As[32][66];
    __shared__ float Bs[32][64];
    const int m0 = blockIdx.x * 64, n0 = blockIdx.y * 64;
    const int tid = threadIdx.x;
    const int tx = tid & 15, ty = tid >> 4;
    float acc[4][4] = {};
    for (int k0 = 0; k0 < DE; k0 += 32) {
        {
            int e = tid;
            int r = e >> 3, c4 = e & 7;
            float4 v = *(const float4*)(X + (size_t)(m0 + r) * DE + k0 + c4 * 4);
            As[c4*4+0][r] = v.x; As[c4*4+1][r] = v.y; As[c4*4+2][r] = v.z; As[c4*4+3][r] = v.w;
            e = tid + 256;
            r = e >> 3; c4 = e & 7;
            v = *(const float4*)(X + (size_t)(m0 + r) * DE + k0 + c4 * 4);
            As[c4*4+0][r] = v.x; As[c4*4+1][r] = v.y; As[c4*4+2][r] = v.z; As[c4*4+3][r] = v.w;
        }
        {
            int e = tid;
            int kk = e >> 4, c4 = e & 15;
            *(float4*)&Bs[kk][c4*4] = *(const float4*)(W + (size_t)(k0 + kk) * DQ + n0 + c4 * 4);
            e = tid + 256;
            kk = e >> 4; c4 = e & 15;
            *(float4*)&Bs[kk][c4*4] = *(const float4*)(W + (size_t)(k0 + kk) * DQ + n0 + c4 * 4);
        }
        __syncthreads();
        #pragma unroll
        for (int k = 0; k < 32; k++) {
            float2 a01 = *(const float2*)&As[k][ty * 4];
            float2 a23 = *(const float2*)&As[k][ty * 4 + 2];
            float4 b = *(const float4*)&Bs[k][tx * 4];
            float av[4] = {a01.x, a01.y, a23.x, a23.y};
            float bv[4] = {b.x, b.y, b.z, b.w};
            #pragma unroll
            for (int i = 0; i < 4; i++)
                #pragma unroll
                for (int j = 0; j < 4; j++)
                    acc[i][j] += av[i] * bv[j];
        }
        __syncthreads();
    }
    float4 bv4 = *(const float4*)(bias + n0 + tx * 4);
    float bb[4] = {bv4.x, bv4.y, bv4.z, bv4.w};
    #pragma unroll
    for (int i = 0; i < 4; i++) {
        int row = m0 + ty * 4 + i;
        float4 o;
        o.x = acc[i][0] + bb[0];
        o.y = acc[i][1] + bb[1];
        o.z = acc[i][2] + bb[2];
        o.w = acc[i][3] + bb[3];
        *(float4*)(out + (size_t)row * DQ + n0 + tx * 4) = o;
    }
}

// ---------------- LayerNorm + routing + bf16 emit + FUSED atomic compaction ----------------
__global__ __launch_bounds__(256) void ln_route_compact(float* __restrict__ xp,
                                                        const float* __restrict__ g,
                                                        const float* __restrict__ b,
                                                        const float* __restrict__ logits,
                                                        float* __restrict__ score,
                                                        unsigned short* __restrict__ xpB,
                                                        int* __restrict__ hlist,
                                                        int* __restrict__ llist,
                                                        int* __restrict__ counts) {
    __shared__ int hloc[32], lloc[32];
    __shared__ int nh_s, nl_s, bh_s, bl_s;
    const int tid = threadIdx.x, lane = tid & 63, wv = tid >> 6;
    if (tid == 0) { nh_s = 0; nl_s = 0; }
    __syncthreads();
    float4 g0 = *(const float4*)(g + lane * 4);
    float4 g1 = *(const float4*)(g + 256 + lane * 4);
    float4 b0 = *(const float4*)(b + lane * 4);
    float4 b1 = *(const float4*)(b + 256 + lane * 4);
    const int rbase = blockIdx.x * 32 + wv * 8;
    for (int i = 0; i < 8; i++) {
        int row = rbase + i;
        float* p = xp + (size_t)row * DQ;
        float4 v0 = *(float4*)(p + lane * 4);
        float4 v1 = *(float4*)(p + 256 + lane * 4);
        float s  = v0.x + v0.y + v0.z + v0.w + v1.x + v1.y + v1.z + v1.w;
        float ss = v0.x*v0.x + v0.y*v0.y + v0.z*v0.z + v0.w*v0.w
                 + v1.x*v1.x + v1.y*v1.y + v1.z*v1.z + v1.w*v1.w;
        s = wave_reduce_sum(s);
        ss = wave_reduce_sum(ss);
        float m = s * (1.f / DQ);
        float var = ss * (1.f / DQ) - m * m;
        float scale = rsqrtf(var + 1e-5f);
        float4 o0, o1;
        o0.x = (v0.x - m) * scale * g0.x + b0.x;
        o0.y = (v0.y - m) * scale * g0.y + b0.y;
        o0.z = (v0.z - m) * scale * g0.z + b0.z;
        o0.w = (v0.w - m) * scale * g0.w + b0.w;
        o1.x = (v1.x - m) * scale * g1.x + b1.x;
        o1.y = (v1.y - m) * scale * g1.y + b1.y;
        o1.z = (v1.z - m) * scale * g1.z + b1.z;
        o1.w = (v1.w - m) * scale * g1.w + b1.w;
        *(float4*)(p + lane * 4) = o0;
        *(float4*)(p + 256 + lane * 4) = o1;
        unsigned short* dst = xpB + (size_t)row * DQ;
        ushort4 h0, h1;
        h0.x = f2bf(o0.x); h0.y = f2bf(o0.y); h0.z = f2bf(o0.z); h0.w = f2bf(o0.w);
        h1.x = f2bf(o1.x); h1.y = f2bf(o1.y); h1.z = f2bf(o1.z); h1.w = f2bf(o1.w);
        *(ushort4*)(dst + lane * 4) = h0;
        *(ushort4*)(dst + 256 + lane * 4) = h1;
        if (lane == 0) {
            float lg = logits[row];
            float sc = 1.f / (1.f + expf(-lg));
            score[row] = sc;
            if (sc > 0.6f) { int pp = atomicAdd(&nh_s, 1); hloc[pp] = row; }
            else           { int pp = atomicAdd(&nl_s, 1); lloc[pp] = row; }
        }
    }
    __syncthreads();
    if (tid == 0) {
        bh_s = atomicAdd(&counts[0], nh_s);
        bl_s = atomicAdd(&counts[1], nl_s);
    }
    __syncthreads();
    if (tid < 32) {
        if (tid < nh_s) hlist[bh_s + tid] = hloc[tid];
    } else if (tid < 64) {
        int j = tid - 32;
        if (j < nl_s) llist[bl_s + j] = lloc[j];
    }
}

// ---------------- fallback LayerNorm + routing (mask-based) ----------------
__global__ __launch_bounds__(256) void ln_route(float* __restrict__ xp,
                                                const float* __restrict__ g,
                                                const float* __restrict__ b,
                                                const float* __restrict__ logits,
                                                float* __restrict__ score,
                                                int* __restrict__ mask,
                                                unsigned short* __restrict__ xpB) {
    int row = blockIdx.x * 4 + (threadIdx.x >> 6);
    int lane = threadIdx.x & 63;
    float* p = xp + (size_t)row * DQ;
    float4 v0 = *(float4*)(p + lane * 4);
    float4 v1 = *(float4*)(p + 256 + lane * 4);
    float s  = v0.x + v0.y + v0.z + v0.w + v1.x + v1.y + v1.z + v1.w;
    float ss = v0.x*v0.x + v0.y*v0.y + v0.z*v0.z + v0.w*v0.w
             + v1.x*v1.x + v1.y*v1.y + v1.z*v1.z + v1.w*v1.w;
    s = wave_reduce_sum(s);
    ss = wave_reduce_sum(ss);
    float m = s * (1.f / DQ);
    float var = ss * (1.f / DQ) - m * m;
    float scale = rsqrtf(var + 1e-5f);
    float4 g0 = *(const float4*)(g + lane * 4);
    float4 g1 = *(const float4*)(g + 256 + lane * 4);
    float4 b0 = *(const float4*)(b + lane * 4);
    float4 b1 = *(const float4*)(b + 256 + lane * 4);
    float4 o0, o1;
    o0.x = (v0.x - m) * scale * g0.x + b0.x;
    o0.y = (v0.y - m) * scale * g0.y + b0.y;
    o0.z = (v0.z - m) * scale * g0.z + b0.z;
    o0.w = (v0.w - m) * scale * g0.w + b0.w;
    o1.x = (v1.x - m) * scale * g1.x + b1.x;
    o1.y = (v1.y - m) * scale * g1.y + b1.y;
    o1.z = (v1.z - m) * scale * g1.z + b1.z;
    o1.w = (v1.w - m) * scale * g1.w + b1.w;
    *(float4*)(p + lane * 4) = o0;
    *(float4*)(p + 256 + lane * 4) = o1;
    if (xpB) {
        unsigned short* dst = xpB + (size_t)row * DQ;
        ushort4 h0, h1;
        h0.x = f2bf(o0.x); h0.y = f2bf(o0.y); h0.z = f2bf(o0.z); h0.w = f2bf(o0.w);
        h1.x = f2bf(o1.x); h1.y = f2bf(o1.y); h1.z = f2bf(o1.z); h1.w = f2bf(o1.w);
        *(ushort4*)(dst + lane * 4) = h0;
        *(ushort4*)(dst + 256 + lane * 4) = h1;
    }
    if (lane == 0) {
        float lg = logits[row];
        float sc = 1.f / (1.f + expf(-lg));
        score[row] = sc;
        mask[row] = sc > 0.6f ? 1 : 0;
    }
}

// ---------------- deterministic compaction (fallback path only) ----------------
__global__ __launch_bounds__(1024) void scan_compact(const int* __restrict__ mask,
                                                     int* __restrict__ hlist,
                                                     int* __restrict__ llist,
                                                     int* __restrict__ counts) {
    __shared__ int wsum[16];
    __shared__ int base_h, base_l;
    int tid = threadIdx.x, lane = tid & 63, wid = tid >> 6;
    if (tid == 0) { base_h = 0; base_l = 0; }
    __syncthreads();
    for (int t0 = 0; t0 < T_TOK; t0 += 1024) {
        int t = t0 + tid;
        int valid = t < T_TOK;
        int m = valid ? mask[t] : 0;
        unsigned long long bal = __ballot(m);
        int pre = __popcll(bal & ((1ull << lane) - 1ull));
        if (lane == 0) wsum[wid] = __popcll(bal);
        __syncthreads();
        int woff = 0;
        for (int w = 0; w < wid; w++) woff += wsum[w];
        int btot = 0;
        for (int w = 0; w < 16; w++) btot += wsum[w];
        int vcnt = T_TOK - t0; if (vcnt > 1024) vcnt = 1024;
        int bh = base_h, bl = base_l;
        if (valid) {
            if (m) hlist[bh + woff + pre] = t;
            else   llist[bl + (tid - (woff + pre))] = t;
        }
        __syncthreads();
        if (tid == 0) { base_h = bh + btot; base_l = bl + (vcnt - btot); }
        __syncthreads();
    }
    if (tid == 0) { counts[0] = base_h; counts[1] = base_l; }
}

// ---------------- merged MFMA approx-score VQ: 128x256 tile, depth-2 counted-vmcnt pipeline ----------------
// 3 LDS buffers; loads for steps t and t+1 always in flight; per step ONE raw
// s_barrier + s_waitcnt vmcnt(3) (never 0 in-loop) so loads span barriers.
// Hazards: RAW covered by vmcnt+barrier (buf t's loads issued 2 steps earlier);
// WAR covered by barrier (buf (t+2)%3 last read at step t-1). Post-loop scratch
// aliases dead buffers. Per-(token,code) MFMA chain unchanged -> bit-identical.
__global__ __launch_bounds__(512) void vq_mfma_all(const unsigned short* __restrict__ xpB,
                                                   const unsigned short* __restrict__ cbhB,
                                                   const float* __restrict__ cs2h,
                                                   const int* __restrict__ hlist,
                                                   const unsigned short* __restrict__ cblB,
                                                   const float* __restrict__ cs2l,
                                                   const int* __restrict__ llist,
                                                   const int* __restrict__ counts,
                                                   float* __restrict__ smaxH,
                                                   int* __restrict__ scntH,
                                                   uint2* __restrict__ candH,
                                                   float* __restrict__ smaxL,
                                                   int* __restrict__ scntL,
                                                   uint2* __restrict__ candL) {
    const int by = blockIdx.y;
    const unsigned short* cbB; const float* cs2; const int* list;
    float* smax; int* scnt; uint2* cand;
    int count, slice, SPLIT;
    if (by < SPL_H) {
        cbB = cbhB; cs2 = cs2h; list = hlist; count = counts[0];
        slice = by; SPLIT = SPL_H; smax = smaxH; scnt = scntH; cand = candH;
    } else {
        cbB = cblB; cs2 = cs2l; list = llist; count = counts[1];
        slice = 0; SPLIT = 1; smax = smaxL; scnt = scntL; cand = candL;
    }
    const int base = blockIdx.x * VQTOK;
    if (base >= count) return;
    const int cbase = slice * CODES_PER_BLK;

    // 3 buffers x (A 8KB + B 16KB) = 73728 B, + rows_s 512 B
    __shared__ __align__(16) unsigned char SMEM[3 * 24576 + 512];
    int* rows_s = (int*)(SMEM + 3 * 24576);
    // post-loop aliases (over buffer 0 region, used only after the k-loop)
    uint2 (*cland)[CAND_CAP] = (uint2(*)[CAND_CAP])SMEM;          // 16384 B
    float* wmaxs  = (float*)(SMEM + 16384);                       // 8*64*4 = 2048
    float* tokmax = (float*)(SMEM + 18432);                       // 512
    int*   ccnt   = (int*)(SMEM + 18944);                         // 512

    const int tid = threadIdx.x;
    const int lane = tid & 63;
    const int w = tid >> 6;            // 0..7
    const int wr = w >> 2, wc = w & 3; // wave quadrant: 64 tokens x 64 codes
    const int stok = tid >> 2, sslot = tid & 3;

    if (tid < VQTOK) {
        int tl = base + tid;
        rows_s[tid] = list[tl < count ? tl : (count - 1)];
    }
    __syncthreads();

    const int swz = sslot ^ ((stok >> 1) & 3);
    const unsigned short* gA  = xpB + (size_t)rows_s[stok] * DQ + swz * 8;
    const unsigned short* gB0 = cbB + (size_t)(cbase + stok) * DQ + swz * 8;
    const unsigned short* gB1 = cbB + (size_t)(cbase + 128 + stok) * DQ + swz * 8;

    auto stage = [&](int buf, int k0) {
        unsigned short* Ab = (unsigned short*)(SMEM + buf * 24576);
        gload_lds16(gA  + k0, Ab + w * 512);
        gload_lds16(gB0 + k0, Ab + 4096 + w * 512);
        gload_lds16(gB1 + k0, Ab + 8192 + w * 512);
    };

    f32x4 acc[4][4] = {};
    const int fr = lane & 15, fs = lane >> 4;

    auto compute = [&](int buf) {
        const unsigned short* Ab = (const unsigned short*)(SMEM + buf * 24576);
        const unsigned short* Bb = Ab + 4096;
        s16x8 af[4], bf[4];
        #pragma unroll
        for (int tm = 0; tm < 4; tm++) {
            int tok = wr * 64 + tm * 16 + fr;
            af[tm] = *(const s16x8*)&Ab[tok * 32 + (fs ^ ((tok >> 1) & 3)) * 8];
        }
        #pragma unroll
        for (int tn = 0; tn < 4; tn++) {
            int cl = wc * 64 + tn * 16 + fr;
            bf[tn] = *(const s16x8*)&Bb[cl * 32 + (fs ^ ((cl >> 1) & 3)) * 8];
        }
        #pragma unroll
        for (int tm = 0; tm < 4; tm++)
            #pragma unroll
            for (int tn = 0; tn < 4; tn++)
                acc[tm][tn] = __builtin_amdgcn_mfma_f32_16x16x32_bf16(af[tm], bf[tn], acc[tm][tn], 0, 0, 0);
    };

    // prologue: steps 0,1 in flight
    stage(0, 0);
    stage(1, 32);
    // main loop: steps 0..13 (prefetch t+2); peeled tail 14,15
    for (int t = 0; t < 14; t++) {
        asm volatile("s_waitcnt vmcnt(3)" ::: "memory");   // buf t's loads landed
        __builtin_amdgcn_s_barrier();                      // all waves: landed + done reading (t+2)%3
        __builtin_amdgcn_sched_barrier(0);
        stage((t + 2) % 3, (t + 2) * 32);
        compute(t % 3);
    }
    asm volatile("s_waitcnt vmcnt(3)" ::: "memory");
    __builtin_amdgcn_s_barrier();
    __builtin_amdgcn_sched_barrier(0);
    compute(14 % 3);
    asm volatile("s_waitcnt vmcnt(0)" ::: "memory");
    __builtin_amdgcn_s_barrier();
    __builtin_amdgcn_sched_barrier(0);
    compute(15 % 3);
    __syncthreads();   // seal buffers before aliasing scratch over them

    if (tid < VQTOK) ccnt[tid] = 0;
    float c2[4];
    #pragma unroll
    for (int tn = 0; tn < 4; tn++) c2[tn] = 0.5f * cs2[cbase + wc * 64 + tn * 16 + fr];
    const int fg = lane >> 4;

    #pragma unroll
    for (int tm = 0; tm < 4; tm++) {
        #pragma unroll
        for (int r = 0; r < 4; r++) {
            float m4 = -3.0e38f;
            #pragma unroll
            for (int tn = 0; tn < 4; tn++) {
                float s = acc[tm][tn][r] - c2[tn];
                m4 = fmaxf(m4, s);
            }
            #pragma unroll
            for (int off = 1; off < 16; off <<= 1)
                m4 = fmaxf(m4, __shfl_xor(m4, off));
            if (fr == 0) wmaxs[w * 64 + tm * 16 + fg * 4 + r] = m4;
        }
    }
    __syncthreads();
    if (tid < VQTOK) {
        int wrt = tid >> 6, tlc = tid & 63;
        tokmax[tid] = fmaxf(fmaxf(wmaxs[(wrt * 4 + 0) * 64 + tlc], wmaxs[(wrt * 4 + 1) * 64 + tlc]),
                            fmaxf(wmaxs[(wrt * 4 + 2) * 64 + tlc], wmaxs[(wrt * 4 + 3) * 64 + tlc]));
    }
    __syncthreads();

    #pragma unroll
    for (int tm = 0; tm < 4; tm++) {
        #pragma unroll
        for (int r = 0; r < 4; r++) {
            int token = wr * 64 + tm * 16 + fg * 4 + r;
            float thr = tokmax[token] - MARGIN;
            #pragma unroll
            for (int tn = 0; tn < 4; tn++) {
                float s = acc[tm][tn][r] - c2[tn];
                if (s > thr) {
                    int pos = atomicAdd(&ccnt[token], 1);
                    if (pos < CAND_CAP) {
                        uint2 cd;
                        cd.x = __float_as_uint(s);
                        cd.y = (unsigned)(cbase + wc * 64 + tn * 16 + fr);
                        cland[token][pos] = cd;
                    }
                }
            }
        }
    }
    __syncthreads();

    if (tid < VQTOK) {
        int tl = base + tid;
        if (tl < count) {
            smax[(size_t)tl * SPLIT + slice] = tokmax[tid];
            scnt[(size_t)tl * SPLIT + slice] = min(ccnt[tid], CAND_CAP);
        }
    }
    for (int i = tid; i < VQTOK * CAND_CAP; i += 512) {
        int token = i >> 4, j = i & (CAND_CAP - 1);
        int tl = base + token;
        if (tl < count && j < min(ccnt[token], CAND_CAP))
            cand[((size_t)tl * SPLIT + slice) * CAND_CAP + j] = cland[token][j];
    }
}

// ---------------- merged exact fp64 rescore + FUSED gather/loss/y ----------------
__global__ __launch_bounds__(256) void vq_rescore_all(float* __restrict__ xp,
                                                      const float* __restrict__ cb_h,
                                                      const float* __restrict__ smaxH,
                                                      const int* __restrict__ scntH,
                                                      const uint2* __restrict__ candH,
                                                      const int* __restrict__ hlist,
                                                      const float* __restrict__ cb_l,
                                                      const float* __restrict__ smaxL,
                                                      const int* __restrict__ scntL,
                                                      const uint2* __restrict__ candL,
                                                      const int* __restrict__ llist,
                                                      const int* __restrict__ counts,
                                                      int* __restrict__ out_idx,
                                                      const float* __restrict__ noise,
                                                      const float* __restrict__ h_ri,
                                                      const float* __restrict__ score,
                                                      float* __restrict__ lh,
                                                      float* __restrict__ ll) {
    const int HB = T_TOK / 4;
    int bx = blockIdx.x;
    const float* cb; const float* smax; const int* scnt; const uint2* cand; const int* list;
    int count, SPLIT, cidx;
    if (bx < HB) {
        cb = cb_h; smax = smaxH; scnt = scntH; cand = candH; list = hlist;
        count = counts[0]; SPLIT = SPL_H; cidx = 0;
    } else {
        bx -= HB;
        cb = cb_l; smax = smaxL; scnt = scntL; cand = candL; list = llist;
        count = counts[1]; SPLIT = 1; cidx = 1;
    }
    const int wid = threadIdx.x >> 6;
    const int lane = threadIdx.x & 63;
    const int tl = bx * 4 + wid;
    if (tl >= count) return;

    float gm = -3.0e38f;
    if (lane < SPLIT) gm = smax[(size_t)tl * SPLIT + lane];
    #pragma unroll
    for (int off = 1; off < 64; off <<= 1)
        gm = fmaxf(gm, __shfl_xor(gm, off));
    const float thr = gm - MARGIN;

    const int t = list[tl];
    float xv[8];
    #pragma unroll
    for (int kk = 0; kk < 8; kk++) xv[kk] = xp[(size_t)t * DQ + lane * 8 + kk];

    double bs = -1.0e300;
    int bi = 0x7fffffff;
    for (int s = 0; s < SPLIT; s++) {
        int cn = scnt[(size_t)tl * SPLIT + s];
        for (int j = 0; j < cn; j++) {
            uint2 cd = cand[((size_t)tl * SPLIT + s) * CAND_CAP + j];
            float av = __uint_as_float(cd.x);
            if (av >= thr) {
                int code = (int)cd.y;
                const float* crow = cb + (size_t)code * DQ;
                double dot = 0.0, nrm = 0.0;
                #pragma unroll
                for (int kk = 0; kk < 8; kk++) {
                    double cv = (double)crow[lane * 8 + kk];
                    dot += (double)xv[kk] * cv;
                    nrm += cv * cv;
                }
                #pragma unroll
                for (int off = 1; off < 64; off <<= 1) {
                    dot += __shfl_xor(dot, off);
                    nrm += __shfl_xor(nrm, off);
                }
                double sc = dot - 0.5 * nrm;
                if (sc > bs || (sc == bs && code < bi)) { bs = sc; bi = code; }
            }
        }
    }
    const float* qrow = cb + (size_t)bi * DQ;
    float4 q0 = *(const float4*)(qrow + lane * 8);
    float4 q1 = *(const float4*)(qrow + lane * 8 + 4);
    const float* nz = noise + (size_t)t * DQ;
    float4 n0 = *(const float4*)(nz + lane * 8);
    float4 n1 = *(const float4*)(nz + lane * 8 + 4);
    float ds = 0.f, dx;
    dx = xv[0] - q0.x; ds += dx * dx;
    dx = xv[1] - q0.y; ds += dx * dx;
    dx = xv[2] - q0.z; ds += dx * dx;
    dx = xv[3] - q0.w; ds += dx * dx;
    dx = xv[4] - q1.x; ds += dx * dx;
    dx = xv[5] - q1.y; ds += dx * dx;
    dx = xv[6] - q1.z; ds += dx * dx;
    dx = xv[7] - q1.w; ds += dx * dx;
    ds = wave_reduce_sum(ds);
    int bbt = t / SEQ;
    float hh0 = h_ri[bbt * 2], hh1 = h_ri[bbt * 2 + 1];
    float hh = sqrtf((hh0 * hh0 + hh1 * hh1) * 0.5f);
    float cc = sqrtf(1e-3f) / hh;
    float4 y0, y1;
    y0.x = q0.x + cc * n0.x; y0.y = q0.y + cc * n0.y;
    y0.z = q0.z + cc * n0.z; y0.w = q0.w + cc * n0.w;
    y1.x = q1.x + cc * n1.x; y1.y = q1.y + cc * n1.y;
    y1.z = q1.z + cc * n1.z; y1.w = q1.w + cc * n1.w;
    *(float4*)(xp + (size_t)t * DQ + lane * 8) = y0;
    *(float4*)(xp + (size_t)t * DQ + lane * 8 + 4) = y1;
    if (lane == 0) {
        out_idx[t] = bi;
        float loss = 1.25f * ds * (1.f / DQ);
        float sc = score[t];
        if (cidx == 0) { lh[t] = loss * sc;  ll[t] = 0.f; }
        else           { lh[t] = 0.f;        ll[t] = loss * (1.f - sc); }
    }
}

// ---------------- FALLBACK fp32 VQ (unchanged) ----------------
template<int NC, int SPLIT>
__global__ __launch_bounds__(256) void vq_partial(const float* __restrict__ xp,
                                                  const float* __restrict__ cb,
                                                  const float* __restrict__ cs2,
                                                  const int* __restrict__ list,
                                                  const int* __restrict__ counts,
                                                  int cidx,
                                                  float* __restrict__ part_s,
                                                  int* __restrict__ part_i) {
    const int count = counts[cidx];
    const int base = blockIdx.x * 64;
    if (base >= count) return;
    const int CODES = NC / SPLIT;
    const int cbase = blockIdx.y * CODES;
    __shared__ float As[32][68];
    __shared__ float Cs[32][68];
    __shared__ int rows_s[64];
    const int tid = threadIdx.x;
    if (tid < 64) {
        int tl = base + tid;
        rows_s[tid] = list[tl < count ? tl : (count - 1)];
    }
    __syncthreads();
    const int tx = tid & 15, ty = tid >> 4;
    float best_s[4];
    int best_i[4];
    #pragma unroll
    for (int i = 0; i < 4; i++) { best_s[i] = -3.0e38f; best_i[i] = 0; }
    for (int c0 = cbase; c0 < cbase + CODES; c0 += 64) {
        float acc[4][4] = {};
        for (int k0 = 0; k0 < DQ; k0 += 32) {
            {
                int e = tid;
                int r = e >> 3, c4 = e & 7;
                float4 v = *(const float4*)(xp + (size_t)rows_s[r] * DQ + k0 + c4 * 4);
                As[c4*4+0][r] = v.x; As[c4*4+1][r] = v.y; As[c4*4+2][r] = v.z; As[c4*4+3][r] = v.w;
                e = tid + 256; r = e >> 3; c4 = e & 7;
                v = *(const float4*)(xp + (size_t)rows_s[r] * DQ + k0 + c4 * 4);
                As[c4*4+0][r] = v.x; As[c4*4+1][r] = v.y; As[c4*4+2][r] = v.z; As[c4*4+3][r] = v.w;
            }
            {
                int e = tid;
                int r = e >> 3, c4 = e & 7;
                float4 v = *(const float4*)(cb + (size_t)(c0 + r) * DQ + k0 + c4 * 4);
                Cs[c4*4+0][r] = v.x; Cs[c4*4+1][r] = v.y; Cs[c4*4+2][r] = v.z; Cs[c4*4+3][r] = v.w;
                e = tid + 256; r = e >> 3; c4 = e & 7;
                v = *(const float4*)(cb + (size_t)(c0 + r) * DQ + k0 + c4 * 4);
                Cs[c4*4+0][r] = v.x; Cs[c4*4+1][r] = v.y; Cs[c4*4+2][r] = v.z; Cs[c4*4+3][r] = v.w;
            }
            __syncthreads();
            #pragma unroll
            for (int k = 0; k < 32; k++) {
                float4 a = *(const float4*)&As[k][ty * 4];
                float4 b = *(const float4*)&Cs[k][tx * 4];
                float av[4] = {a.x, a.y, a.z, a.w};
                float bv[4] = {b.x, b.y, b.z, b.w};
                #pragma unroll
                for (int i = 0; i < 4; i++)
                    #pragma unroll
                    for (int j = 0; j < 4; j++)
                        acc[i][j] += av[i] * bv[j];
            }
            __syncthreads();
        }
        float4 c2v = *(const float4*)(cs2 + c0 + tx * 4);
        float c2[4] = {c2v.x, c2v.y, c2v.z, c2v.w};
        #pragma unroll
        for (int i = 0; i < 4; i++) {
            float s = acc[i][0] - 0.5f * c2[0];
            int bi = c0 + tx * 4;
            #pragma unroll
            for (int j = 1; j < 4; j++) {
                float sj = acc[i][j] - 0.5f * c2[j];
                if (sj > s) { s = sj; bi = c0 + tx * 4 + j; }
            }
            #pragma unroll
            for (int off = 1; off < 16; off <<= 1) {
                float os = __shfl_xor(s, off);
                int oi = __shfl_xor(bi, off);
                if (os > s || (os == s && oi < bi)) { s = os; bi = oi; }
            }
            if (s > best_s[i] || (s == best_s[i] && bi < best_i[i])) {
                best_s[i] = s; best_i[i] = bi;
            }
        }
    }
    if (tx == 0) {
        #pragma unroll
        for (int i = 0; i < 4; i++) {
            int tl = base + ty * 4 + i;
            if (tl < count) {
                part_s[(size_t)tl * SPLIT + blockIdx.y] = best_s[i];
                part_i[(size_t)tl * SPLIT + blockIdx.y] = best_i[i];
            }
        }
    }
}

template<int SPLIT>
__global__ __launch_bounds__(256) void vq_reduce(const float* __restrict__ part_s,
                                                 const int* __restrict__ part_i,
                                                 const int* __restrict__ list,
                                                 const int* __restrict__ counts,
                                                 int cidx,
                                                 int* __restrict__ out_idx) {
    int tl = blockIdx.x * 256 + threadIdx.x;
    if (tl >= counts[cidx]) return;
    float bs = part_s[(size_t)tl * SPLIT];
    int bi = part_i[(size_t)tl * SPLIT];
    #pragma unroll
    for (int s = 1; s < SPLIT; s++) {
        float v = part_s[(size_t)tl * SPLIT + s];
        int vi = part_i[(size_t)tl * SPLIT + s];
        if (v > bs || (v == bs && vi < bi)) { bs = v; bi = vi; }
    }
    out_idx[list[tl]] = bi;
}

// ---------------- gather q, per-token loss, y (fallback path only) ----------------
__global__ __launch_bounds__(256) void gather_loss_y(float* __restrict__ xp,
                                                     const float* __restrict__ cb_h,
                                                     const float* __restrict__ cb_l,
                                                     const int* __restrict__ idx,
                                                     const float* __restrict__ score,
                                                     const int* __restrict__ mask,
                                                     const float* __restrict__ noise,
                                                     const float* __restrict__ h_ri,
                                                     float* __restrict__ lh,
                                                     float* __restrict__ ll) {
    int t = blockIdx.x * 4 + (threadIdx.x >> 6);
    int lane = threadIdx.x & 63;
    int m = mask[t];
    float sc = score[t];
    const float* q = (m ? cb_h : cb_l) + (size_t)idx[t] * DQ;
    float* x = xp + (size_t)t * DQ;
    const float* nz = noise + (size_t)t * DQ;
    int bb = t / SEQ;
    float h0 = h_ri[bb * 2], h1 = h_ri[bb * 2 + 1];
    float h = sqrtf((h0 * h0 + h1 * h1) * 0.5f);
    float c = sqrtf(1e-3f) / h;
    float4 xv0 = *(float4*)(x + lane * 4);
    float4 xv1 = *(float4*)(x + 256 + lane * 4);
    float4 qv0 = *(const float4*)(q + lane * 4);
    float4 qv1 = *(const float4*)(q + 256 + lane * 4);
    float4 nv0 = *(const float4*)(nz + lane * 4);
    float4 nv1 = *(const float4*)(nz + 256 + lane * 4);
    float dx, ds = 0.f;
    dx = xv0.x - qv0.x; ds += dx * dx;
    dx = xv0.y - qv0.y; ds += dx * dx;
    dx = xv0.z - qv0.z; ds += dx * dx;
    dx = xv0.w - qv0.w; ds += dx * dx;
    dx = xv1.x - qv1.x; ds += dx * dx;
    dx = xv1.y - qv1.y; ds += dx * dx;
    dx = xv1.z - qv1.z; ds += dx * dx;
    dx = xv1.w - qv1.w; ds += dx * dx;
    ds = wave_reduce_sum(ds);
    float4 y0, y1;
    y0.x = qv0.x + c * nv0.x; y0.y = qv0.y + c * nv0.y;
    y0.z = qv0.z + c * nv0.z; y0.w = qv0.w + c * nv0.w;
    y1.x = qv1.x + c * nv1.x; y1.y = qv1.y + c * nv1.y;
    y1.z = qv1.z + c * nv1.z; y1.w = qv1.w + c * nv1.w;
    *(float4*)(x + lane * 4) = y0;
    *(float4*)(x + 256 + lane * 4) = y1;
    if (lane == 0) {
        float loss = 1.25f * ds * (1.f / DQ);
        lh[t] = m ? loss * sc : 0.f;
        ll[t] = m ? 0.f : loss * (1.f - sc);
    }
}

// ---------------- deterministic loss reduction (fallback path only) ----------------
__global__ __launch_bounds__(256) void loss_reduce(const float* __restrict__ lh,
                                                   const float* __restrict__ ll,
                                                   const int* __restrict__ counts,
                                                   float* __restrict__ out) {
    __shared__ float sh[256], sl[256];
    int tid = threadIdx.x;
    float ah = 0.f, al = 0.f;
    for (int t = tid; t < T_TOK; t += 256) { ah += lh[t]; al += ll[t]; }
    sh[tid] = ah; sl[tid] = al;
    __syncthreads();
    for (int o = 128; o > 0; o >>= 1) {
        if (tid < o) { sh[tid] += sh[tid + o]; sl[tid] += sl[tid + o]; }
        __syncthreads();
    }
    if (tid == 0) {
        int nh = counts[0];
        int nl = T_TOK - nh;
        nh = nh > 1 ? nh : 1;
        nl = nl > 1 ? nl : 1;
        out[(size_t)T_TOK * DD] = 0.5f * (sh[0] / (float)nh + sl[0] / (float)nl);
    }
}

// ---------------- fp32 dec (fallback only) ----------------
__global__ __launch_bounds__(256) void dec_gemm(const float* __restrict__ Y,
                                                const float* __restrict__ W,
                                                const float* __restrict__ bias,
                                                float* __restrict__ out) {
    __shared__ float As[32][66];
    __shared__ float Bs[32][64];
    const int m0 = blockIdx.x * 64, n0 = blockIdx.y * 64;
    const int tid = threadIdx.x;
    const int tx = tid & 15, ty = tid >> 4;
    float acc[4][4] = {};
    for (int k0 = 0; k0 < DQ; k0 += 32) {
        {
            int e = tid;
            int r = e >> 3, c4 = e & 7;
            float4 v = *(const float4*)(Y + (size_t)(m0 + r) * DQ + k0 + c4 * 4);
            As[c4*4+0][r] = v.x; As[c4*4+1][r] = v.y; As[c4*4+2][r] = v.z; As[c4*4+3][r] = v.w;
            e = tid + 256; r = e >> 3; c4 = e & 7;
            v = *(const float4*)(Y + (size_t)(m0 + r) * DQ + k0 + c4 * 4);
            As[c4*4+0][r] = v.x; As[c4*4+1][r] = v.y; As[c4*4+2][r] = v.z; As[c4*4+3][r] = v.w;
        }
        {
            int e = tid;
            int kk = e >> 4, c4 = e & 15;
            *(float4*)&Bs[kk][c4*4] = *(const float4*)(W + (size_t)(k0 + kk) * DD + n0 + c4 * 4);
            e = tid + 256; kk = e >> 4; c4 = e & 15;
            *(float4*)&Bs[kk][c4*4] = *(const float4*)(W + (size_t)(k0 + kk) * DD + n0 + c4 * 4);
        }
        __syncthreads();
        #pragma unroll
        for (int k = 0; k < 32; k++) {
            float2 a01 = *(const float2*)&As[k][ty * 4];
            float2 a23 = *(const float2*)&As[k][ty * 4 + 2];
            float4 b = *(const float4*)&Bs[k][tx * 4];
            float av[4] = {a01.x, a01.y, a23.x, a23.y};
            float bv[4] = {b.x, b.y, b.z, b.w};
            #pragma unroll
            for (int i = 0; i < 4; i++)
                #pragma unroll
                for (int j = 0; j < 4; j++)
                    acc[i][j] += av[i] * bv[j];
        }
        __syncthreads();
    }
    float4 bv4 = *(const float4*)(bias + n0 + tx * 4);
    float bbv[4] = {bv4.x, bv4.y, bv4.z, bv4.w};
    #pragma unroll
    for (int i = 0; i < 4; i++) {
        int row = m0 + ty * 4 + i;
        float4 o;
        o.x = acc[i][0] + bbv[0];
        o.y = acc[i][1] + bbv[1];
        o.z = acc[i][2] + bbv[2];
        o.w = acc[i][3] + bbv[3];
        *(float4*)(out + (size_t)row * DD + n0 + tx * 4) = o;
    }
}

extern "C" void kernel_launch(void* const* d_in, const int* in_sizes, int n_in,
                              void* d_out, int out_size, void* d_ws, size_t ws_size,
                              hipStream_t stream) {
    const float* x_tokens = (const float*)d_in[0];
    const float* fim      = (const float*)d_in[1];
    const float* W_proj   = (const float*)d_in[2];
    const float* b_proj   = (const float*)d_in[3];
    const float* ln_g     = (const float*)d_in[4];
    const float* ln_b     = (const float*)d_in[5];
    const float* cb_high  = (const float*)d_in[6];
    const float* cb_low   = (const float*)d_in[7];
    const float* W_dec    = (const float*)d_in[8];
    const float* b_dec    = (const float*)d_in[9];
    const float* h_ri     = (const float*)d_in[10];
    const float* noise    = (const float*)d_in[11];
    float* out = (float*)d_out;

    char* ws = (char*)d_ws;
    size_t off = 0;
    float* xp = (float*)(ws + off);     off += (size_t)T_TOK * DQ * 4;
    int*   idxb = (int*)(ws + off);     off += (size_t)T_TOK * 4;
    float* score = (float*)(ws + off);  off += (size_t)T_TOK * 4;
    int*   mask = (int*)(ws + off);     off += (size_t)T_TOK * 4;
    float* lh = (float*)(ws + off);     off += (size_t)T_TOK * 4;
    float* ll = (float*)(ws + off);     off += (size_t)T_TOK * 4;
    int*   hlist = (int*)(ws + off);    off += (size_t)T_TOK * 4;
    int*   llist = (int*)(ws + off);    off += (size_t)T_TOK * 4;
    int*   counts = (int*)(ws + off);   off += 64;
    float* cs2h = (float*)(ws + off);   off += (size_t)NCH * 4;
    float* cs2l = (float*)(ws + off);   off += (size_t)NCL * 4;
    size_t off_common = off;

    unsigned short* xpB  = (unsigned short*)(ws + off); off += (size_t)T_TOK * DQ * 2;
    unsigned short* cbhB = (unsigned short*)(ws + off); off += (size_t)NCH * DQ * 2;
    unsigned short* cblB = (unsigned short*)(ws + off); off += (size_t)NCL * DQ * 2;
    float* smaxH = (float*)(ws + off);  off += (size_t)T_TOK * SPL_H * 4;
    int*   scntH = (int*)(ws + off);    off += (size_t)T_TOK * SPL_H * 4;
    uint2* candH = (uint2*)(ws + off);  off += (size_t)T_TOK * SPL_H * CAND_CAP * 8;
    float* smaxL = (float*)(ws + off);  off += (size_t)T_TOK * 4;
    int*   scntL = (int*)(ws + off);    off += (size_t)T_TOK * 4;
    uint2* candL = (uint2*)(ws + off);  off += (size_t)T_TOK * CAND_CAP * 8;
    unsigned short* WThi  = (unsigned short*)(ws + off); off += (size_t)DQ * DE * 2;
    unsigned short* WTlo  = (unsigned short*)(ws + off); off += (size_t)DQ * DE * 2;
    unsigned short* WdThi = (unsigned short*)(ws + off); off += (size_t)DD * DQ * 2;
    unsigned short* WdTlo = (unsigned short*)(ws + off); off += (size_t)DD * DQ * 2;
    size_t need_new = off;
    const bool use_mfma = ws_size >= need_new;

    if (use_mfma) {
        prep_all<<<1856, 256, 0, stream>>>(cb_high, cs2h, cbhB, cb_low, cs2l, cblB,
                                           W_proj, WThi, WTlo, W_dec, WdThi, WdTlo, counts);
        gemm_mfma3_128<DE, DQ><<<dim3(T_TOK / 128, DQ / 128), 256, 0, stream>>>(
            x_tokens, WThi, WTlo, b_proj, xp);
        ln_route_compact<<<T_TOK / 32, 256, 0, stream>>>(
            xp, ln_g, ln_b, fim, score, xpB, hlist, llist, counts);
        vq_mfma_all<<<dim3(T_TOK / VQTOK, SPL_H + 1), 512, 0, stream>>>(
            xpB, cbhB, cs2h, hlist, cblB, cs2l, llist, counts,
            smaxH, scntH, candH, smaxL, scntL, candL);
        vq_rescore_all<<<2 * (T_TOK / 4), 256, 0, stream>>>(
            xp, cb_high, smaxH, scntH, candH, hlist,
            cb_low, smaxL, scntL, candL, llist,
            counts, idxb, noise, h_ri, score, lh, ll);
        dec_mfma3_loss<<<dim3(T_TOK / 64 + 1, DD / 64), 256, 0, stream>>>(
            xp, WdThi, WdTlo, b_dec, out, lh, ll, counts);
    } else {
        code_sumsq<NCH><<<NCH / 4, 256, 0, stream>>>(cb_high, cs2h);
        code_sumsq<NCL><<<NCL / 4, 256, 0, stream>>>(cb_low, cs2l);
        proj_gemm<<<dim3(T_TOK / 64, DQ / 64), 256, 0, stream>>>(x_tokens, W_proj, b_proj, xp);
        ln_route<<<T_TOK / 4, 256, 0, stream>>>(xp, ln_g, ln_b, fim, score, mask, nullptr);
        scan_compact<<<1, 1024, 0, stream>>>(mask, hlist, llist, counts);
        float* part_s = (float*)(ws + off_common);
        int*   part_i = (int*)(ws + off_common + (size_t)T_TOK * 16 * 4);
        vq_partial<NCH, 16><<<dim3(T_TOK / 64, 16), 256, 0, stream>>>(
            xp, cb_high, cs2h, hlist, counts, 0, part_s, part_i);
        vq_reduce<16><<<(T_TOK + 255) / 256, 256, 0, stream>>>(part_s, part_i, hlist, counts, 0, idxb);
        vq_partial<NCL, 4><<<dim3(T_TOK / 64, 4), 256, 0, stream>>>(
            xp, cb_low, cs2l, llist, counts, 1, part_s, part_i);
        vq_reduce<4><<<(T_TOK + 255) / 256, 256, 0, stream>>>(part_s, part_i, llist, counts, 1, idxb);
        gather_loss_y<<<T_TOK / 4, 256, 0, stream>>>(xp, cb_high, cb_low, idxb, score, mask,
                                                     noise, h_ri, lh, ll);
        loss_reduce<<<1, 256, 0, stream>>>(lh, ll, counts, out);
        dec_gemm<<<dim3(T_TOK / 64, DD / 64), 256, 0, stream>>>(xp, W_dec, b_dec, out);
    }
}